// Round 1
// baseline (1151.387 us; speedup 1.0000x reference)
//
#include <hip/hip_runtime.h>
#include <hip/hip_bf16.h>
#include <math.h>

#define HEADS 4
#define HID 32
#define EMB 32
#define SLOPE 0.2f
#define BN_EPS 1e-5f
#define STATS_BLOCKS 512

__device__ __forceinline__ float lrelu(float x) { return x > 0.f ? x : SLOPE * x; }
__device__ __forceinline__ float elu(float x) { return x > 0.f ? x : expm1f(x); }

// ---------------- zero int buffer ----------------
__global__ void k_zero(int* p, int n) {
    int i = blockIdx.x * blockDim.x + threadIdx.x;
    if (i < n) p[i] = 0;
}

// ---------------- node transform layer 1: h1 = x @ W1 ; al_src/al_dst ----------------
__global__ void k_node1(const float* __restrict__ x, const float* __restrict__ W1,
                        const float* __restrict__ as1, const float* __restrict__ ad1,
                        float* __restrict__ h1, float* __restrict__ als, float* __restrict__ ald,
                        int n) {
    int idx = blockIdx.x * blockDim.x + threadIdx.x;
    int node = idx >> 2, hd = idx & 3;
    if (node >= n) return;
    float x0 = x[node * 2], x1 = x[node * 2 + 1];
    float ps = 0.f, pd = 0.f;
#pragma unroll
    for (int d = 0; d < 32; d++) {
        int c = hd * 32 + d;
        float v = x0 * W1[c] + x1 * W1[128 + c];
        h1[node * 128 + c] = v;
        ps += v * as1[c];
        pd += v * ad1[c];
    }
    als[node * 4 + hd] = ps;
    ald[node * 4 + hd] = pd;
}

// ---------------- degree count (dst, incl self loops) ----------------
__global__ void k_count(const int* __restrict__ ei, int* __restrict__ cnt, int E_, int N_) {
    int e = blockIdx.x * blockDim.x + threadIdx.x;
    if (e >= E_ + N_) return;
    int d = (e < E_) ? ei[E_ + e] : (e - E_);
    atomicAdd(&cnt[d], 1);
}

// ---------------- scan (3 stages) ----------------
__global__ void k_scan1(const int* __restrict__ cnt, int* __restrict__ incl,
                        int* __restrict__ blksum, int n) {
    __shared__ int s[256];
    int t = threadIdx.x, i = blockIdx.x * 256 + t;
    int v = (i < n) ? cnt[i] : 0;
    s[t] = v;
    __syncthreads();
    for (int off = 1; off < 256; off <<= 1) {
        int a = (t >= off) ? s[t - off] : 0;
        __syncthreads();
        s[t] += a;
        __syncthreads();
    }
    if (i < n) incl[i] = s[t];
    if (t == 255) blksum[blockIdx.x] = s[255];
}
__global__ void k_scan2(int* blksum, int nb) {
    if (threadIdx.x == 0 && blockIdx.x == 0) {
        int acc = 0;
        for (int i = 0; i < nb; i++) { int v = blksum[i]; blksum[i] = acc; acc += v; }
    }
}
__global__ void k_scan3(const int* __restrict__ cnt, const int* __restrict__ incl,
                        const int* __restrict__ blksum, int* __restrict__ rp,
                        int* __restrict__ pos, int n) {
    int i = blockIdx.x * blockDim.x + threadIdx.x;
    if (i >= n) return;
    int excl = incl[i] - cnt[i] + blksum[i >> 8];
    rp[i] = excl;
    pos[i] = excl;
    if (i == n - 1) rp[n] = incl[i] + blksum[i >> 8];
}

// ---------------- scatter edges into CSR (store src only) ----------------
__global__ void k_scatter(const int* __restrict__ ei, int* __restrict__ pos,
                          int* __restrict__ esrc, int E_, int N_) {
    int e = blockIdx.x * blockDim.x + threadIdx.x;
    if (e >= E_ + N_) return;
    int s, d;
    if (e < E_) { s = ei[e]; d = ei[E_ + e]; } else { s = d = e - E_; }
    int p = atomicAdd(&pos[d], 1);
    esrc[p] = s;
}

// ---------------- layer 1 aggregation: wave per dst node, 4 heads x 32 ----------------
__global__ void k_agg1(const float* __restrict__ h1, const float* __restrict__ als1,
                       const float* __restrict__ ald1, const int* __restrict__ rp,
                       const int* __restrict__ esrc, const float* __restrict__ b1,
                       float* __restrict__ out, int n) {
    int wid = (blockIdx.x * blockDim.x + threadIdx.x) >> 6;
    int lane = threadIdx.x & 63;
    if (wid >= n) return;
    int beg = rp[wid], end = rp[wid + 1];
    const float4 ad = *reinterpret_cast<const float4*>(&ald1[wid * 4]);
    float m0 = -1e30f, m1 = -1e30f, m2 = -1e30f, m3 = -1e30f;
    for (int i = beg; i < end; i++) {
        int s = esrc[i];
        const float4 a = *reinterpret_cast<const float4*>(&als1[s * 4]);
        m0 = fmaxf(m0, lrelu(a.x + ad.x));
        m1 = fmaxf(m1, lrelu(a.y + ad.y));
        m2 = fmaxf(m2, lrelu(a.z + ad.z));
        m3 = fmaxf(m3, lrelu(a.w + ad.w));
    }
    float z0 = 0.f, z1 = 0.f, z2 = 0.f, z3 = 0.f;
    float acc0 = 0.f, acc1 = 0.f;
    bool lo = lane < 32;
    for (int i = beg; i < end; i++) {
        int s = esrc[i];
        const float4 a = *reinterpret_cast<const float4*>(&als1[s * 4]);
        float w0 = __expf(lrelu(a.x + ad.x) - m0); z0 += w0;
        float w1 = __expf(lrelu(a.y + ad.y) - m1); z1 += w1;
        float w2 = __expf(lrelu(a.z + ad.z) - m2); z2 += w2;
        float w3 = __expf(lrelu(a.w + ad.w) - m3); z3 += w3;
        float wa = lo ? w0 : w1;
        float wb = lo ? w2 : w3;
        const float* hr = &h1[(size_t)s * 128];
        acc0 += wa * hr[lane];
        acc1 += wb * hr[64 + lane];
    }
    float za = lo ? z0 : z1, zb = lo ? z2 : z3;
    out[(size_t)wid * 128 + lane] = acc0 / (za + 1e-16f) + b1[lane];
    out[(size_t)wid * 128 + 64 + lane] = acc1 / (zb + 1e-16f) + b1[64 + lane];
}

// ---------------- BN stats: stage 1 (deterministic tree) ----------------
__global__ void k_stats(const float* __restrict__ x, float* __restrict__ partials,
                        int n, int C) {
    int t = threadIdx.x;
    int c = t & (C - 1);
    int rr = t / C;
    int RPB = 256 / C;
    float s = 0.f, s2 = 0.f;
    for (int r = blockIdx.x * RPB + rr; r < n; r += gridDim.x * RPB) {
        float v = x[(size_t)r * C + c];
        s += v;
        s2 += v * v;
    }
    __shared__ float ls[256], ls2[256];
    ls[t] = s;
    ls2[t] = s2;
    __syncthreads();
    if (rr == 0) {
        for (int j = 1; j < RPB; j++) { s += ls[j * C + c]; s2 += ls2[j * C + c]; }
        partials[(size_t)blockIdx.x * 2 * C + c] = s;
        partials[(size_t)blockIdx.x * 2 * C + C + c] = s2;
    }
}
// ---------------- BN stats stage 2: produce affine A,B ----------------
__global__ void k_stats2(const float* __restrict__ partials, const float* __restrict__ gamma,
                         const float* __restrict__ beta, float* __restrict__ AB,
                         int n, int C, int nb) {
    int c = threadIdx.x;
    if (c >= C) return;
    float s = 0.f, s2 = 0.f;
    for (int b = 0; b < nb; b++) {
        s += partials[(size_t)b * 2 * C + c];
        s2 += partials[(size_t)b * 2 * C + C + c];
    }
    float mu = s / n;
    float var = s2 / n - mu * mu;
    float inv = rsqrtf(var + BN_EPS);
    float A = gamma[c] * inv;
    AB[c] = A;
    AB[C + c] = beta[c] - mu * A;
}

// ---------------- node transform layer 2: BN+ELU then @ W2, attn logits ----------------
__global__ void k_node2(const float* __restrict__ hin, const float* __restrict__ AB1,
                        const float* __restrict__ W2, const float* __restrict__ as2,
                        const float* __restrict__ ad2, float* __restrict__ h2,
                        float* __restrict__ als2, float* __restrict__ ald2, int n) {
    __shared__ float sy[64 * 129];
    __shared__ float sw[128 * 32];
    int t = threadIdx.x;
    for (int i = t; i < 128 * 32; i += 256) sw[i] = W2[i];
    int base = blockIdx.x * 64;
    for (int i = t; i < 64 * 128; i += 256) {
        int r = i >> 7, c = i & 127;
        float v = 0.f;
        if (base + r < n) {
            float xx = hin[(size_t)(base + r) * 128 + c];
            v = elu(xx * AB1[c] + AB1[128 + c]);
        }
        sy[r * 129 + c] = v;
    }
    __syncthreads();
    int node = t >> 2, q = t & 3;
    float acc[8];
#pragma unroll
    for (int d = 0; d < 8; d++) acc[d] = 0.f;
    for (int k = 0; k < 128; k++) {
        float y = sy[node * 129 + k];
#pragma unroll
        for (int d = 0; d < 8; d++) acc[d] += y * sw[k * 32 + q * 8 + d];
    }
    float ps = 0.f, pd = 0.f;
#pragma unroll
    for (int d = 0; d < 8; d++) {
        ps += acc[d] * as2[q * 8 + d];
        pd += acc[d] * ad2[q * 8 + d];
    }
    ps += __shfl_xor(ps, 1); ps += __shfl_xor(ps, 2);
    pd += __shfl_xor(pd, 1); pd += __shfl_xor(pd, 2);
    int g = base + node;
    if (g < n) {
#pragma unroll
        for (int d = 0; d < 8; d++) h2[(size_t)g * 32 + q * 8 + d] = acc[d];
        if (q == 0) { als2[g] = ps; ald2[g] = pd; }
    }
}

// ---------------- layer 2 aggregation: wave per dst node, 1 head x 32 ----------------
__global__ void k_agg2(const float* __restrict__ h2, const float* __restrict__ als2,
                       const float* __restrict__ ald2, const int* __restrict__ rp,
                       const int* __restrict__ esrc, const float* __restrict__ b2,
                       float* __restrict__ out, int n) {
    int wid = (blockIdx.x * blockDim.x + threadIdx.x) >> 6;
    int lane = threadIdx.x & 63;
    if (wid >= n) return;
    int beg = rp[wid], end = rp[wid + 1];
    float ad = ald2[wid];
    int half = lane >> 5, f = lane & 31;
    float m = -1e30f;
    for (int i = beg + half; i < end; i += 2) {
        m = fmaxf(m, lrelu(als2[esrc[i]] + ad));
    }
    m = fmaxf(m, __shfl_xor(m, 32));
    float z = 0.f, acc = 0.f;
    for (int i = beg + half; i < end; i += 2) {
        int s = esrc[i];
        float w = __expf(lrelu(als2[s] + ad) - m);
        z += w;
        acc += w * h2[(size_t)s * 32 + f];
    }
    z += __shfl_xor(z, 32);
    acc += __shfl_xor(acc, 32);
    if (lane < 32) out[(size_t)wid * 32 + f] = acc / (z + 1e-16f) + b2[f];
}

// ---------------- graph boundaries via binary search on sorted batch ----------------
__global__ void k_bounds(const int* __restrict__ batch, int* __restrict__ bnd, int n, int g) {
    int i = blockIdx.x * blockDim.x + threadIdx.x;
    if (i > g) return;
    if (i == g) { bnd[g] = n; return; }
    int lo = 0, hi = n;
    while (lo < hi) {
        int mid = (lo + hi) >> 1;
        if (batch[mid] < i) lo = mid + 1; else hi = mid;
    }
    bnd[i] = lo;
}

// ---------------- BN2+ELU + mean pool + classifier: wave per graph ----------------
__global__ void k_pool(const float* __restrict__ x, const float* __restrict__ AB2,
                       const int* __restrict__ bnd, const float* __restrict__ Wc,
                       const float* __restrict__ bc, float* __restrict__ out, int G_) {
    int wid = (blockIdx.x * blockDim.x + threadIdx.x) >> 6;
    int lane = threadIdx.x & 63;
    if (wid >= G_) return;
    int beg = bnd[wid], end = bnd[wid + 1];
    int half = lane >> 5, f = lane & 31;
    float A = AB2[f], B = AB2[32 + f];
    float acc = 0.f;
    for (int r = beg + half; r < end; r += 2) {
        float v = x[(size_t)r * 32 + f] * A + B;
        acc += elu(v);
    }
    acc += __shfl_xor(acc, 32);
    float cntf = (float)((end - beg) > 1 ? (end - beg) : 1);
    float embv = acc / cntf;
    float p0 = embv * Wc[f * 2], p1 = embv * Wc[f * 2 + 1];
#pragma unroll
    for (int o = 1; o < 32; o <<= 1) {
        p0 += __shfl_xor(p0, o);
        p1 += __shfl_xor(p1, o);
    }
    if (lane == 0) {
        out[wid * 2] = p0 + bc[0];
        out[wid * 2 + 1] = p1 + bc[1];
    }
}

extern "C" void kernel_launch(void* const* d_in, const int* in_sizes, int n_in,
                              void* d_out, int out_size, void* d_ws, size_t ws_size,
                              hipStream_t stream) {
    const float* x = (const float*)d_in[0];
    const int* ei = (const int*)d_in[1];
    const int* batch = (const int*)d_in[2];
    const float* W1 = (const float*)d_in[3];
    const float* as1 = (const float*)d_in[4];
    const float* ad1 = (const float*)d_in[5];
    const float* b1 = (const float*)d_in[6];
    const float* g1 = (const float*)d_in[7];
    const float* be1 = (const float*)d_in[8];
    const float* W2 = (const float*)d_in[9];
    const float* as2 = (const float*)d_in[10];
    const float* ad2 = (const float*)d_in[11];
    const float* b2 = (const float*)d_in[12];
    const float* g2 = (const float*)d_in[13];
    const float* be2 = (const float*)d_in[14];
    const float* Wc = (const float*)d_in[15];
    const float* bc = (const float*)d_in[16];
    float* out = (float*)d_out;

    const int N = in_sizes[0] / 2;
    const int E = in_sizes[1] / 2;
    const int G = out_size / 2;
    const int Etot = E + N;
    const int NB = (N + 255) / 256;  // scan blocks

    // workspace layout
    char* w = (char*)d_ws;
    size_t off = 0;
    auto alloc = [&](size_t bytes) { void* p = w + off; off = (off + bytes + 255) & ~(size_t)255; return p; };
    float* h1 = (float*)alloc((size_t)N * 128 * 4);
    float* h_ag1 = (float*)alloc((size_t)N * 128 * 4);
    float* als1 = (float*)alloc((size_t)N * 4 * 4);
    float* ald1 = (float*)alloc((size_t)N * 4 * 4);
    int* esrc = (int*)alloc((size_t)Etot * 4);
    int* cnt = (int*)alloc((size_t)N * 4);
    int* incl = (int*)alloc((size_t)N * 4);
    int* rp = (int*)alloc((size_t)(N + 1) * 4);
    int* pos = (int*)alloc((size_t)N * 4);
    int* blksum = (int*)alloc((size_t)NB * 4);
    float* partials = (float*)alloc((size_t)STATS_BLOCKS * 256 * 4);
    float* AB1 = (float*)alloc(256 * 4);
    float* AB2 = (float*)alloc(64 * 4);
    int* bnd = (int*)alloc((size_t)(G + 1) * 4);
    // reuse h1's space after layer-1 aggregation:
    float* h2 = h1;                                   // N*32 floats
    float* als2 = h1 + (size_t)N * 32;                // N floats
    float* ald2 = h1 + (size_t)N * 33;                // N floats
    float* out2 = h1 + (size_t)N * 34;                // N*32 floats

    // 1. zero counts
    k_zero<<<(N + 255) / 256, 256, 0, stream>>>(cnt, N);
    // 2. node transform layer 1
    k_node1<<<(N * 4 + 255) / 256, 256, 0, stream>>>(x, W1, as1, ad1, h1, als1, ald1, N);
    // 3. degree count
    k_count<<<(Etot + 255) / 256, 256, 0, stream>>>(ei, cnt, E, N);
    // 4. scan
    k_scan1<<<NB, 256, 0, stream>>>(cnt, incl, blksum, N);
    k_scan2<<<1, 64, 0, stream>>>(blksum, NB);
    k_scan3<<<(N + 255) / 256, 256, 0, stream>>>(cnt, incl, blksum, rp, pos, N);
    // 5. scatter
    k_scatter<<<(Etot + 255) / 256, 256, 0, stream>>>(ei, pos, esrc, E, N);
    // 6. layer 1 aggregation (wave per node)
    k_agg1<<<(N * 64 + 255) / 256, 256, 0, stream>>>(h1, als1, ald1, rp, esrc, b1, h_ag1, N);
    // 7. BN1 stats
    k_stats<<<STATS_BLOCKS, 256, 0, stream>>>(h_ag1, partials, N, 128);
    k_stats2<<<1, 128, 0, stream>>>(partials, g1, be1, AB1, N, 128, STATS_BLOCKS);
    // 8. node transform layer 2 (BN+ELU fused)
    k_node2<<<(N + 63) / 64, 256, 0, stream>>>(h_ag1, AB1, W2, as2, ad2, h2, als2, ald2, N);
    // 9. layer 2 aggregation
    k_agg2<<<(N * 64 + 255) / 256, 256, 0, stream>>>(h2, als2, ald2, rp, esrc, b2, out2, N);
    // 10. BN2 stats
    k_stats<<<STATS_BLOCKS, 256, 0, stream>>>(out2, partials, N, 32);
    k_stats2<<<1, 32, 0, stream>>>(partials, g2, be2, AB2, N, 32, STATS_BLOCKS);
    // 11. graph boundaries
    k_bounds<<<(G + 256) / 256, 256, 0, stream>>>(batch, bnd, N, G);
    // 12. BN2+ELU + pool + classifier
    k_pool<<<(G * 64 + 255) / 256, 256, 0, stream>>>(out2, AB2, bnd, Wc, bc, out, G);
}

// Round 2
// 826.859 us; speedup vs baseline: 1.3925x; 1.3925x over previous
//
#include <hip/hip_runtime.h>
#include <hip/hip_bf16.h>
#include <math.h>

#define HEADS 4
#define HID 32
#define EMB 32
#define SLOPE 0.2f
#define BN_EPS 1e-5f
#define STATS_BLOCKS 512

__device__ __forceinline__ float lrelu(float x) { return x > 0.f ? x : SLOPE * x; }
__device__ __forceinline__ float elu(float x) { return x > 0.f ? x : expm1f(x); }

// ---------------- zero int buffer ----------------
__global__ void k_zero(int* p, int n) {
    int i = blockIdx.x * blockDim.x + threadIdx.x;
    if (i < n) p[i] = 0;
}

// ---------------- node transform layer 1: h1 = x @ W1 ; al_src/al_dst ----------------
__global__ void k_node1(const float* __restrict__ x, const float* __restrict__ W1,
                        const float* __restrict__ as1, const float* __restrict__ ad1,
                        float* __restrict__ h1, float* __restrict__ als, float* __restrict__ ald,
                        int n) {
    int idx = blockIdx.x * blockDim.x + threadIdx.x;
    int node = idx >> 2, hd = idx & 3;
    if (node >= n) return;
    float x0 = x[node * 2], x1 = x[node * 2 + 1];
    float ps = 0.f, pd = 0.f;
#pragma unroll
    for (int d = 0; d < 32; d++) {
        int c = hd * 32 + d;
        float v = x0 * W1[c] + x1 * W1[128 + c];
        h1[node * 128 + c] = v;
        ps += v * as1[c];
        pd += v * ad1[c];
    }
    als[node * 4 + hd] = ps;
    ald[node * 4 + hd] = pd;
}

// ---------------- degree count (dst, incl self loops) ----------------
__global__ void k_count(const int* __restrict__ ei, int* __restrict__ cnt, int E_, int N_) {
    int e = blockIdx.x * blockDim.x + threadIdx.x;
    if (e >= E_ + N_) return;
    int d = (e < E_) ? ei[E_ + e] : (e - E_);
    atomicAdd(&cnt[d], 1);
}

// ---------------- scan (3 stages) ----------------
__global__ void k_scan1(const int* __restrict__ cnt, int* __restrict__ incl,
                        int* __restrict__ blksum, int n) {
    __shared__ int s[256];
    int t = threadIdx.x, i = blockIdx.x * 256 + t;
    int v = (i < n) ? cnt[i] : 0;
    s[t] = v;
    __syncthreads();
    for (int off = 1; off < 256; off <<= 1) {
        int a = (t >= off) ? s[t - off] : 0;
        __syncthreads();
        s[t] += a;
        __syncthreads();
    }
    if (i < n) incl[i] = s[t];
    if (t == 255) blksum[blockIdx.x] = s[255];
}
// parallel scan of block sums (supports nb <= 1024)
__global__ void k_scan2(int* blksum, int nb) {
    __shared__ int s[1024];
    int t = threadIdx.x;
    int v = (t < nb) ? blksum[t] : 0;
    s[t] = v;
    __syncthreads();
    for (int off = 1; off < 1024; off <<= 1) {
        int a = (t >= off) ? s[t - off] : 0;
        __syncthreads();
        s[t] += a;
        __syncthreads();
    }
    if (t < nb) blksum[t] = s[t] - v;  // exclusive
}
__global__ void k_scan3(const int* __restrict__ cnt, const int* __restrict__ incl,
                        const int* __restrict__ blksum, int* __restrict__ rp,
                        int* __restrict__ pos, int n) {
    int i = blockIdx.x * blockDim.x + threadIdx.x;
    if (i >= n) return;
    int excl = incl[i] - cnt[i] + blksum[i >> 8];
    rp[i] = excl;
    pos[i] = excl;
    if (i == n - 1) rp[n] = incl[i] + blksum[i >> 8];
}

// ---------------- scatter edges into CSR (store src only) ----------------
__global__ void k_scatter(const int* __restrict__ ei, int* __restrict__ pos,
                          int* __restrict__ esrc, int E_, int N_) {
    int e = blockIdx.x * blockDim.x + threadIdx.x;
    if (e >= E_ + N_) return;
    int s, d;
    if (e < E_) { s = ei[e]; d = ei[E_ + e]; } else { s = d = e - E_; }
    int p = atomicAdd(&pos[d], 1);
    esrc[p] = s;
}

// ---------------- layer 1 aggregation: wave per dst node, LDS-staged weights ----------------
// No max pass: logits are O(1) here so exp() cannot overflow; softmax is shift-invariant.
__global__ void __launch_bounds__(256) k_agg1(
        const float* __restrict__ h1, const float* __restrict__ als1,
        const float* __restrict__ ald1, const int* __restrict__ rp,
        const int* __restrict__ esrc, const float* __restrict__ b1,
        float* __restrict__ out, int n) {
    __shared__ int ss[4][64];
    __shared__ float sw[4][256];  // head-major: [h*64 + edge]
    int wslot = threadIdx.x >> 6;
    int lane = threadIdx.x & 63;
    int wid = blockIdx.x * 4 + wslot;
    if (wid >= n) return;
    int beg = rp[wid], end = rp[wid + 1];
    const float4 ad = *reinterpret_cast<const float4*>(&ald1[wid * 4]);
    bool lo = lane < 32;
    int ha = lo ? 0 : 1, hb = lo ? 2 : 3;  // heads this lane accumulates
    float acc0 = 0.f, acc1 = 0.f, za = 0.f, zb = 0.f;
    for (int cb = beg; cb < end; cb += 64) {
        int cnt = end - cb;
        if (cnt > 64) cnt = 64;
        if (lane < cnt) {
            int s = esrc[cb + lane];
            const float4 a = *reinterpret_cast<const float4*>(&als1[s * 4]);
            ss[wslot][lane] = s;
            sw[wslot][lane] = __expf(lrelu(a.x + ad.x));
            sw[wslot][64 + lane] = __expf(lrelu(a.y + ad.y));
            sw[wslot][128 + lane] = __expf(lrelu(a.z + ad.z));
            sw[wslot][192 + lane] = __expf(lrelu(a.w + ad.w));
        }
        // wave-private LDS slot: in-wave lgkmcnt ordering suffices, no barrier
        // (waves in this block have different trip counts -> __syncthreads would hang)
        for (int j = 0; j < cnt; j++) {
            int s = ss[wslot][j];
            float wa = sw[wslot][ha * 64 + j];
            float wb = sw[wslot][hb * 64 + j];
            za += wa;
            zb += wb;
            const float* hr = &h1[(size_t)s * 128];
            acc0 = fmaf(wa, hr[lane], acc0);
            acc1 = fmaf(wb, hr[64 + lane], acc1);
        }
    }
    out[(size_t)wid * 128 + lane] = acc0 / (za + 1e-16f) + b1[lane];
    out[(size_t)wid * 128 + 64 + lane] = acc1 / (zb + 1e-16f) + b1[64 + lane];
}

// ---------------- BN stats: stage 1 (deterministic tree) ----------------
__global__ void k_stats(const float* __restrict__ x, float* __restrict__ partials,
                        int n, int C) {
    int t = threadIdx.x;
    int c = t & (C - 1);
    int rr = t / C;
    int RPB = 256 / C;
    float s = 0.f, s2 = 0.f;
    for (int r = blockIdx.x * RPB + rr; r < n; r += gridDim.x * RPB) {
        float v = x[(size_t)r * C + c];
        s += v;
        s2 += v * v;
    }
    __shared__ float ls[256], ls2[256];
    ls[t] = s;
    ls2[t] = s2;
    __syncthreads();
    if (rr == 0) {
        for (int j = 1; j < RPB; j++) { s += ls[j * C + c]; s2 += ls2[j * C + c]; }
        partials[(size_t)blockIdx.x * 2 * C + c] = s;
        partials[(size_t)blockIdx.x * 2 * C + C + c] = s2;
    }
}
// ---------------- BN stats stage 2: produce affine A,B ----------------
__global__ void k_stats2(const float* __restrict__ partials, const float* __restrict__ gamma,
                         const float* __restrict__ beta, float* __restrict__ AB,
                         int n, int C, int nb) {
    int c = threadIdx.x;
    if (c >= C) return;
    float s = 0.f, s2 = 0.f;
    for (int b = 0; b < nb; b++) {
        s += partials[(size_t)b * 2 * C + c];
        s2 += partials[(size_t)b * 2 * C + C + c];
    }
    float mu = s / n;
    float var = s2 / n - mu * mu;
    float inv = rsqrtf(var + BN_EPS);
    float A = gamma[c] * inv;
    AB[c] = A;
    AB[C + c] = beta[c] - mu * A;
}

// ---------------- node transform layer 2: BN+ELU then @ W2, attn logits ----------------
__global__ void k_node2(const float* __restrict__ hin, const float* __restrict__ AB1,
                        const float* __restrict__ W2, const float* __restrict__ as2,
                        const float* __restrict__ ad2, float* __restrict__ h2,
                        float* __restrict__ als2, float* __restrict__ ald2, int n) {
    __shared__ float sy[64 * 129];
    __shared__ float sw[128 * 32];
    int t = threadIdx.x;
    for (int i = t; i < 128 * 32; i += 256) sw[i] = W2[i];
    int base = blockIdx.x * 64;
    for (int i = t; i < 64 * 128; i += 256) {
        int r = i >> 7, c = i & 127;
        float v = 0.f;
        if (base + r < n) {
            float xx = hin[(size_t)(base + r) * 128 + c];
            v = elu(xx * AB1[c] + AB1[128 + c]);
        }
        sy[r * 129 + c] = v;
    }
    __syncthreads();
    int node = t >> 2, q = t & 3;
    float acc[8];
#pragma unroll
    for (int d = 0; d < 8; d++) acc[d] = 0.f;
    for (int k = 0; k < 128; k++) {
        float y = sy[node * 129 + k];
#pragma unroll
        for (int d = 0; d < 8; d++) acc[d] += y * sw[k * 32 + q * 8 + d];
    }
    float ps = 0.f, pd = 0.f;
#pragma unroll
    for (int d = 0; d < 8; d++) {
        ps += acc[d] * as2[q * 8 + d];
        pd += acc[d] * ad2[q * 8 + d];
    }
    ps += __shfl_xor(ps, 1); ps += __shfl_xor(ps, 2);
    pd += __shfl_xor(pd, 1); pd += __shfl_xor(pd, 2);
    int g = base + node;
    if (g < n) {
#pragma unroll
        for (int d = 0; d < 8; d++) h2[(size_t)g * 32 + q * 8 + d] = acc[d];
        if (q == 0) { als2[g] = ps; ald2[g] = pd; }
    }
}

// ---------------- layer 2 aggregation: wave per dst node, LDS-staged weights ----------------
__global__ void __launch_bounds__(256) k_agg2(
        const float* __restrict__ h2, const float* __restrict__ als2,
        const float* __restrict__ ald2, const int* __restrict__ rp,
        const int* __restrict__ esrc, const float* __restrict__ b2,
        float* __restrict__ out, int n) {
    __shared__ int ss[4][64];
    __shared__ float sw[4][64];
    int wslot = threadIdx.x >> 6;
    int lane = threadIdx.x & 63;
    int wid = blockIdx.x * 4 + wslot;
    if (wid >= n) return;
    int beg = rp[wid], end = rp[wid + 1];
    float ad = ald2[wid];
    int half = lane >> 5, f = lane & 31;
    float acc = 0.f, z = 0.f;
    for (int cb = beg; cb < end; cb += 64) {
        int cnt = end - cb;
        if (cnt > 64) cnt = 64;
        if (lane < cnt) {
            int s = esrc[cb + lane];
            ss[wslot][lane] = s;
            sw[wslot][lane] = __expf(lrelu(als2[s] + ad));
        }
        for (int j = half; j < cnt; j += 2) {
            int s = ss[wslot][j];
            float w = sw[wslot][j];
            z += w;
            acc = fmaf(w, h2[(size_t)s * 32 + f], acc);
        }
    }
    z += __shfl_xor(z, 32);
    acc += __shfl_xor(acc, 32);
    if (lane < 32) out[(size_t)wid * 32 + f] = acc / (z + 1e-16f) + b2[f];
}

// ---------------- graph boundaries via binary search on sorted batch ----------------
__global__ void k_bounds(const int* __restrict__ batch, int* __restrict__ bnd, int n, int g) {
    int i = blockIdx.x * blockDim.x + threadIdx.x;
    if (i > g) return;
    if (i == g) { bnd[g] = n; return; }
    int lo = 0, hi = n;
    while (lo < hi) {
        int mid = (lo + hi) >> 1;
        if (batch[mid] < i) lo = mid + 1; else hi = mid;
    }
    bnd[i] = lo;
}

// ---------------- BN2+ELU + mean pool + classifier: wave per graph ----------------
__global__ void k_pool(const float* __restrict__ x, const float* __restrict__ AB2,
                       const int* __restrict__ bnd, const float* __restrict__ Wc,
                       const float* __restrict__ bc, float* __restrict__ out, int G_) {
    int wid = (blockIdx.x * blockDim.x + threadIdx.x) >> 6;
    int lane = threadIdx.x & 63;
    if (wid >= G_) return;
    int beg = bnd[wid], end = bnd[wid + 1];
    int half = lane >> 5, f = lane & 31;
    float A = AB2[f], B = AB2[32 + f];
    float acc = 0.f;
    for (int r = beg + half; r < end; r += 2) {
        float v = x[(size_t)r * 32 + f] * A + B;
        acc += elu(v);
    }
    acc += __shfl_xor(acc, 32);
    float cntf = (float)((end - beg) > 1 ? (end - beg) : 1);
    float embv = acc / cntf;
    float p0 = embv * Wc[f * 2], p1 = embv * Wc[f * 2 + 1];
#pragma unroll
    for (int o = 1; o < 32; o <<= 1) {
        p0 += __shfl_xor(p0, o);
        p1 += __shfl_xor(p1, o);
    }
    if (lane == 0) {
        out[wid * 2] = p0 + bc[0];
        out[wid * 2 + 1] = p1 + bc[1];
    }
}

extern "C" void kernel_launch(void* const* d_in, const int* in_sizes, int n_in,
                              void* d_out, int out_size, void* d_ws, size_t ws_size,
                              hipStream_t stream) {
    const float* x = (const float*)d_in[0];
    const int* ei = (const int*)d_in[1];
    const int* batch = (const int*)d_in[2];
    const float* W1 = (const float*)d_in[3];
    const float* as1 = (const float*)d_in[4];
    const float* ad1 = (const float*)d_in[5];
    const float* b1 = (const float*)d_in[6];
    const float* g1 = (const float*)d_in[7];
    const float* be1 = (const float*)d_in[8];
    const float* W2 = (const float*)d_in[9];
    const float* as2 = (const float*)d_in[10];
    const float* ad2 = (const float*)d_in[11];
    const float* b2 = (const float*)d_in[12];
    const float* g2 = (const float*)d_in[13];
    const float* be2 = (const float*)d_in[14];
    const float* Wc = (const float*)d_in[15];
    const float* bc = (const float*)d_in[16];
    float* out = (float*)d_out;

    const int N = in_sizes[0] / 2;
    const int E = in_sizes[1] / 2;
    const int G = out_size / 2;
    const int Etot = E + N;
    const int NB = (N + 255) / 256;  // scan blocks (must be <= 1024)

    // workspace layout
    char* w = (char*)d_ws;
    size_t off = 0;
    auto alloc = [&](size_t bytes) { void* p = w + off; off = (off + bytes + 255) & ~(size_t)255; return p; };
    float* h1 = (float*)alloc((size_t)N * 128 * 4);
    float* h_ag1 = (float*)alloc((size_t)N * 128 * 4);
    float* als1 = (float*)alloc((size_t)N * 4 * 4);
    float* ald1 = (float*)alloc((size_t)N * 4 * 4);
    int* esrc = (int*)alloc((size_t)Etot * 4);
    int* cnt = (int*)alloc((size_t)N * 4);
    int* incl = (int*)alloc((size_t)N * 4);
    int* rp = (int*)alloc((size_t)(N + 1) * 4);
    int* pos = (int*)alloc((size_t)N * 4);
    int* blksum = (int*)alloc((size_t)NB * 4);
    float* partials = (float*)alloc((size_t)STATS_BLOCKS * 256 * 4);
    float* AB1 = (float*)alloc(256 * 4);
    float* AB2 = (float*)alloc(64 * 4);
    int* bnd = (int*)alloc((size_t)(G + 1) * 4);
    // reuse h1's space after layer-1 aggregation:
    float* h2 = h1;                                   // N*32 floats
    float* als2 = h1 + (size_t)N * 32;                // N floats
    float* ald2 = h1 + (size_t)N * 33;                // N floats
    float* out2 = h1 + (size_t)N * 34;                // N*32 floats

    // 1. zero counts
    k_zero<<<(N + 255) / 256, 256, 0, stream>>>(cnt, N);
    // 2. node transform layer 1
    k_node1<<<(N * 4 + 255) / 256, 256, 0, stream>>>(x, W1, as1, ad1, h1, als1, ald1, N);
    // 3. degree count
    k_count<<<(Etot + 255) / 256, 256, 0, stream>>>(ei, cnt, E, N);
    // 4. scan
    k_scan1<<<NB, 256, 0, stream>>>(cnt, incl, blksum, N);
    k_scan2<<<1, 1024, 0, stream>>>(blksum, NB);
    k_scan3<<<(N + 255) / 256, 256, 0, stream>>>(cnt, incl, blksum, rp, pos, N);
    // 5. scatter
    k_scatter<<<(Etot + 255) / 256, 256, 0, stream>>>(ei, pos, esrc, E, N);
    // 6. layer 1 aggregation (wave per node)
    k_agg1<<<(N + 3) / 4, 256, 0, stream>>>(h1, als1, ald1, rp, esrc, b1, h_ag1, N);
    // 7. BN1 stats
    k_stats<<<STATS_BLOCKS, 256, 0, stream>>>(h_ag1, partials, N, 128);
    k_stats2<<<1, 128, 0, stream>>>(partials, g1, be1, AB1, N, 128, STATS_BLOCKS);
    // 8. node transform layer 2 (BN+ELU fused)
    k_node2<<<(N + 63) / 64, 256, 0, stream>>>(h_ag1, AB1, W2, as2, ad2, h2, als2, ald2, N);
    // 9. layer 2 aggregation
    k_agg2<<<(N + 3) / 4, 256, 0, stream>>>(h2, als2, ald2, rp, esrc, b2, out2, N);
    // 10. BN2 stats
    k_stats<<<STATS_BLOCKS, 256, 0, stream>>>(out2, partials, N, 32);
    k_stats2<<<1, 32, 0, stream>>>(partials, g2, be2, AB2, N, 32, STATS_BLOCKS);
    // 11. graph boundaries
    k_bounds<<<(G + 256) / 256, 256, 0, stream>>>(batch, bnd, N, G);
    // 12. BN2+ELU + pool + classifier
    k_pool<<<(G * 64 + 255) / 256, 256, 0, stream>>>(out2, AB2, bnd, Wc, bc, out, G);
}

// Round 3
// 759.734 us; speedup vs baseline: 1.5155x; 1.0884x over previous
//
#include <hip/hip_runtime.h>
#include <hip/hip_bf16.h>
#include <math.h>

#define HEADS 4
#define HID 32
#define EMB 32
#define SLOPE 0.2f
#define BN_EPS 1e-5f
#define STATS_BLOCKS 512

__device__ __forceinline__ float lrelu(float x) { return x > 0.f ? x : SLOPE * x; }
__device__ __forceinline__ float elu(float x) { return x > 0.f ? x : expm1f(x); }

// RNE float->bf16 and pack/unpack helpers
__device__ __forceinline__ unsigned f2bf_pack(float a, float b) {
    unsigned ua = __float_as_uint(a);
    unsigned ub = __float_as_uint(b);
    unsigned ra = (ua + 0x7fffu + ((ua >> 16) & 1u)) >> 16;
    unsigned rb = (ub + 0x7fffu + ((ub >> 16) & 1u)) >> 16;
    return ra | (rb << 16);
}
__device__ __forceinline__ float bf_lo(unsigned p) { return __uint_as_float(p << 16); }
__device__ __forceinline__ float bf_hi(unsigned p) { return __uint_as_float(p & 0xffff0000u); }

// ---------------- zero int buffer ----------------
__global__ void k_zero(int* p, int n) {
    int i = blockIdx.x * blockDim.x + threadIdx.x;
    if (i < n) p[i] = 0;
}

// ---------------- node transform layer 1: h1 = x @ W1 (packed bf16); al_src/al_dst ----------------
__global__ void k_node1(const float* __restrict__ x, const float* __restrict__ W1,
                        const float* __restrict__ as1, const float* __restrict__ ad1,
                        unsigned* __restrict__ h1bf, float* __restrict__ als, float* __restrict__ ald,
                        int n) {
    int idx = blockIdx.x * blockDim.x + threadIdx.x;
    int node = idx >> 2, hd = idx & 3;
    if (node >= n) return;
    float x0 = x[node * 2], x1 = x[node * 2 + 1];
    float ps = 0.f, pd = 0.f;
#pragma unroll
    for (int d = 0; d < 32; d += 2) {
        int c = hd * 32 + d;
        float v0 = x0 * W1[c] + x1 * W1[128 + c];
        float v1 = x0 * W1[c + 1] + x1 * W1[128 + c + 1];
        ps += v0 * as1[c] + v1 * as1[c + 1];
        pd += v0 * ad1[c] + v1 * ad1[c + 1];
        h1bf[(size_t)node * 64 + hd * 16 + (d >> 1)] = f2bf_pack(v0, v1);
    }
    als[node * 4 + hd] = ps;
    ald[node * 4 + hd] = pd;
}

// ---------------- degree count (dst, incl self loops) ----------------
__global__ void k_count(const int* __restrict__ ei, int* __restrict__ cnt, int E_, int N_) {
    int e = blockIdx.x * blockDim.x + threadIdx.x;
    if (e >= E_ + N_) return;
    int d = (e < E_) ? ei[E_ + e] : (e - E_);
    atomicAdd(&cnt[d], 1);
}

// ---------------- scan (3 stages) ----------------
__global__ void k_scan1(const int* __restrict__ cnt, int* __restrict__ incl,
                        int* __restrict__ blksum, int n) {
    __shared__ int s[256];
    int t = threadIdx.x, i = blockIdx.x * 256 + t;
    int v = (i < n) ? cnt[i] : 0;
    s[t] = v;
    __syncthreads();
    for (int off = 1; off < 256; off <<= 1) {
        int a = (t >= off) ? s[t - off] : 0;
        __syncthreads();
        s[t] += a;
        __syncthreads();
    }
    if (i < n) incl[i] = s[t];
    if (t == 255) blksum[blockIdx.x] = s[255];
}
__global__ void k_scan2(int* blksum, int nb) {
    __shared__ int s[1024];
    int t = threadIdx.x;
    int v = (t < nb) ? blksum[t] : 0;
    s[t] = v;
    __syncthreads();
    for (int off = 1; off < 1024; off <<= 1) {
        int a = (t >= off) ? s[t - off] : 0;
        __syncthreads();
        s[t] += a;
        __syncthreads();
    }
    if (t < nb) blksum[t] = s[t] - v;  // exclusive
}
__global__ void k_scan3(const int* __restrict__ cnt, const int* __restrict__ incl,
                        const int* __restrict__ blksum, int* __restrict__ rp,
                        int* __restrict__ pos, int n) {
    int i = blockIdx.x * blockDim.x + threadIdx.x;
    if (i >= n) return;
    int excl = incl[i] - cnt[i] + blksum[i >> 8];
    rp[i] = excl;
    pos[i] = excl;
    if (i == n - 1) rp[n] = incl[i] + blksum[i >> 8];
}

// ---------------- scatter edges into CSR (store src only) ----------------
__global__ void k_scatter(const int* __restrict__ ei, int* __restrict__ pos,
                          int* __restrict__ esrc, int E_, int N_) {
    int e = blockIdx.x * blockDim.x + threadIdx.x;
    if (e >= E_ + N_) return;
    int s, d;
    if (e < E_) { s = ei[e]; d = ei[E_ + e]; } else { s = d = e - E_; }
    int p = atomicAdd(&pos[d], 1);
    esrc[p] = s;
}

// ---------------- layer 1 aggregation: wave per dst node, bf16 gather (1 dword/lane/edge) ----
// No max pass: logits are O(1) here so exp() cannot overflow; softmax is shift-invariant.
__global__ void __launch_bounds__(256) k_agg1(
        const unsigned* __restrict__ h1bf, const float* __restrict__ als1,
        const float* __restrict__ ald1, const int* __restrict__ rp,
        const int* __restrict__ esrc, const float* __restrict__ b1,
        float* __restrict__ out, int n) {
    __shared__ int ss[4][64];
    __shared__ float sw[4][256];  // head-major: [h*64 + edge]
    int wslot = threadIdx.x >> 6;
    int lane = threadIdx.x & 63;
    int wid = blockIdx.x * 4 + wslot;
    if (wid >= n) return;
    int beg = rp[wid], end = rp[wid + 1];
    const float4 ad = *reinterpret_cast<const float4*>(&ald1[wid * 4]);
    int hd = lane >> 4;  // this lane's channels 2*lane,2*lane+1 belong to head lane/16
    float2 acc = make_float2(0.f, 0.f);
    float z = 0.f;
    for (int cb = beg; cb < end; cb += 64) {
        int cnt = end - cb;
        if (cnt > 64) cnt = 64;
        if (lane < cnt) {
            int s = esrc[cb + lane];
            const float4 a = *reinterpret_cast<const float4*>(&als1[s * 4]);
            ss[wslot][lane] = s;
            sw[wslot][lane] = __expf(lrelu(a.x + ad.x));
            sw[wslot][64 + lane] = __expf(lrelu(a.y + ad.y));
            sw[wslot][128 + lane] = __expf(lrelu(a.z + ad.z));
            sw[wslot][192 + lane] = __expf(lrelu(a.w + ad.w));
        }
        // wave-private LDS slot: in-wave lgkmcnt ordering suffices, no barrier
#pragma unroll 2
        for (int j = 0; j < cnt; j++) {
            int s = ss[wslot][j];
            float w = sw[wslot][hd * 64 + j];
            z += w;
            unsigned p = h1bf[(size_t)s * 64 + lane];
            acc.x = fmaf(w, bf_lo(p), acc.x);
            acc.y = fmaf(w, bf_hi(p), acc.y);
        }
    }
    float inv = 1.f / (z + 1e-16f);
    const float2 bv = *reinterpret_cast<const float2*>(&b1[2 * lane]);
    float2 o = make_float2(acc.x * inv + bv.x, acc.y * inv + bv.y);
    *reinterpret_cast<float2*>(&out[(size_t)wid * 128 + 2 * lane]) = o;
}

// ---------------- BN stats: stage 1 (deterministic tree) ----------------
__global__ void k_stats(const float* __restrict__ x, float* __restrict__ partials,
                        int n, int C) {
    int t = threadIdx.x;
    int c = t & (C - 1);
    int rr = t / C;
    int RPB = 256 / C;
    float s = 0.f, s2 = 0.f;
    for (int r = blockIdx.x * RPB + rr; r < n; r += gridDim.x * RPB) {
        float v = x[(size_t)r * C + c];
        s += v;
        s2 += v * v;
    }
    __shared__ float ls[256], ls2[256];
    ls[t] = s;
    ls2[t] = s2;
    __syncthreads();
    if (rr == 0) {
        for (int j = 1; j < RPB; j++) { s += ls[j * C + c]; s2 += ls2[j * C + c]; }
        partials[(size_t)blockIdx.x * 2 * C + c] = s;
        partials[(size_t)blockIdx.x * 2 * C + C + c] = s2;
    }
}
// ---------------- BN stats stage 2: produce affine A,B ----------------
__global__ void k_stats2(const float* __restrict__ partials, const float* __restrict__ gamma,
                         const float* __restrict__ beta, float* __restrict__ AB,
                         int n, int C, int nb) {
    int c = threadIdx.x;
    if (c >= C) return;
    float s = 0.f, s2 = 0.f;
    for (int b = 0; b < nb; b++) {
        s += partials[(size_t)b * 2 * C + c];
        s2 += partials[(size_t)b * 2 * C + C + c];
    }
    float mu = s / n;
    float var = s2 / n - mu * mu;
    float inv = rsqrtf(var + BN_EPS);
    float A = gamma[c] * inv;
    AB[c] = A;
    AB[C + c] = beta[c] - mu * A;
}

// ---------------- node transform layer 2: BN+ELU then @ W2 (bf16 out), attn logits --------
__global__ void k_node2(const float* __restrict__ hin, const float* __restrict__ AB1,
                        const float* __restrict__ W2, const float* __restrict__ as2,
                        const float* __restrict__ ad2, unsigned* __restrict__ h2bf,
                        float* __restrict__ als2, float* __restrict__ ald2, int n) {
    __shared__ float sy[64 * 129];
    __shared__ float sw[128 * 32];
    int t = threadIdx.x;
    for (int i = t; i < 128 * 32; i += 256) sw[i] = W2[i];
    int base = blockIdx.x * 64;
    for (int i = t; i < 64 * 128; i += 256) {
        int r = i >> 7, c = i & 127;
        float v = 0.f;
        if (base + r < n) {
            float xx = hin[(size_t)(base + r) * 128 + c];
            v = elu(xx * AB1[c] + AB1[128 + c]);
        }
        sy[r * 129 + c] = v;
    }
    __syncthreads();
    int node = t >> 2, q = t & 3;
    float acc[8];
#pragma unroll
    for (int d = 0; d < 8; d++) acc[d] = 0.f;
    for (int k = 0; k < 128; k++) {
        float y = sy[node * 129 + k];
#pragma unroll
        for (int d = 0; d < 8; d++) acc[d] += y * sw[k * 32 + q * 8 + d];
    }
    float ps = 0.f, pd = 0.f;
#pragma unroll
    for (int d = 0; d < 8; d++) {
        ps += acc[d] * as2[q * 8 + d];
        pd += acc[d] * ad2[q * 8 + d];
    }
    ps += __shfl_xor(ps, 1); ps += __shfl_xor(ps, 2);
    pd += __shfl_xor(pd, 1); pd += __shfl_xor(pd, 2);
    int g = base + node;
    if (g < n) {
#pragma unroll
        for (int d = 0; d < 8; d += 2)
            h2bf[(size_t)g * 16 + q * 4 + (d >> 1)] = f2bf_pack(acc[d], acc[d + 1]);
        if (q == 0) { als2[g] = ps; ald2[g] = pd; }
    }
}

// ---------------- layer 2 aggregation: wave per dst node, 4 edges/step, bf16 gather -------
__global__ void __launch_bounds__(256) k_agg2(
        const unsigned* __restrict__ h2bf, const float* __restrict__ als2,
        const float* __restrict__ ald2, const int* __restrict__ rp,
        const int* __restrict__ esrc, const float* __restrict__ b2,
        float* __restrict__ out, int n) {
    __shared__ int ss[4][64];
    __shared__ float sw[4][64];
    int wslot = threadIdx.x >> 6;
    int lane = threadIdx.x & 63;
    int wid = blockIdx.x * 4 + wslot;
    if (wid >= n) return;
    int beg = rp[wid], end = rp[wid + 1];
    float ad = ald2[wid];
    int eg = lane >> 4;      // edge subgroup 0..3
    int cp = lane & 15;      // channel pair: channels 2cp, 2cp+1
    float2 acc = make_float2(0.f, 0.f);
    float z = 0.f;
    for (int cb = beg; cb < end; cb += 64) {
        int cnt = end - cb;
        if (cnt > 64) cnt = 64;
        if (lane < cnt) {
            int s = esrc[cb + lane];
            ss[wslot][lane] = s;
            sw[wslot][lane] = __expf(lrelu(als2[s] + ad));
        }
        for (int j = eg; j < cnt; j += 4) {
            int s = ss[wslot][j];
            float w = sw[wslot][j];
            z += w;
            unsigned p = h2bf[(size_t)s * 16 + cp];
            acc.x = fmaf(w, bf_lo(p), acc.x);
            acc.y = fmaf(w, bf_hi(p), acc.y);
        }
    }
    // reduce across the 4 edge subgroups
    z += __shfl_xor(z, 16);   z += __shfl_xor(z, 32);
    acc.x += __shfl_xor(acc.x, 16); acc.x += __shfl_xor(acc.x, 32);
    acc.y += __shfl_xor(acc.y, 16); acc.y += __shfl_xor(acc.y, 32);
    if (lane < 16) {
        float inv = 1.f / (z + 1e-16f);
        const float2 bv = *reinterpret_cast<const float2*>(&b2[2 * cp]);
        float2 o = make_float2(acc.x * inv + bv.x, acc.y * inv + bv.y);
        *reinterpret_cast<float2*>(&out[(size_t)wid * 32 + 2 * cp]) = o;
    }
}

// ---------------- graph boundaries via binary search on sorted batch ----------------
__global__ void k_bounds(const int* __restrict__ batch, int* __restrict__ bnd, int n, int g) {
    int i = blockIdx.x * blockDim.x + threadIdx.x;
    if (i > g) return;
    if (i == g) { bnd[g] = n; return; }
    int lo = 0, hi = n;
    while (lo < hi) {
        int mid = (lo + hi) >> 1;
        if (batch[mid] < i) lo = mid + 1; else hi = mid;
    }
    bnd[i] = lo;
}

// ---------------- BN2+ELU + mean pool + classifier: wave per graph ----------------
__global__ void k_pool(const float* __restrict__ x, const float* __restrict__ AB2,
                       const int* __restrict__ bnd, const float* __restrict__ Wc,
                       const float* __restrict__ bc, float* __restrict__ out, int G_) {
    int wid = (blockIdx.x * blockDim.x + threadIdx.x) >> 6;
    int lane = threadIdx.x & 63;
    if (wid >= G_) return;
    int beg = bnd[wid], end = bnd[wid + 1];
    int half = lane >> 5, f = lane & 31;
    float A = AB2[f], B = AB2[32 + f];
    float acc = 0.f;
    for (int r = beg + half; r < end; r += 2) {
        float v = x[(size_t)r * 32 + f] * A + B;
        acc += elu(v);
    }
    acc += __shfl_xor(acc, 32);
    float cntf = (float)((end - beg) > 1 ? (end - beg) : 1);
    float embv = acc / cntf;
    float p0 = embv * Wc[f * 2], p1 = embv * Wc[f * 2 + 1];
#pragma unroll
    for (int o = 1; o < 32; o <<= 1) {
        p0 += __shfl_xor(p0, o);
        p1 += __shfl_xor(p1, o);
    }
    if (lane == 0) {
        out[wid * 2] = p0 + bc[0];
        out[wid * 2 + 1] = p1 + bc[1];
    }
}

extern "C" void kernel_launch(void* const* d_in, const int* in_sizes, int n_in,
                              void* d_out, int out_size, void* d_ws, size_t ws_size,
                              hipStream_t stream) {
    const float* x = (const float*)d_in[0];
    const int* ei = (const int*)d_in[1];
    const int* batch = (const int*)d_in[2];
    const float* W1 = (const float*)d_in[3];
    const float* as1 = (const float*)d_in[4];
    const float* ad1 = (const float*)d_in[5];
    const float* b1 = (const float*)d_in[6];
    const float* g1 = (const float*)d_in[7];
    const float* be1 = (const float*)d_in[8];
    const float* W2 = (const float*)d_in[9];
    const float* as2 = (const float*)d_in[10];
    const float* ad2 = (const float*)d_in[11];
    const float* b2 = (const float*)d_in[12];
    const float* g2 = (const float*)d_in[13];
    const float* be2 = (const float*)d_in[14];
    const float* Wc = (const float*)d_in[15];
    const float* bc = (const float*)d_in[16];
    float* out = (float*)d_out;

    const int N = in_sizes[0] / 2;
    const int E = in_sizes[1] / 2;
    const int G = out_size / 2;
    const int Etot = E + N;
    const int NB = (N + 255) / 256;  // scan blocks (must be <= 1024)

    // workspace layout
    char* w = (char*)d_ws;
    size_t off = 0;
    auto alloc = [&](size_t bytes) { void* p = w + off; off = (off + bytes + 255) & ~(size_t)255; return p; };
    unsigned* h1bf = (unsigned*)alloc((size_t)N * 64 * 4);   // N x 128 bf16 packed
    float* h_ag1 = (float*)alloc((size_t)N * 128 * 4);
    float* als1 = (float*)alloc((size_t)N * 4 * 4);
    float* ald1 = (float*)alloc((size_t)N * 4 * 4);
    int* esrc = (int*)alloc((size_t)Etot * 4);
    int* cnt = (int*)alloc((size_t)N * 4);
    int* incl = (int*)alloc((size_t)N * 4);
    int* rp = (int*)alloc((size_t)(N + 1) * 4);
    int* pos = (int*)alloc((size_t)N * 4);
    int* blksum = (int*)alloc((size_t)NB * 4);
    float* partials = (float*)alloc((size_t)STATS_BLOCKS * 256 * 4);
    float* AB1 = (float*)alloc(256 * 4);
    float* AB2 = (float*)alloc(64 * 4);
    int* bnd = (int*)alloc((size_t)(G + 1) * 4);
    // reuse h1bf's space after layer-1 aggregation (N*64 uints available):
    unsigned* h2bf = h1bf;                                   // N*16 uints (N x 32 bf16)
    float* als2 = (float*)(h1bf + (size_t)N * 16);           // N floats
    float* ald2 = (float*)(h1bf + (size_t)N * 17);           // N floats
    float* out2 = (float*)(h1bf + (size_t)N * 18);           // N*32 floats (ends at N*50)

    // 1. zero counts
    k_zero<<<(N + 255) / 256, 256, 0, stream>>>(cnt, N);
    // 2. node transform layer 1
    k_node1<<<(N * 4 + 255) / 256, 256, 0, stream>>>(x, W1, as1, ad1, h1bf, als1, ald1, N);
    // 3. degree count
    k_count<<<(Etot + 255) / 256, 256, 0, stream>>>(ei, cnt, E, N);
    // 4. scan
    k_scan1<<<NB, 256, 0, stream>>>(cnt, incl, blksum, N);
    k_scan2<<<1, 1024, 0, stream>>>(blksum, NB);
    k_scan3<<<(N + 255) / 256, 256, 0, stream>>>(cnt, incl, blksum, rp, pos, N);
    // 5. scatter
    k_scatter<<<(Etot + 255) / 256, 256, 0, stream>>>(ei, pos, esrc, E, N);
    // 6. layer 1 aggregation (wave per node)
    k_agg1<<<(N + 3) / 4, 256, 0, stream>>>(h1bf, als1, ald1, rp, esrc, b1, h_ag1, N);
    // 7. BN1 stats
    k_stats<<<STATS_BLOCKS, 256, 0, stream>>>(h_ag1, partials, N, 128);
    k_stats2<<<1, 128, 0, stream>>>(partials, g1, be1, AB1, N, 128, STATS_BLOCKS);
    // 8. node transform layer 2 (BN+ELU fused)
    k_node2<<<(N + 63) / 64, 256, 0, stream>>>(h_ag1, AB1, W2, as2, ad2, h2bf, als2, ald2, N);
    // 9. layer 2 aggregation
    k_agg2<<<(N + 3) / 4, 256, 0, stream>>>(h2bf, als2, ald2, rp, esrc, b2, out2, N);
    // 10. BN2 stats
    k_stats<<<STATS_BLOCKS, 256, 0, stream>>>(out2, partials, N, 32);
    k_stats2<<<1, 32, 0, stream>>>(partials, g2, be2, AB2, N, 32, STATS_BLOCKS);
    // 11. graph boundaries
    k_bounds<<<(G + 256) / 256, 256, 0, stream>>>(batch, bnd, N, G);
    // 12. BN2+ELU + pool + classifier
    k_pool<<<(G * 64 + 255) / 256, 256, 0, stream>>>(out2, AB2, bnd, Wc, bc, out, G);
}

// Round 4
// 567.382 us; speedup vs baseline: 2.0293x; 1.3390x over previous
//
#include <hip/hip_runtime.h>
#include <hip/hip_bf16.h>
#include <math.h>

#define HEADS 4
#define HID 32
#define EMB 32
#define SLOPE 0.2f
#define BN_EPS 1e-5f
#define STATS_BLOCKS 256

__device__ __forceinline__ float lrelu(float x) { return x > 0.f ? x : SLOPE * x; }
__device__ __forceinline__ float elu(float x) { return x > 0.f ? x : expm1f(x); }

// RNE float->bf16 and pack/unpack helpers
__device__ __forceinline__ unsigned f2bf_pack(float a, float b) {
    unsigned ua = __float_as_uint(a);
    unsigned ub = __float_as_uint(b);
    unsigned ra = (ua + 0x7fffu + ((ua >> 16) & 1u)) >> 16;
    unsigned rb = (ub + 0x7fffu + ((ub >> 16) & 1u)) >> 16;
    return ra | (rb << 16);
}
__device__ __forceinline__ float bf_lo(unsigned p) { return __uint_as_float(p << 16); }
__device__ __forceinline__ float bf_hi(unsigned p) { return __uint_as_float(p & 0xffff0000u); }

// ---------------- zero int buffer ----------------
__global__ void k_zero(int* p, int n) {
    int i = blockIdx.x * blockDim.x + threadIdx.x;
    if (i < n) p[i] = 0;
}

// ---------------- node transform layer 1: h1 = x @ W1 (packed bf16); al_src/al_dst ----------------
__global__ void k_node1(const float* __restrict__ x, const float* __restrict__ W1,
                        const float* __restrict__ as1, const float* __restrict__ ad1,
                        unsigned* __restrict__ h1bf, float* __restrict__ als, float* __restrict__ ald,
                        int n) {
    int idx = blockIdx.x * blockDim.x + threadIdx.x;
    int node = idx >> 2, hd = idx & 3;
    if (node >= n) return;
    float x0 = x[node * 2], x1 = x[node * 2 + 1];
    float ps = 0.f, pd = 0.f;
#pragma unroll
    for (int d = 0; d < 32; d += 2) {
        int c = hd * 32 + d;
        float v0 = x0 * W1[c] + x1 * W1[128 + c];
        float v1 = x0 * W1[c + 1] + x1 * W1[128 + c + 1];
        ps += v0 * as1[c] + v1 * as1[c + 1];
        pd += v0 * ad1[c] + v1 * ad1[c + 1];
        h1bf[(size_t)node * 64 + hd * 16 + (d >> 1)] = f2bf_pack(v0, v1);
    }
    als[node * 4 + hd] = ps;
    ald[node * 4 + hd] = pd;
}

// ---------------- degree count of REAL edges (self loops handled in scan) ----------------
__global__ void k_count(const int* __restrict__ ei, int* __restrict__ cnt, int E_) {
    int e = (blockIdx.x * blockDim.x + threadIdx.x) * 2;
    if (e >= E_) return;
    if (e + 1 < E_) {
        int2 d = *reinterpret_cast<const int2*>(&ei[E_ + e]);
        atomicAdd(&cnt[d.x], 1);
        atomicAdd(&cnt[d.y], 1);
    } else {
        atomicAdd(&cnt[ei[E_ + e]], 1);
    }
}

// ---------------- scan (3 stages); each node gets cnt+1 slots (self loop last) ----------------
__global__ void k_scan1(const int* __restrict__ cnt, int* __restrict__ incl,
                        int* __restrict__ blksum, int n) {
    __shared__ int s[256];
    int t = threadIdx.x, i = blockIdx.x * 256 + t;
    int v = (i < n) ? (cnt[i] + 1) : 0;
    s[t] = v;
    __syncthreads();
    for (int off = 1; off < 256; off <<= 1) {
        int a = (t >= off) ? s[t - off] : 0;
        __syncthreads();
        s[t] += a;
        __syncthreads();
    }
    if (i < n) incl[i] = s[t];
    if (t == 255) blksum[blockIdx.x] = s[255];
}
__global__ void k_scan2(int* blksum, int nb) {
    __shared__ int s[1024];
    int t = threadIdx.x;
    int v = (t < nb) ? blksum[t] : 0;
    s[t] = v;
    __syncthreads();
    for (int off = 1; off < 1024; off <<= 1) {
        int a = (t >= off) ? s[t - off] : 0;
        __syncthreads();
        s[t] += a;
        __syncthreads();
    }
    if (t < nb) blksum[t] = s[t] - v;  // exclusive
}
// also places the self-loop entry at the LAST slot of each segment (plain store, no atomic)
__global__ void k_scan3(const int* __restrict__ cnt, const int* __restrict__ incl,
                        const int* __restrict__ blksum, int* __restrict__ rp,
                        int* __restrict__ pos, int* __restrict__ esrc, int n) {
    int i = blockIdx.x * blockDim.x + threadIdx.x;
    if (i >= n) return;
    int c = cnt[i];
    int excl = incl[i] - (c + 1) + blksum[i >> 8];
    rp[i] = excl;
    pos[i] = excl;
    esrc[excl + c] = i;  // self loop occupies the final slot
    if (i == n - 1) rp[n] = incl[i] + blksum[i >> 8];
}

// ---------------- scatter real edges into CSR (nontemporal scattered stores) ----------------
__global__ void k_scatter(const int* __restrict__ ei, int* __restrict__ pos,
                          int* __restrict__ esrc, int E_) {
    int e = (blockIdx.x * blockDim.x + threadIdx.x) * 2;
    if (e >= E_) return;
    if (e + 1 < E_) {
        int2 s = *reinterpret_cast<const int2*>(&ei[e]);
        int2 d = *reinterpret_cast<const int2*>(&ei[E_ + e]);
        int p0 = atomicAdd(&pos[d.x], 1);
        __builtin_nontemporal_store(s.x, &esrc[p0]);
        int p1 = atomicAdd(&pos[d.y], 1);
        __builtin_nontemporal_store(s.y, &esrc[p1]);
    } else {
        int p0 = atomicAdd(&pos[ei[E_ + e]], 1);
        __builtin_nontemporal_store(ei[e], &esrc[p0]);
    }
}

// ---------------- layer 1 aggregation: wave per dst node, bf16 gather (1 dword/lane/edge) ----
// No max pass: logits are O(1) here so exp() cannot overflow; softmax is shift-invariant.
__global__ void __launch_bounds__(256) k_agg1(
        const unsigned* __restrict__ h1bf, const float* __restrict__ als1,
        const float* __restrict__ ald1, const int* __restrict__ rp,
        const int* __restrict__ esrc, const float* __restrict__ b1,
        float* __restrict__ out, int n) {
    __shared__ int ss[4][64];
    __shared__ float sw[4][256];  // head-major: [h*64 + edge]
    int wslot = threadIdx.x >> 6;
    int lane = threadIdx.x & 63;
    int wid = blockIdx.x * 4 + wslot;
    if (wid >= n) return;
    int beg = rp[wid], end = rp[wid + 1];
    const float4 ad = *reinterpret_cast<const float4*>(&ald1[wid * 4]);
    int hd = lane >> 4;  // this lane's channels 2*lane,2*lane+1 belong to head lane/16
    float2 acc = make_float2(0.f, 0.f);
    float z = 0.f;
    for (int cb = beg; cb < end; cb += 64) {
        int cnt = end - cb;
        if (cnt > 64) cnt = 64;
        if (lane < cnt) {
            int s = esrc[cb + lane];
            const float4 a = *reinterpret_cast<const float4*>(&als1[s * 4]);
            ss[wslot][lane] = s;
            sw[wslot][lane] = __expf(lrelu(a.x + ad.x));
            sw[wslot][64 + lane] = __expf(lrelu(a.y + ad.y));
            sw[wslot][128 + lane] = __expf(lrelu(a.z + ad.z));
            sw[wslot][192 + lane] = __expf(lrelu(a.w + ad.w));
        }
        // wave-private LDS slot: in-wave lgkmcnt ordering suffices, no barrier
#pragma unroll 2
        for (int j = 0; j < cnt; j++) {
            int s = ss[wslot][j];
            float w = sw[wslot][hd * 64 + j];
            z += w;
            unsigned p = h1bf[(size_t)s * 64 + lane];
            acc.x = fmaf(w, bf_lo(p), acc.x);
            acc.y = fmaf(w, bf_hi(p), acc.y);
        }
    }
    float inv = 1.f / (z + 1e-16f);
    const float2 bv = *reinterpret_cast<const float2*>(&b1[2 * lane]);
    float2 o = make_float2(acc.x * inv + bv.x, acc.y * inv + bv.y);
    *reinterpret_cast<float2*>(&out[(size_t)wid * 128 + 2 * lane]) = o;
}

// ---------------- BN stats: stage 1 (deterministic tree) ----------------
__global__ void k_stats(const float* __restrict__ x, float* __restrict__ partials,
                        int n, int C) {
    int t = threadIdx.x;
    int c = t & (C - 1);
    int rr = t / C;
    int RPB = 256 / C;
    float s = 0.f, s2 = 0.f;
    for (int r = blockIdx.x * RPB + rr; r < n; r += gridDim.x * RPB) {
        float v = x[(size_t)r * C + c];
        s += v;
        s2 += v * v;
    }
    __shared__ float ls[256], ls2[256];
    ls[t] = s;
    ls2[t] = s2;
    __syncthreads();
    if (rr == 0) {
        for (int j = 1; j < RPB; j++) { s += ls[j * C + c]; s2 += ls2[j * C + c]; }
        partials[(size_t)blockIdx.x * 2 * C + c] = s;
        partials[(size_t)blockIdx.x * 2 * C + C + c] = s2;
    }
}
// ---------------- BN stats stage 2: parallel finalize (512 threads) ----------------
__global__ void k_stats2(const float* __restrict__ partials, const float* __restrict__ gamma,
                         const float* __restrict__ beta, float* __restrict__ AB,
                         int n, int C, int nb) {
    __shared__ float ls[512], ls2[512];
    int t = threadIdx.x;
    int R = 512 / C;          // threads per channel
    int c = t & (C - 1);
    int r = t / C;
    float s = 0.f, s2 = 0.f;
    for (int b = r; b < nb; b += R) {
        s += partials[(size_t)b * 2 * C + c];
        s2 += partials[(size_t)b * 2 * C + C + c];
    }
    ls[t] = s;
    ls2[t] = s2;
    __syncthreads();
    for (int step = R >> 1; step > 0; step >>= 1) {
        if (r < step) {
            ls[t] += ls[t + step * C];
            ls2[t] += ls2[t + step * C];
        }
        __syncthreads();
    }
    if (r == 0) {
        float mu = ls[t] / n;
        float var = ls2[t] / n - mu * mu;
        float inv = rsqrtf(var + BN_EPS);
        float A = gamma[c] * inv;
        AB[c] = A;
        AB[C + c] = beta[c] - mu * A;
    }
}

// ---------------- node transform layer 2: BN+ELU then @ W2 (bf16 out), attn logits --------
__global__ void k_node2(const float* __restrict__ hin, const float* __restrict__ AB1,
                        const float* __restrict__ W2, const float* __restrict__ as2,
                        const float* __restrict__ ad2, unsigned* __restrict__ h2bf,
                        float* __restrict__ als2, float* __restrict__ ald2, int n) {
    __shared__ float sy[64 * 129];
    __shared__ float sw[128 * 32];
    int t = threadIdx.x;
    for (int i = t; i < 128 * 32; i += 256) sw[i] = W2[i];
    int base = blockIdx.x * 64;
    for (int i = t; i < 64 * 128; i += 256) {
        int r = i >> 7, c = i & 127;
        float v = 0.f;
        if (base + r < n) {
            float xx = hin[(size_t)(base + r) * 128 + c];
            v = elu(xx * AB1[c] + AB1[128 + c]);
        }
        sy[r * 129 + c] = v;
    }
    __syncthreads();
    int node = t >> 2, q = t & 3;
    float acc[8];
#pragma unroll
    for (int d = 0; d < 8; d++) acc[d] = 0.f;
    for (int k = 0; k < 128; k++) {
        float y = sy[node * 129 + k];
#pragma unroll
        for (int d = 0; d < 8; d++) acc[d] += y * sw[k * 32 + q * 8 + d];
    }
    float ps = 0.f, pd = 0.f;
#pragma unroll
    for (int d = 0; d < 8; d++) {
        ps += acc[d] * as2[q * 8 + d];
        pd += acc[d] * ad2[q * 8 + d];
    }
    ps += __shfl_xor(ps, 1); ps += __shfl_xor(ps, 2);
    pd += __shfl_xor(pd, 1); pd += __shfl_xor(pd, 2);
    int g = base + node;
    if (g < n) {
#pragma unroll
        for (int d = 0; d < 8; d += 2)
            h2bf[(size_t)g * 16 + q * 4 + (d >> 1)] = f2bf_pack(acc[d], acc[d + 1]);
        if (q == 0) { als2[g] = ps; ald2[g] = pd; }
    }
}

// ---------------- layer 2 aggregation: wave per dst node, 4 edges/step, bf16 gather -------
__global__ void __launch_bounds__(256) k_agg2(
        const unsigned* __restrict__ h2bf, const float* __restrict__ als2,
        const float* __restrict__ ald2, const int* __restrict__ rp,
        const int* __restrict__ esrc, const float* __restrict__ b2,
        float* __restrict__ out, int n) {
    __shared__ int ss[4][64];
    __shared__ float sw[4][64];
    int wslot = threadIdx.x >> 6;
    int lane = threadIdx.x & 63;
    int wid = blockIdx.x * 4 + wslot;
    if (wid >= n) return;
    int beg = rp[wid], end = rp[wid + 1];
    float ad = ald2[wid];
    int eg = lane >> 4;      // edge subgroup 0..3
    int cp = lane & 15;      // channel pair: channels 2cp, 2cp+1
    float2 acc = make_float2(0.f, 0.f);
    float z = 0.f;
    for (int cb = beg; cb < end; cb += 64) {
        int cnt = end - cb;
        if (cnt > 64) cnt = 64;
        if (lane < cnt) {
            int s = esrc[cb + lane];
            ss[wslot][lane] = s;
            sw[wslot][lane] = __expf(lrelu(als2[s] + ad));
        }
        for (int j = eg; j < cnt; j += 4) {
            int s = ss[wslot][j];
            float w = sw[wslot][j];
            z += w;
            unsigned p = h2bf[(size_t)s * 16 + cp];
            acc.x = fmaf(w, bf_lo(p), acc.x);
            acc.y = fmaf(w, bf_hi(p), acc.y);
        }
    }
    // reduce across the 4 edge subgroups
    z += __shfl_xor(z, 16);   z += __shfl_xor(z, 32);
    acc.x += __shfl_xor(acc.x, 16); acc.x += __shfl_xor(acc.x, 32);
    acc.y += __shfl_xor(acc.y, 16); acc.y += __shfl_xor(acc.y, 32);
    if (lane < 16) {
        float inv = 1.f / (z + 1e-16f);
        const float2 bv = *reinterpret_cast<const float2*>(&b2[2 * cp]);
        float2 o = make_float2(acc.x * inv + bv.x, acc.y * inv + bv.y);
        *reinterpret_cast<float2*>(&out[(size_t)wid * 32 + 2 * cp]) = o;
    }
}

// ---------------- graph boundaries via binary search on sorted batch ----------------
__global__ void k_bounds(const int* __restrict__ batch, int* __restrict__ bnd, int n, int g) {
    int i = blockIdx.x * blockDim.x + threadIdx.x;
    if (i > g) return;
    if (i == g) { bnd[g] = n; return; }
    int lo = 0, hi = n;
    while (lo < hi) {
        int mid = (lo + hi) >> 1;
        if (batch[mid] < i) lo = mid + 1; else hi = mid;
    }
    bnd[i] = lo;
}

// ---------------- BN2+ELU + mean pool + classifier: wave per graph ----------------
__global__ void k_pool(const float* __restrict__ x, const float* __restrict__ AB2,
                       const int* __restrict__ bnd, const float* __restrict__ Wc,
                       const float* __restrict__ bc, float* __restrict__ out, int G_) {
    int wid = (blockIdx.x * blockDim.x + threadIdx.x) >> 6;
    int lane = threadIdx.x & 63;
    if (wid >= G_) return;
    int beg = bnd[wid], end = bnd[wid + 1];
    int half = lane >> 5, f = lane & 31;
    float A = AB2[f], B = AB2[32 + f];
    float acc = 0.f;
    for (int r = beg + half; r < end; r += 2) {
        float v = x[(size_t)r * 32 + f] * A + B;
        acc += elu(v);
    }
    acc += __shfl_xor(acc, 32);
    float cntf = (float)((end - beg) > 1 ? (end - beg) : 1);
    float embv = acc / cntf;
    float p0 = embv * Wc[f * 2], p1 = embv * Wc[f * 2 + 1];
#pragma unroll
    for (int o = 1; o < 32; o <<= 1) {
        p0 += __shfl_xor(p0, o);
        p1 += __shfl_xor(p1, o);
    }
    if (lane == 0) {
        out[wid * 2] = p0 + bc[0];
        out[wid * 2 + 1] = p1 + bc[1];
    }
}

extern "C" void kernel_launch(void* const* d_in, const int* in_sizes, int n_in,
                              void* d_out, int out_size, void* d_ws, size_t ws_size,
                              hipStream_t stream) {
    const float* x = (const float*)d_in[0];
    const int* ei = (const int*)d_in[1];
    const int* batch = (const int*)d_in[2];
    const float* W1 = (const float*)d_in[3];
    const float* as1 = (const float*)d_in[4];
    const float* ad1 = (const float*)d_in[5];
    const float* b1 = (const float*)d_in[6];
    const float* g1 = (const float*)d_in[7];
    const float* be1 = (const float*)d_in[8];
    const float* W2 = (const float*)d_in[9];
    const float* as2 = (const float*)d_in[10];
    const float* ad2 = (const float*)d_in[11];
    const float* b2 = (const float*)d_in[12];
    const float* g2 = (const float*)d_in[13];
    const float* be2 = (const float*)d_in[14];
    const float* Wc = (const float*)d_in[15];
    const float* bc = (const float*)d_in[16];
    float* out = (float*)d_out;

    const int N = in_sizes[0] / 2;
    const int E = in_sizes[1] / 2;
    const int G = out_size / 2;
    const int Etot = E + N;
    const int NB = (N + 255) / 256;  // scan blocks (must be <= 1024)

    // workspace layout
    char* w = (char*)d_ws;
    size_t off = 0;
    auto alloc = [&](size_t bytes) { void* p = w + off; off = (off + bytes + 255) & ~(size_t)255; return p; };
    unsigned* h1bf = (unsigned*)alloc((size_t)N * 64 * 4);   // N x 128 bf16 packed
    float* h_ag1 = (float*)alloc((size_t)N * 128 * 4);
    float* als1 = (float*)alloc((size_t)N * 4 * 4);
    float* ald1 = (float*)alloc((size_t)N * 4 * 4);
    int* esrc = (int*)alloc((size_t)Etot * 4);
    int* cnt = (int*)alloc((size_t)N * 4);
    int* incl = (int*)alloc((size_t)N * 4);
    int* rp = (int*)alloc((size_t)(N + 1) * 4);
    int* pos = (int*)alloc((size_t)N * 4);
    int* blksum = (int*)alloc((size_t)NB * 4);
    float* partials = (float*)alloc((size_t)STATS_BLOCKS * 256 * 4);
    float* AB1 = (float*)alloc(256 * 4);
    float* AB2 = (float*)alloc(64 * 4);
    int* bnd = (int*)alloc((size_t)(G + 1) * 4);
    // reuse h1bf's space after layer-1 aggregation (N*64 uints available):
    unsigned* h2bf = h1bf;                                   // N*16 uints (N x 32 bf16)
    float* als2 = (float*)(h1bf + (size_t)N * 16);           // N floats
    float* ald2 = (float*)(h1bf + (size_t)N * 17);           // N floats
    float* out2 = (float*)(h1bf + (size_t)N * 18);           // N*32 floats (ends at N*50)

    // 1. zero counts
    k_zero<<<(N + 255) / 256, 256, 0, stream>>>(cnt, N);
    // 2. node transform layer 1
    k_node1<<<(N * 4 + 255) / 256, 256, 0, stream>>>(x, W1, as1, ad1, h1bf, als1, ald1, N);
    // 3. degree count (real edges only; 2 edges/thread)
    k_count<<<(E / 2 + 256) / 256, 256, 0, stream>>>(ei, cnt, E);
    // 4. scan (+1 slot per node for self loop; scan3 also places self loops)
    k_scan1<<<NB, 256, 0, stream>>>(cnt, incl, blksum, N);
    k_scan2<<<1, 1024, 0, stream>>>(blksum, NB);
    k_scan3<<<(N + 255) / 256, 256, 0, stream>>>(cnt, incl, blksum, rp, pos, esrc, N);
    // 5. scatter real edges (2 edges/thread, nontemporal stores)
    k_scatter<<<(E / 2 + 256) / 256, 256, 0, stream>>>(ei, pos, esrc, E);
    // 6. layer 1 aggregation (wave per node)
    k_agg1<<<(N + 3) / 4, 256, 0, stream>>>(h1bf, als1, ald1, rp, esrc, b1, h_ag1, N);
    // 7. BN1 stats
    k_stats<<<STATS_BLOCKS, 256, 0, stream>>>(h_ag1, partials, N, 128);
    k_stats2<<<1, 512, 0, stream>>>(partials, g1, be1, AB1, N, 128, STATS_BLOCKS);
    // 8. node transform layer 2 (BN+ELU fused)
    k_node2<<<(N + 63) / 64, 256, 0, stream>>>(h_ag1, AB1, W2, as2, ad2, h2bf, als2, ald2, N);
    // 9. layer 2 aggregation
    k_agg2<<<(N + 3) / 4, 256, 0, stream>>>(h2bf, als2, ald2, rp, esrc, b2, out2, N);
    // 10. BN2 stats
    k_stats<<<STATS_BLOCKS, 256, 0, stream>>>(out2, partials, N, 32);
    k_stats2<<<1, 512, 0, stream>>>(partials, g2, be2, AB2, N, 32, STATS_BLOCKS);
    // 11. graph boundaries
    k_bounds<<<(G + 256) / 256, 256, 0, stream>>>(batch, bnd, N, G);
    // 12. BN2+ELU + pool + classifier
    k_pool<<<(G * 64 + 255) / 256, 256, 0, stream>>>(out2, AB2, bnd, Wc, bc, out, G);
}

// Round 5
// 474.820 us; speedup vs baseline: 2.4249x; 1.1949x over previous
//
#include <hip/hip_runtime.h>
#include <hip/hip_bf16.h>
#include <math.h>

#define HEADS 4
#define HID 32
#define EMB 32
#define SLOPE 0.2f
#define BN_EPS 1e-5f
#define STATS_BLOCKS 256
#define BNUM 256   // bucket array size (actual B = ceil(N/512) <= 256)
#define BCAP 32    // LDS FIFO depth per bucket in k_stage

__device__ __forceinline__ float lrelu(float x) { return x > 0.f ? x : SLOPE * x; }
__device__ __forceinline__ float elu(float x) { return x > 0.f ? x : expm1f(x); }

// RNE float->bf16 and pack/unpack helpers
__device__ __forceinline__ unsigned f2bf_pack(float a, float b) {
    unsigned ua = __float_as_uint(a);
    unsigned ub = __float_as_uint(b);
    unsigned ra = (ua + 0x7fffu + ((ua >> 16) & 1u)) >> 16;
    unsigned rb = (ub + 0x7fffu + ((ub >> 16) & 1u)) >> 16;
    return ra | (rb << 16);
}
__device__ __forceinline__ float bf_lo(unsigned p) { return __uint_as_float(p << 16); }
__device__ __forceinline__ float bf_hi(unsigned p) { return __uint_as_float(p & 0xffff0000u); }

// ---------------- zero int buffer ----------------
__global__ void k_zero(int* p, int n) {
    int i = blockIdx.x * blockDim.x + threadIdx.x;
    if (i < n) p[i] = 0;
}

// ---------------- node transform layer 1: h1 = x @ W1 (packed bf16); al_src/al_dst ----------------
__global__ void k_node1(const float* __restrict__ x, const float* __restrict__ W1,
                        const float* __restrict__ as1, const float* __restrict__ ad1,
                        unsigned* __restrict__ h1bf, float* __restrict__ als, float* __restrict__ ald,
                        int n) {
    int idx = blockIdx.x * blockDim.x + threadIdx.x;
    int node = idx >> 2, hd = idx & 3;
    if (node >= n) return;
    float x0 = x[node * 2], x1 = x[node * 2 + 1];
    float ps = 0.f, pd = 0.f;
#pragma unroll
    for (int d = 0; d < 32; d += 2) {
        int c = hd * 32 + d;
        float v0 = x0 * W1[c] + x1 * W1[128 + c];
        float v1 = x0 * W1[c + 1] + x1 * W1[128 + c + 1];
        ps += v0 * as1[c] + v1 * as1[c + 1];
        pd += v0 * ad1[c] + v1 * ad1[c + 1];
        h1bf[(size_t)node * 64 + hd * 16 + (d >> 1)] = f2bf_pack(v0, v1);
    }
    als[node * 4 + hd] = ps;
    ald[node * 4 + hd] = pd;
}

// ---------------- bucket histogram of real edges (bucket = dst >> 9) ----------------
__global__ void k_bcount(const int* __restrict__ ei, int* __restrict__ bcnt, int E_, int B_) {
    __shared__ int h[BNUM];
    int t = threadIdx.x;
    h[t] = 0;
    __syncthreads();
    for (int e = blockIdx.x * blockDim.x + t; e < E_; e += gridDim.x * blockDim.x)
        atomicAdd(&h[ei[E_ + e] >> 9], 1);
    __syncthreads();
    if (t < B_ && h[t]) atomicAdd(&bcnt[t], h[t]);
}

// ---------------- scan bucket counts -> staged bases & esrc bases; rp[N] ----------------
__global__ void k_bscan(const int* __restrict__ bcnt, int* __restrict__ sbase,
                        int* __restrict__ ebase, int* __restrict__ rp,
                        int N_, int B_, int E_) {
    __shared__ int s1[BNUM], s2[BNUM];
    int t = threadIdx.x;
    int bc = 0, nodecnt = 0;
    if (t < B_) {
        bc = bcnt[t];
        int n0 = t << 9;
        nodecnt = N_ - n0;
        if (nodecnt > 512) nodecnt = 512;
        if (nodecnt < 0) nodecnt = 0;
    }
    s1[t] = bc;
    s2[t] = bc + nodecnt;
    __syncthreads();
    for (int off = 1; off < BNUM; off <<= 1) {
        int a1 = (t >= off) ? s1[t - off] : 0;
        int a2 = (t >= off) ? s2[t - off] : 0;
        __syncthreads();
        s1[t] += a1;
        s2[t] += a2;
        __syncthreads();
    }
    if (t < B_) {
        sbase[t] = s1[t] - bc;
        ebase[t] = s2[t] - (bc + nodecnt);
    }
    if (t == 0) rp[N_] = E_ + N_;
}

// ---------------- stage edges into buckets (LDS FIFO, 64B full-line flushes) ----------------
__global__ void __launch_bounds__(256) k_stage(const int* __restrict__ ei,
                                               const int* __restrict__ sbase,
                                               int* __restrict__ app,
                                               unsigned* __restrict__ staged,
                                               int E_, int B_) {
    __shared__ int lcnt[BNUM];
    __shared__ unsigned lbuf[BNUM * BCAP];
    int t = threadIdx.x;
    lcnt[t] = 0;   // blockDim == 256 == BNUM
    __syncthreads();
    for (int base = blockIdx.x * 256; base < E_; base += gridDim.x * 256) {
        int e = base + t;
        if (e < E_) {
            int s = ei[e], d = ei[E_ + e];
            int b = d >> 9;
            unsigned pk = ((unsigned)s << 9) | (unsigned)(d & 511);
            int sl = atomicAdd(&lcnt[b], 1);
            if (sl < BCAP) lbuf[b * BCAP + sl] = pk;
            else staged[sbase[b] + atomicAdd(&app[b], 1)] = pk;  // overflow (rare)
        }
        __syncthreads();
        if (t < B_) {
            int c = lcnt[t]; if (c > BCAP) c = BCAP;
            int k = c & ~15;
            if (k) {
                int gp = atomicAdd(&app[t], k);
                unsigned* gdst = &staged[sbase[t] + gp];
                for (int i = 0; i < k; i++) gdst[i] = lbuf[t * BCAP + i];
                for (int i = k; i < c; i++) lbuf[t * BCAP + i - k] = lbuf[t * BCAP + i];
                c -= k;
            }
            lcnt[t] = c;
        }
        __syncthreads();
    }
    if (t < B_) {
        int c = lcnt[t]; if (c > BCAP) c = BCAP;
        if (c) {
            int gp = atomicAdd(&app[t], c);
            unsigned* gdst = &staged[sbase[t] + gp];
            for (int i = 0; i < c; i++) gdst[i] = lbuf[t * BCAP + i];
        }
    }
}

// ---------------- per-bucket finalize: count, scan, write rp + esrc (+self loops) -------
__global__ void __launch_bounds__(512) k_bucket(const unsigned* __restrict__ staged,
                                                const int* __restrict__ bcnt,
                                                const int* __restrict__ sbase,
                                                const int* __restrict__ ebase,
                                                int* __restrict__ rp, int* __restrict__ esrc,
                                                int N_) {
    int b = blockIdx.x;
    int n0 = b << 9;
    int nn = N_ - n0;
    if (nn > 512) nn = 512;
    if (nn <= 0) return;
    __shared__ int lc[512];
    __shared__ int sc[512];
    __shared__ int wpos[512];
    int t = threadIdx.x;
    lc[t] = 0;
    __syncthreads();
    int m = bcnt[b], sb = sbase[b];
    for (int i = t; i < m; i += 512) atomicAdd(&lc[staged[sb + i] & 511], 1);
    __syncthreads();
    sc[t] = lc[t];
    __syncthreads();
    for (int off = 1; off < 512; off <<= 1) {
        int a = (t >= off) ? sc[t - off] : 0;
        __syncthreads();
        sc[t] += a;
        __syncthreads();
    }
    if (t < nn) {
        int r = ebase[b] + (sc[t] - lc[t]) + t;  // global segment start for node n0+t
        rp[n0 + t] = r;
        wpos[t] = r;
        esrc[r + lc[t]] = n0 + t;                // self loop at final slot (no atomic)
    }
    __syncthreads();
    for (int i = t; i < m; i += 512) {
        unsigned p = staged[sb + i];
        int q = atomicAdd(&wpos[p & 511], 1);
        esrc[q] = (int)(p >> 9);
    }
}

// ---------------- layer 1 aggregation: wave per dst node, bf16 gather (1 dword/lane/edge) ----
// No max pass: logits are O(1) here so exp() cannot overflow; softmax is shift-invariant.
__global__ void __launch_bounds__(256) k_agg1(
        const unsigned* __restrict__ h1bf, const float* __restrict__ als1,
        const float* __restrict__ ald1, const int* __restrict__ rp,
        const int* __restrict__ esrc, const float* __restrict__ b1,
        float* __restrict__ out, int n) {
    __shared__ int ss[4][64];
    __shared__ float sw[4][256];  // head-major: [h*64 + edge]
    int wslot = threadIdx.x >> 6;
    int lane = threadIdx.x & 63;
    int wid = blockIdx.x * 4 + wslot;
    if (wid >= n) return;
    int beg = rp[wid], end = rp[wid + 1];
    const float4 ad = *reinterpret_cast<const float4*>(&ald1[wid * 4]);
    int hd = lane >> 4;  // this lane's channels 2*lane,2*lane+1 belong to head lane/16
    float2 acc = make_float2(0.f, 0.f);
    float z = 0.f;
    for (int cb = beg; cb < end; cb += 64) {
        int cnt = end - cb;
        if (cnt > 64) cnt = 64;
        if (lane < cnt) {
            int s = esrc[cb + lane];
            const float4 a = *reinterpret_cast<const float4*>(&als1[s * 4]);
            ss[wslot][lane] = s;
            sw[wslot][lane] = __expf(lrelu(a.x + ad.x));
            sw[wslot][64 + lane] = __expf(lrelu(a.y + ad.y));
            sw[wslot][128 + lane] = __expf(lrelu(a.z + ad.z));
            sw[wslot][192 + lane] = __expf(lrelu(a.w + ad.w));
        }
        // wave-private LDS slot: in-wave lgkmcnt ordering suffices, no barrier
#pragma unroll 2
        for (int j = 0; j < cnt; j++) {
            int s = ss[wslot][j];
            float w = sw[wslot][hd * 64 + j];
            z += w;
            unsigned p = h1bf[(size_t)s * 64 + lane];
            acc.x = fmaf(w, bf_lo(p), acc.x);
            acc.y = fmaf(w, bf_hi(p), acc.y);
        }
    }
    float inv = 1.f / (z + 1e-16f);
    const float2 bv = *reinterpret_cast<const float2*>(&b1[2 * lane]);
    float2 o = make_float2(acc.x * inv + bv.x, acc.y * inv + bv.y);
    *reinterpret_cast<float2*>(&out[(size_t)wid * 128 + 2 * lane]) = o;
}

// ---------------- BN stats: stage 1 (deterministic tree) ----------------
__global__ void k_stats(const float* __restrict__ x, float* __restrict__ partials,
                        int n, int C) {
    int t = threadIdx.x;
    int c = t & (C - 1);
    int rr = t / C;
    int RPB = 256 / C;
    float s = 0.f, s2 = 0.f;
    for (int r = blockIdx.x * RPB + rr; r < n; r += gridDim.x * RPB) {
        float v = x[(size_t)r * C + c];
        s += v;
        s2 += v * v;
    }
    __shared__ float ls[256], ls2[256];
    ls[t] = s;
    ls2[t] = s2;
    __syncthreads();
    if (rr == 0) {
        for (int j = 1; j < RPB; j++) { s += ls[j * C + c]; s2 += ls2[j * C + c]; }
        partials[(size_t)blockIdx.x * 2 * C + c] = s;
        partials[(size_t)blockIdx.x * 2 * C + C + c] = s2;
    }
}
// ---------------- BN stats stage 2: parallel finalize (512 threads) ----------------
__global__ void k_stats2(const float* __restrict__ partials, const float* __restrict__ gamma,
                         const float* __restrict__ beta, float* __restrict__ AB,
                         int n, int C, int nb) {
    __shared__ float ls[512], ls2[512];
    int t = threadIdx.x;
    int R = 512 / C;          // threads per channel
    int c = t & (C - 1);
    int r = t / C;
    float s = 0.f, s2 = 0.f;
    for (int b = r; b < nb; b += R) {
        s += partials[(size_t)b * 2 * C + c];
        s2 += partials[(size_t)b * 2 * C + C + c];
    }
    ls[t] = s;
    ls2[t] = s2;
    __syncthreads();
    for (int step = R >> 1; step > 0; step >>= 1) {
        if (r < step) {
            ls[t] += ls[t + step * C];
            ls2[t] += ls2[t + step * C];
        }
        __syncthreads();
    }
    if (r == 0) {
        float mu = ls[t] / n;
        float var = ls2[t] / n - mu * mu;
        float inv = rsqrtf(var + BN_EPS);
        float A = gamma[c] * inv;
        AB[c] = A;
        AB[C + c] = beta[c] - mu * A;
    }
}

// ---------------- node transform layer 2: BN+ELU then @ W2 (bf16 out), attn logits --------
__global__ void k_node2(const float* __restrict__ hin, const float* __restrict__ AB1,
                        const float* __restrict__ W2, const float* __restrict__ as2,
                        const float* __restrict__ ad2, unsigned* __restrict__ h2bf,
                        float* __restrict__ als2, float* __restrict__ ald2, int n) {
    __shared__ float sy[64 * 129];
    __shared__ float sw[128 * 32];
    int t = threadIdx.x;
    for (int i = t; i < 128 * 32; i += 256) sw[i] = W2[i];
    int base = blockIdx.x * 64;
    for (int i = t; i < 64 * 128; i += 256) {
        int r = i >> 7, c = i & 127;
        float v = 0.f;
        if (base + r < n) {
            float xx = hin[(size_t)(base + r) * 128 + c];
            v = elu(xx * AB1[c] + AB1[128 + c]);
        }
        sy[r * 129 + c] = v;
    }
    __syncthreads();
    int node = t >> 2, q = t & 3;
    float acc[8];
#pragma unroll
    for (int d = 0; d < 8; d++) acc[d] = 0.f;
    for (int k = 0; k < 128; k++) {
        float y = sy[node * 129 + k];
#pragma unroll
        for (int d = 0; d < 8; d++) acc[d] += y * sw[k * 32 + q * 8 + d];
    }
    float ps = 0.f, pd = 0.f;
#pragma unroll
    for (int d = 0; d < 8; d++) {
        ps += acc[d] * as2[q * 8 + d];
        pd += acc[d] * ad2[q * 8 + d];
    }
    ps += __shfl_xor(ps, 1); ps += __shfl_xor(ps, 2);
    pd += __shfl_xor(pd, 1); pd += __shfl_xor(pd, 2);
    int g = base + node;
    if (g < n) {
#pragma unroll
        for (int d = 0; d < 8; d += 2)
            h2bf[(size_t)g * 16 + q * 4 + (d >> 1)] = f2bf_pack(acc[d], acc[d + 1]);
        if (q == 0) { als2[g] = ps; ald2[g] = pd; }
    }
}

// ---------------- layer 2 aggregation: wave per dst node, 4 edges/step, bf16 gather -------
__global__ void __launch_bounds__(256) k_agg2(
        const unsigned* __restrict__ h2bf, const float* __restrict__ als2,
        const float* __restrict__ ald2, const int* __restrict__ rp,
        const int* __restrict__ esrc, const float* __restrict__ b2,
        float* __restrict__ out, int n) {
    __shared__ int ss[4][64];
    __shared__ float sw[4][64];
    int wslot = threadIdx.x >> 6;
    int lane = threadIdx.x & 63;
    int wid = blockIdx.x * 4 + wslot;
    if (wid >= n) return;
    int beg = rp[wid], end = rp[wid + 1];
    float ad = ald2[wid];
    int eg = lane >> 4;      // edge subgroup 0..3
    int cp = lane & 15;      // channel pair: channels 2cp, 2cp+1
    float2 acc = make_float2(0.f, 0.f);
    float z = 0.f;
    for (int cb = beg; cb < end; cb += 64) {
        int cnt = end - cb;
        if (cnt > 64) cnt = 64;
        if (lane < cnt) {
            int s = esrc[cb + lane];
            ss[wslot][lane] = s;
            sw[wslot][lane] = __expf(lrelu(als2[s] + ad));
        }
        for (int j = eg; j < cnt; j += 4) {
            int s = ss[wslot][j];
            float w = sw[wslot][j];
            z += w;
            unsigned p = h2bf[(size_t)s * 16 + cp];
            acc.x = fmaf(w, bf_lo(p), acc.x);
            acc.y = fmaf(w, bf_hi(p), acc.y);
        }
    }
    // reduce across the 4 edge subgroups
    z += __shfl_xor(z, 16);   z += __shfl_xor(z, 32);
    acc.x += __shfl_xor(acc.x, 16); acc.x += __shfl_xor(acc.x, 32);
    acc.y += __shfl_xor(acc.y, 16); acc.y += __shfl_xor(acc.y, 32);
    if (lane < 16) {
        float inv = 1.f / (z + 1e-16f);
        const float2 bv = *reinterpret_cast<const float2*>(&b2[2 * cp]);
        float2 o = make_float2(acc.x * inv + bv.x, acc.y * inv + bv.y);
        *reinterpret_cast<float2*>(&out[(size_t)wid * 32 + 2 * cp]) = o;
    }
}

// ---------------- graph boundaries via binary search on sorted batch ----------------
__global__ void k_bounds(const int* __restrict__ batch, int* __restrict__ bnd, int n, int g) {
    int i = blockIdx.x * blockDim.x + threadIdx.x;
    if (i > g) return;
    if (i == g) { bnd[g] = n; return; }
    int lo = 0, hi = n;
    while (lo < hi) {
        int mid = (lo + hi) >> 1;
        if (batch[mid] < i) lo = mid + 1; else hi = mid;
    }
    bnd[i] = lo;
}

// ---------------- BN2+ELU + mean pool + classifier: wave per graph ----------------
__global__ void k_pool(const float* __restrict__ x, const float* __restrict__ AB2,
                       const int* __restrict__ bnd, const float* __restrict__ Wc,
                       const float* __restrict__ bc, float* __restrict__ out, int G_) {
    int wid = (blockIdx.x * blockDim.x + threadIdx.x) >> 6;
    int lane = threadIdx.x & 63;
    if (wid >= G_) return;
    int beg = bnd[wid], end = bnd[wid + 1];
    int half = lane >> 5, f = lane & 31;
    float A = AB2[f], B = AB2[32 + f];
    float acc = 0.f;
    for (int r = beg + half; r < end; r += 2) {
        float v = x[(size_t)r * 32 + f] * A + B;
        acc += elu(v);
    }
    acc += __shfl_xor(acc, 32);
    float cntf = (float)((end - beg) > 1 ? (end - beg) : 1);
    float embv = acc / cntf;
    float p0 = embv * Wc[f * 2], p1 = embv * Wc[f * 2 + 1];
#pragma unroll
    for (int o = 1; o < 32; o <<= 1) {
        p0 += __shfl_xor(p0, o);
        p1 += __shfl_xor(p1, o);
    }
    if (lane == 0) {
        out[wid * 2] = p0 + bc[0];
        out[wid * 2 + 1] = p1 + bc[1];
    }
}

extern "C" void kernel_launch(void* const* d_in, const int* in_sizes, int n_in,
                              void* d_out, int out_size, void* d_ws, size_t ws_size,
                              hipStream_t stream) {
    const float* x = (const float*)d_in[0];
    const int* ei = (const int*)d_in[1];
    const int* batch = (const int*)d_in[2];
    const float* W1 = (const float*)d_in[3];
    const float* as1 = (const float*)d_in[4];
    const float* ad1 = (const float*)d_in[5];
    const float* b1 = (const float*)d_in[6];
    const float* g1 = (const float*)d_in[7];
    const float* be1 = (const float*)d_in[8];
    const float* W2 = (const float*)d_in[9];
    const float* as2 = (const float*)d_in[10];
    const float* ad2 = (const float*)d_in[11];
    const float* b2 = (const float*)d_in[12];
    const float* g2 = (const float*)d_in[13];
    const float* be2 = (const float*)d_in[14];
    const float* Wc = (const float*)d_in[15];
    const float* bc = (const float*)d_in[16];
    float* out = (float*)d_out;

    const int N = in_sizes[0] / 2;
    const int E = in_sizes[1] / 2;
    const int G = out_size / 2;
    const int Etot = E + N;
    const int B = (N + 511) >> 9;     // buckets of 512 dst nodes (<= 256)

    // workspace layout
    char* w = (char*)d_ws;
    size_t off = 0;
    auto alloc = [&](size_t bytes) { void* p = w + off; off = (off + bytes + 255) & ~(size_t)255; return p; };
    unsigned* h1bf = (unsigned*)alloc((size_t)N * 64 * 4);   // N x 128 bf16 packed
    float* h_ag1 = (float*)alloc((size_t)N * 128 * 4);
    float* als1 = (float*)alloc((size_t)N * 4 * 4);
    float* ald1 = (float*)alloc((size_t)N * 4 * 4);
    int* esrc = (int*)alloc((size_t)Etot * 4);
    unsigned* staged = (unsigned*)alloc((size_t)E * 4);
    int* rp = (int*)alloc((size_t)(N + 1) * 4);
    int* bcnt = (int*)alloc(BNUM * 4);
    int* app = (int*)alloc(BNUM * 4);
    int* sbase = (int*)alloc(BNUM * 4);
    int* ebase = (int*)alloc(BNUM * 4);
    float* partials = (float*)alloc((size_t)STATS_BLOCKS * 256 * 4);
    float* AB1 = (float*)alloc(256 * 4);
    float* AB2 = (float*)alloc(64 * 4);
    int* bnd = (int*)alloc((size_t)(G + 1) * 4);
    // reuse h1bf's space after layer-1 aggregation (N*64 uints available):
    unsigned* h2bf = h1bf;                                   // N*16 uints (N x 32 bf16)
    float* als2 = (float*)(h1bf + (size_t)N * 16);           // N floats
    float* ald2 = (float*)(h1bf + (size_t)N * 17);           // N floats
    float* out2 = (float*)(h1bf + (size_t)N * 18);           // N*32 floats (ends at N*50)

    // 1. zero bucket counters (bcnt + app are adjacent allocations? zero separately)
    k_zero<<<1, 256, 0, stream>>>(bcnt, BNUM);
    k_zero<<<1, 256, 0, stream>>>(app, BNUM);
    // 2. node transform layer 1
    k_node1<<<(N * 4 + 255) / 256, 256, 0, stream>>>(x, W1, as1, ad1, h1bf, als1, ald1, N);
    // 3. bucket histogram
    k_bcount<<<256, 256, 0, stream>>>(ei, bcnt, E, B);
    // 4. bucket scan -> staged/esrc bases, rp[N]
    k_bscan<<<1, BNUM, 0, stream>>>(bcnt, sbase, ebase, rp, N, B, E);
    // 5. stage edges into buckets (full-line flushes)
    k_stage<<<128, 256, 0, stream>>>(ei, sbase, app, staged, E, B);
    // 6. per-bucket finalize: rp + esrc (+self loops)
    k_bucket<<<B, 512, 0, stream>>>(staged, bcnt, sbase, ebase, rp, esrc, N);
    // 7. layer 1 aggregation (wave per node)
    k_agg1<<<(N + 3) / 4, 256, 0, stream>>>(h1bf, als1, ald1, rp, esrc, b1, h_ag1, N);
    // 8. BN1 stats
    k_stats<<<STATS_BLOCKS, 256, 0, stream>>>(h_ag1, partials, N, 128);
    k_stats2<<<1, 512, 0, stream>>>(partials, g1, be1, AB1, N, 128, STATS_BLOCKS);
    // 9. node transform layer 2 (BN+ELU fused)
    k_node2<<<(N + 63) / 64, 256, 0, stream>>>(h_ag1, AB1, W2, as2, ad2, h2bf, als2, ald2, N);
    // 10. layer 2 aggregation
    k_agg2<<<(N + 3) / 4, 256, 0, stream>>>(h2bf, als2, ald2, rp, esrc, b2, out2, N);
    // 11. BN2 stats
    k_stats<<<STATS_BLOCKS, 256, 0, stream>>>(out2, partials, N, 32);
    k_stats2<<<1, 512, 0, stream>>>(partials, g2, be2, AB2, N, 32, STATS_BLOCKS);
    // 12. graph boundaries
    k_bounds<<<(G + 256) / 256, 256, 0, stream>>>(batch, bnd, N, G);
    // 13. BN2+ELU + pool + classifier
    k_pool<<<(G * 64 + 255) / 256, 256, 0, stream>>>(out2, AB2, bnd, Wc, bc, out, G);
}

// Round 6
// 407.371 us; speedup vs baseline: 2.8264x; 1.1656x over previous
//
#include <hip/hip_runtime.h>
#include <hip/hip_bf16.h>
#include <math.h>

#define HEADS 4
#define HID 32
#define EMB 32
#define SLOPE 0.2f
#define BN_EPS 1e-5f
#define STATS_BLOCKS 256
#define BNUM 256   // bucket array size (actual B = ceil(N/512) <= 256)
#define P 256      // radix blocks

__device__ __forceinline__ float lrelu(float x) { return x > 0.f ? x : SLOPE * x; }
__device__ __forceinline__ float elu(float x) { return x > 0.f ? x : expm1f(x); }

// RNE float->bf16 and pack/unpack helpers
__device__ __forceinline__ unsigned f2bf_pack(float a, float b) {
    unsigned ua = __float_as_uint(a);
    unsigned ub = __float_as_uint(b);
    unsigned ra = (ua + 0x7fffu + ((ua >> 16) & 1u)) >> 16;
    unsigned rb = (ub + 0x7fffu + ((ub >> 16) & 1u)) >> 16;
    return ra | (rb << 16);
}
__device__ __forceinline__ float bf_lo(unsigned p) { return __uint_as_float(p << 16); }
__device__ __forceinline__ float bf_hi(unsigned p) { return __uint_as_float(p & 0xffff0000u); }

// ---------------- node transform layer 1: h1 = x @ W1 (packed bf16); al_src/al_dst ----------------
__global__ void k_node1(const float* __restrict__ x, const float* __restrict__ W1,
                        const float* __restrict__ as1, const float* __restrict__ ad1,
                        unsigned* __restrict__ h1bf, float* __restrict__ als, float* __restrict__ ald,
                        int n) {
    int idx = blockIdx.x * blockDim.x + threadIdx.x;
    int node = idx >> 2, hd = idx & 3;
    if (node >= n) return;
    float x0 = x[node * 2], x1 = x[node * 2 + 1];
    float ps = 0.f, pd = 0.f;
#pragma unroll
    for (int d = 0; d < 32; d += 2) {
        int c = hd * 32 + d;
        float v0 = x0 * W1[c] + x1 * W1[128 + c];
        float v1 = x0 * W1[c + 1] + x1 * W1[128 + c + 1];
        ps += v0 * as1[c] + v1 * as1[c + 1];
        pd += v0 * ad1[c] + v1 * ad1[c + 1];
        h1bf[(size_t)node * 64 + hd * 16 + (d >> 1)] = f2bf_pack(v0, v1);
    }
    als[node * 4 + hd] = ps;
    ald[node * 4 + hd] = pd;
}

// ---------------- pass A: per-block histogram, p-major ghist[p][b] ----------------
__global__ void __launch_bounds__(256) k_hist(const int* __restrict__ ei,
                                              int* __restrict__ ghist, int E_, int CH) {
    __shared__ int h[BNUM];
    int t = threadIdx.x, p = blockIdx.x;
    h[t] = 0;
    __syncthreads();
    int beg = p * CH, end = beg + CH;
    if (end > E_) end = E_;
    for (int e = beg + t; e < end; e += 256) atomicAdd(&h[ei[E_ + e] >> 9], 1);
    __syncthreads();
    ghist[p * BNUM + t] = h[t];  // coalesced
}

// ---------------- pass B: exclusive scan of ghist in bucket-major order ----------------
// linear index i = b*P + p  ->  ghist[p*BNUM + b]. Also emits sbase[b] and rp[N].
__global__ void __launch_bounds__(1024) k_gscan(const int* __restrict__ ghist,
                                                int* __restrict__ goff, int* __restrict__ sbase,
                                                int* __restrict__ rp, int N_, int E_) {
    __shared__ int s[1024];
    int t = threadIdx.x;
    const int PER = (BNUM * P) / 1024;  // 64
    int b0 = t >> 2;                    // fixed b for this thread's chunk
    int p0 = (t & 3) * PER;             // p range start
    int v[PER];
    int sum = 0;
#pragma unroll
    for (int k = 0; k < PER; k++) {
        v[k] = ghist[(p0 + k) * BNUM + b0];
        sum += v[k];
    }
    s[t] = sum;
    __syncthreads();
    for (int off = 1; off < 1024; off <<= 1) {
        int a = (t >= off) ? s[t - off] : 0;
        __syncthreads();
        s[t] += a;
        __syncthreads();
    }
    int run = s[t] - sum;  // exclusive prefix of this chunk
#pragma unroll
    for (int k = 0; k < PER; k++) {
        if (p0 + k == 0) sbase[b0] = run;
        goff[(p0 + k) * BNUM + b0] = run;
        run += v[k];
    }
    if (t == 0) {
        sbase[BNUM] = E_;
        rp[N_] = E_ + N_;
    }
}

// ---------------- pass C: scatter into block-private per-bucket ranges ----------------
__global__ void __launch_bounds__(256) k_scatter3(const int* __restrict__ ei,
                                                  const int* __restrict__ goff,
                                                  unsigned* __restrict__ staged,
                                                  int E_, int CH) {
    __shared__ int loff[BNUM];
    __shared__ int lpos[BNUM];
    int t = threadIdx.x, p = blockIdx.x;
    loff[t] = goff[p * BNUM + t];
    lpos[t] = 0;
    __syncthreads();
    int beg = p * CH, end = beg + CH;
    if (end > E_) end = E_;
    for (int e = beg + t; e < end; e += 256) {
        int s = ei[e], d = ei[E_ + e];
        int b = d >> 9;
        unsigned pk = ((unsigned)s << 9) | (unsigned)(d & 511);
        int pos = loff[b] + atomicAdd(&lpos[b], 1);
        staged[pos] = pk;
    }
}

// ---------------- per-bucket finalize: count, scan, write rp + esrc (+self loops) -------
__global__ void __launch_bounds__(512) k_bucket(const unsigned* __restrict__ staged,
                                                const int* __restrict__ sbase,
                                                int* __restrict__ rp, int* __restrict__ esrc,
                                                int N_) {
    int b = blockIdx.x;
    int n0 = b << 9;
    int nn = N_ - n0;
    if (nn > 512) nn = 512;
    if (nn <= 0) return;
    __shared__ int lc[512];
    __shared__ int sc[512];
    __shared__ int wpos[512];
    int t = threadIdx.x;
    lc[t] = 0;
    __syncthreads();
    int sb = sbase[b];
    int m = sbase[b + 1] - sb;
    int eb = sb + (b << 9);  // global esrc base: edges before + nodes before
    for (int i = t; i < m; i += 512) atomicAdd(&lc[staged[sb + i] & 511], 1);
    __syncthreads();
    sc[t] = lc[t];
    __syncthreads();
    for (int off = 1; off < 512; off <<= 1) {
        int a = (t >= off) ? sc[t - off] : 0;
        __syncthreads();
        sc[t] += a;
        __syncthreads();
    }
    if (t < nn) {
        int r = eb + (sc[t] - lc[t]) + t;  // segment start for node n0+t
        rp[n0 + t] = r;
        wpos[t] = r;
        esrc[r + lc[t]] = n0 + t;          // self loop at final slot (no atomic)
    }
    __syncthreads();
    for (int i = t; i < m; i += 512) {
        unsigned p = staged[sb + i];
        int q = atomicAdd(&wpos[p & 511], 1);
        esrc[q] = (int)(p >> 9);
    }
}

// ---------------- layer 1 aggregation: wave per dst node, bf16 gather (1 dword/lane/edge) ----
// No max pass: logits are O(1) here so exp() cannot overflow; softmax is shift-invariant.
// sw layout is edge-interleaved [4*j + hd] so the 4 head weights sit in 4 consecutive banks.
__global__ void __launch_bounds__(256) k_agg1(
        const unsigned* __restrict__ h1bf, const float* __restrict__ als1,
        const float* __restrict__ ald1, const int* __restrict__ rp,
        const int* __restrict__ esrc, const float* __restrict__ b1,
        float* __restrict__ out, int n) {
    __shared__ int ss[4][64];
    __shared__ float sw[4][256];  // [edge j][head] interleaved: index 4*j+hd
    int wslot = threadIdx.x >> 6;
    int lane = threadIdx.x & 63;
    int wid = blockIdx.x * 4 + wslot;
    if (wid >= n) return;
    int beg = rp[wid], end = rp[wid + 1];
    const float4 ad = *reinterpret_cast<const float4*>(&ald1[wid * 4]);
    int hd = lane >> 4;  // this lane's channels 2*lane,2*lane+1 belong to head lane/16
    float2 acc = make_float2(0.f, 0.f);
    float z = 0.f;
    for (int cb = beg; cb < end; cb += 64) {
        int cnt = end - cb;
        if (cnt > 64) cnt = 64;
        if (lane < cnt) {
            int s = esrc[cb + lane];
            const float4 a = *reinterpret_cast<const float4*>(&als1[s * 4]);
            ss[wslot][lane] = s;
            float4 wv;
            wv.x = __expf(lrelu(a.x + ad.x));
            wv.y = __expf(lrelu(a.y + ad.y));
            wv.z = __expf(lrelu(a.z + ad.z));
            wv.w = __expf(lrelu(a.w + ad.w));
            *reinterpret_cast<float4*>(&sw[wslot][4 * lane]) = wv;
        }
        // wave-private LDS slot: in-wave lgkmcnt ordering suffices, no barrier
#pragma unroll 2
        for (int j = 0; j < cnt; j++) {
            int s = ss[wslot][j];
            float w = sw[wslot][4 * j + hd];
            z += w;
            unsigned p = h1bf[(size_t)s * 64 + lane];
            acc.x = fmaf(w, bf_lo(p), acc.x);
            acc.y = fmaf(w, bf_hi(p), acc.y);
        }
    }
    float inv = 1.f / (z + 1e-16f);
    const float2 bv = *reinterpret_cast<const float2*>(&b1[2 * lane]);
    float2 o = make_float2(acc.x * inv + bv.x, acc.y * inv + bv.y);
    *reinterpret_cast<float2*>(&out[(size_t)wid * 128 + 2 * lane]) = o;
}

// ---------------- BN stats: stage 1 (deterministic tree) ----------------
__global__ void k_stats(const float* __restrict__ x, float* __restrict__ partials,
                        int n, int C) {
    int t = threadIdx.x;
    int c = t & (C - 1);
    int rr = t / C;
    int RPB = 256 / C;
    float s = 0.f, s2 = 0.f;
    for (int r = blockIdx.x * RPB + rr; r < n; r += gridDim.x * RPB) {
        float v = x[(size_t)r * C + c];
        s += v;
        s2 += v * v;
    }
    __shared__ float ls[256], ls2[256];
    ls[t] = s;
    ls2[t] = s2;
    __syncthreads();
    if (rr == 0) {
        for (int j = 1; j < RPB; j++) { s += ls[j * C + c]; s2 += ls2[j * C + c]; }
        partials[(size_t)blockIdx.x * 2 * C + c] = s;
        partials[(size_t)blockIdx.x * 2 * C + C + c] = s2;
    }
}
// ---------------- BN stats stage 2: parallel finalize (512 threads) ----------------
__global__ void k_stats2(const float* __restrict__ partials, const float* __restrict__ gamma,
                         const float* __restrict__ beta, float* __restrict__ AB,
                         int n, int C, int nb) {
    __shared__ float ls[512], ls2[512];
    int t = threadIdx.x;
    int R = 512 / C;          // threads per channel
    int c = t & (C - 1);
    int r = t / C;
    float s = 0.f, s2 = 0.f;
    for (int b = r; b < nb; b += R) {
        s += partials[(size_t)b * 2 * C + c];
        s2 += partials[(size_t)b * 2 * C + C + c];
    }
    ls[t] = s;
    ls2[t] = s2;
    __syncthreads();
    for (int step = R >> 1; step > 0; step >>= 1) {
        if (r < step) {
            ls[t] += ls[t + step * C];
            ls2[t] += ls2[t + step * C];
        }
        __syncthreads();
    }
    if (r == 0) {
        float mu = ls[t] / n;
        float var = ls2[t] / n - mu * mu;
        float inv = rsqrtf(var + BN_EPS);
        float A = gamma[c] * inv;
        AB[c] = A;
        AB[C + c] = beta[c] - mu * A;
    }
}

// ---------------- node transform layer 2: BN+ELU then @ W2 (bf16 out), attn logits --------
__global__ void k_node2(const float* __restrict__ hin, const float* __restrict__ AB1,
                        const float* __restrict__ W2, const float* __restrict__ as2,
                        const float* __restrict__ ad2, unsigned* __restrict__ h2bf,
                        float* __restrict__ als2, float* __restrict__ ald2, int n) {
    __shared__ float sy[64 * 129];
    __shared__ float sw[128 * 32];
    int t = threadIdx.x;
    for (int i = t; i < 128 * 32; i += 256) sw[i] = W2[i];
    int base = blockIdx.x * 64;
    for (int i = t; i < 64 * 128; i += 256) {
        int r = i >> 7, c = i & 127;
        float v = 0.f;
        if (base + r < n) {
            float xx = hin[(size_t)(base + r) * 128 + c];
            v = elu(xx * AB1[c] + AB1[128 + c]);
        }
        sy[r * 129 + c] = v;
    }
    __syncthreads();
    int node = t >> 2, q = t & 3;
    float acc[8];
#pragma unroll
    for (int d = 0; d < 8; d++) acc[d] = 0.f;
    for (int k = 0; k < 128; k++) {
        float y = sy[node * 129 + k];
#pragma unroll
        for (int d = 0; d < 8; d++) acc[d] += y * sw[k * 32 + q * 8 + d];
    }
    float ps = 0.f, pd = 0.f;
#pragma unroll
    for (int d = 0; d < 8; d++) {
        ps += acc[d] * as2[q * 8 + d];
        pd += acc[d] * ad2[q * 8 + d];
    }
    ps += __shfl_xor(ps, 1); ps += __shfl_xor(ps, 2);
    pd += __shfl_xor(pd, 1); pd += __shfl_xor(pd, 2);
    int g = base + node;
    if (g < n) {
#pragma unroll
        for (int d = 0; d < 8; d += 2)
            h2bf[(size_t)g * 16 + q * 4 + (d >> 1)] = f2bf_pack(acc[d], acc[d + 1]);
        if (q == 0) { als2[g] = ps; ald2[g] = pd; }
    }
}

// ---------------- layer 2 aggregation: wave per dst node, 4 edges/step, bf16 gather -------
__global__ void __launch_bounds__(256) k_agg2(
        const unsigned* __restrict__ h2bf, const float* __restrict__ als2,
        const float* __restrict__ ald2, const int* __restrict__ rp,
        const int* __restrict__ esrc, const float* __restrict__ b2,
        float* __restrict__ out, int n) {
    __shared__ int ss[4][64];
    __shared__ float sw[4][64];
    int wslot = threadIdx.x >> 6;
    int lane = threadIdx.x & 63;
    int wid = blockIdx.x * 4 + wslot;
    if (wid >= n) return;
    int beg = rp[wid], end = rp[wid + 1];
    float ad = ald2[wid];
    int eg = lane >> 4;      // edge subgroup 0..3
    int cp = lane & 15;      // channel pair: channels 2cp, 2cp+1
    float2 acc = make_float2(0.f, 0.f);
    float z = 0.f;
    for (int cb = beg; cb < end; cb += 64) {
        int cnt = end - cb;
        if (cnt > 64) cnt = 64;
        if (lane < cnt) {
            int s = esrc[cb + lane];
            ss[wslot][lane] = s;
            sw[wslot][lane] = __expf(lrelu(als2[s] + ad));
        }
        for (int j = eg; j < cnt; j += 4) {
            int s = ss[wslot][j];
            float w = sw[wslot][j];
            z += w;
            unsigned p = h2bf[(size_t)s * 16 + cp];
            acc.x = fmaf(w, bf_lo(p), acc.x);
            acc.y = fmaf(w, bf_hi(p), acc.y);
        }
    }
    // reduce across the 4 edge subgroups
    z += __shfl_xor(z, 16);   z += __shfl_xor(z, 32);
    acc.x += __shfl_xor(acc.x, 16); acc.x += __shfl_xor(acc.x, 32);
    acc.y += __shfl_xor(acc.y, 16); acc.y += __shfl_xor(acc.y, 32);
    if (lane < 16) {
        float inv = 1.f / (z + 1e-16f);
        const float2 bv = *reinterpret_cast<const float2*>(&b2[2 * cp]);
        float2 o = make_float2(acc.x * inv + bv.x, acc.y * inv + bv.y);
        *reinterpret_cast<float2*>(&out[(size_t)wid * 32 + 2 * cp]) = o;
    }
}

// ---------------- graph boundaries via binary search on sorted batch ----------------
__global__ void k_bounds(const int* __restrict__ batch, int* __restrict__ bnd, int n, int g) {
    int i = blockIdx.x * blockDim.x + threadIdx.x;
    if (i > g) return;
    if (i == g) { bnd[g] = n; return; }
    int lo = 0, hi = n;
    while (lo < hi) {
        int mid = (lo + hi) >> 1;
        if (batch[mid] < i) lo = mid + 1; else hi = mid;
    }
    bnd[i] = lo;
}

// ---------------- BN2+ELU + mean pool + classifier: wave per graph ----------------
__global__ void k_pool(const float* __restrict__ x, const float* __restrict__ AB2,
                       const int* __restrict__ bnd, const float* __restrict__ Wc,
                       const float* __restrict__ bc, float* __restrict__ out, int G_) {
    int wid = (blockIdx.x * blockDim.x + threadIdx.x) >> 6;
    int lane = threadIdx.x & 63;
    if (wid >= G_) return;
    int beg = bnd[wid], end = bnd[wid + 1];
    int half = lane >> 5, f = lane & 31;
    float A = AB2[f], B = AB2[32 + f];
    float acc = 0.f;
    for (int r = beg + half; r < end; r += 2) {
        float v = x[(size_t)r * 32 + f] * A + B;
        acc += elu(v);
    }
    acc += __shfl_xor(acc, 32);
    float cntf = (float)((end - beg) > 1 ? (end - beg) : 1);
    float embv = acc / cntf;
    float p0 = embv * Wc[f * 2], p1 = embv * Wc[f * 2 + 1];
#pragma unroll
    for (int o = 1; o < 32; o <<= 1) {
        p0 += __shfl_xor(p0, o);
        p1 += __shfl_xor(p1, o);
    }
    if (lane == 0) {
        out[wid * 2] = p0 + bc[0];
        out[wid * 2 + 1] = p1 + bc[1];
    }
}

extern "C" void kernel_launch(void* const* d_in, const int* in_sizes, int n_in,
                              void* d_out, int out_size, void* d_ws, size_t ws_size,
                              hipStream_t stream) {
    const float* x = (const float*)d_in[0];
    const int* ei = (const int*)d_in[1];
    const int* batch = (const int*)d_in[2];
    const float* W1 = (const float*)d_in[3];
    const float* as1 = (const float*)d_in[4];
    const float* ad1 = (const float*)d_in[5];
    const float* b1 = (const float*)d_in[6];
    const float* g1 = (const float*)d_in[7];
    const float* be1 = (const float*)d_in[8];
    const float* W2 = (const float*)d_in[9];
    const float* as2 = (const float*)d_in[10];
    const float* ad2 = (const float*)d_in[11];
    const float* b2 = (const float*)d_in[12];
    const float* g2 = (const float*)d_in[13];
    const float* be2 = (const float*)d_in[14];
    const float* Wc = (const float*)d_in[15];
    const float* bc = (const float*)d_in[16];
    float* out = (float*)d_out;

    const int N = in_sizes[0] / 2;
    const int E = in_sizes[1] / 2;
    const int G = out_size / 2;
    const int Etot = E + N;
    const int B = (N + 511) >> 9;     // buckets of 512 dst nodes (<= 256)
    const int CH = (E + P - 1) / P;   // edges per radix block

    // workspace layout
    char* w = (char*)d_ws;
    size_t off = 0;
    auto alloc = [&](size_t bytes) { void* p = w + off; off = (off + bytes + 255) & ~(size_t)255; return p; };
    unsigned* h1bf = (unsigned*)alloc((size_t)N * 64 * 4);   // N x 128 bf16 packed
    float* h_ag1 = (float*)alloc((size_t)N * 128 * 4);
    float* als1 = (float*)alloc((size_t)N * 4 * 4);
    float* ald1 = (float*)alloc((size_t)N * 4 * 4);
    int* esrc = (int*)alloc((size_t)Etot * 4);
    unsigned* staged = (unsigned*)alloc((size_t)E * 4);
    int* rp = (int*)alloc((size_t)(N + 1) * 4);
    int* ghist = (int*)alloc((size_t)P * BNUM * 4);
    int* goff = (int*)alloc((size_t)P * BNUM * 4);
    int* sbase = (int*)alloc((BNUM + 1) * 4);
    float* partials = (float*)alloc((size_t)STATS_BLOCKS * 256 * 4);
    float* AB1 = (float*)alloc(256 * 4);
    float* AB2 = (float*)alloc(64 * 4);
    int* bnd = (int*)alloc((size_t)(G + 1) * 4);
    // reuse h1bf's space after layer-1 aggregation (N*64 uints available):
    unsigned* h2bf = h1bf;                                   // N*16 uints (N x 32 bf16)
    float* als2 = (float*)(h1bf + (size_t)N * 16);           // N floats
    float* ald2 = (float*)(h1bf + (size_t)N * 17);           // N floats
    float* out2 = (float*)(h1bf + (size_t)N * 18);           // N*32 floats (ends at N*50)

    // 1. node transform layer 1
    k_node1<<<(N * 4 + 255) / 256, 256, 0, stream>>>(x, W1, as1, ad1, h1bf, als1, ald1, N);
    // 2. radix pass A: per-block histograms
    k_hist<<<P, 256, 0, stream>>>(ei, ghist, E, CH);
    // 3. radix pass B: bucket-major exclusive scan -> goff, sbase, rp[N]
    k_gscan<<<1, 1024, 0, stream>>>(ghist, goff, sbase, rp, N, E);
    // 4. radix pass C: scatter to block-private ranges
    k_scatter3<<<P, 256, 0, stream>>>(ei, goff, staged, E, CH);
    // 5. per-bucket finalize: rp + esrc (+self loops)
    k_bucket<<<B, 512, 0, stream>>>(staged, sbase, rp, esrc, N);
    // 6. layer 1 aggregation (wave per node)
    k_agg1<<<(N + 3) / 4, 256, 0, stream>>>(h1bf, als1, ald1, rp, esrc, b1, h_ag1, N);
    // 7. BN1 stats
    k_stats<<<STATS_BLOCKS, 256, 0, stream>>>(h_ag1, partials, N, 128);
    k_stats2<<<1, 512, 0, stream>>>(partials, g1, be1, AB1, N, 128, STATS_BLOCKS);
    // 8. node transform layer 2 (BN+ELU fused)
    k_node2<<<(N + 63) / 64, 256, 0, stream>>>(h_ag1, AB1, W2, as2, ad2, h2bf, als2, ald2, N);
    // 9. layer 2 aggregation
    k_agg2<<<(N + 3) / 4, 256, 0, stream>>>(h2bf, als2, ald2, rp, esrc, b2, out2, N);
    // 10. BN2 stats
    k_stats<<<STATS_BLOCKS, 256, 0, stream>>>(out2, partials, N, 32);
    k_stats2<<<1, 512, 0, stream>>>(partials, g2, be2, AB2, N, 32, STATS_BLOCKS);
    // 11. graph boundaries
    k_bounds<<<(G + 256) / 256, 256, 0, stream>>>(batch, bnd, N, G);
    // 12. BN2+ELU + pool + classifier
    k_pool<<<(G * 64 + 255) / 256, 256, 0, stream>>>(out2, AB2, bnd, Wc, bc, out, G);
}

// Round 7
// 381.356 us; speedup vs baseline: 3.0192x; 1.0682x over previous
//
#include <hip/hip_runtime.h>
#include <hip/hip_bf16.h>
#include <math.h>

#define HEADS 4
#define HID 32
#define EMB 32
#define SLOPE 0.2f
#define BN_EPS 1e-5f
#define STATS_BLOCKS 256
#define BNUM 256   // bucket array size (actual B = ceil(N/512) <= 256)
#define P 256      // radix blocks

__device__ __forceinline__ float lrelu(float x) { return x > 0.f ? x : SLOPE * x; }
__device__ __forceinline__ float elu(float x) { return x > 0.f ? x : expm1f(x); }

// RNE float->bf16 and pack/unpack helpers
__device__ __forceinline__ unsigned f2bf_pack(float a, float b) {
    unsigned ua = __float_as_uint(a);
    unsigned ub = __float_as_uint(b);
    unsigned ra = (ua + 0x7fffu + ((ua >> 16) & 1u)) >> 16;
    unsigned rb = (ub + 0x7fffu + ((ub >> 16) & 1u)) >> 16;
    return ra | (rb << 16);
}
__device__ __forceinline__ float bf_lo(unsigned p) { return __uint_as_float(p << 16); }
__device__ __forceinline__ float bf_hi(unsigned p) { return __uint_as_float(p & 0xffff0000u); }

// ---------------- node transform layer 1: h1 = x @ W1 (packed bf16); al_src/al_dst ----------------
__global__ void k_node1(const float* __restrict__ x, const float* __restrict__ W1,
                        const float* __restrict__ as1, const float* __restrict__ ad1,
                        unsigned* __restrict__ h1bf, float* __restrict__ als, float* __restrict__ ald,
                        int n) {
    int idx = blockIdx.x * blockDim.x + threadIdx.x;
    int node = idx >> 2, hd = idx & 3;
    if (node >= n) return;
    float x0 = x[node * 2], x1 = x[node * 2 + 1];
    float ps = 0.f, pd = 0.f;
#pragma unroll
    for (int d = 0; d < 32; d += 2) {
        int c = hd * 32 + d;
        float v0 = x0 * W1[c] + x1 * W1[128 + c];
        float v1 = x0 * W1[c + 1] + x1 * W1[128 + c + 1];
        ps += v0 * as1[c] + v1 * as1[c + 1];
        pd += v0 * ad1[c] + v1 * ad1[c + 1];
        h1bf[(size_t)node * 64 + hd * 16 + (d >> 1)] = f2bf_pack(v0, v1);
    }
    als[node * 4 + hd] = ps;
    ald[node * 4 + hd] = pd;
}

// ---------------- pass A: per-block histogram, p-major ghist[p][b] ----------------
__global__ void __launch_bounds__(256) k_hist(const int* __restrict__ ei,
                                              int* __restrict__ ghist, int E_, int CH) {
    __shared__ int h[BNUM];
    int t = threadIdx.x, p = blockIdx.x;
    h[t] = 0;
    __syncthreads();
    int beg = p * CH, end = beg + CH;
    if (end > E_) end = E_;
    for (int e = beg + t; e < end; e += 256) atomicAdd(&h[ei[E_ + e] >> 9], 1);
    __syncthreads();
    ghist[p * BNUM + t] = h[t];  // coalesced
}

// ---------------- pass B: exclusive scan of ghist in bucket-major order ----------------
__global__ void __launch_bounds__(1024) k_gscan(const int* __restrict__ ghist,
                                                int* __restrict__ goff, int* __restrict__ sbase,
                                                int* __restrict__ rp, int N_, int E_) {
    __shared__ int s[1024];
    int t = threadIdx.x;
    const int PER = (BNUM * P) / 1024;  // 64
    int b0 = t >> 2;
    int p0 = (t & 3) * PER;
    int v[PER];
    int sum = 0;
#pragma unroll
    for (int k = 0; k < PER; k++) {
        v[k] = ghist[(p0 + k) * BNUM + b0];
        sum += v[k];
    }
    s[t] = sum;
    __syncthreads();
    for (int off = 1; off < 1024; off <<= 1) {
        int a = (t >= off) ? s[t - off] : 0;
        __syncthreads();
        s[t] += a;
        __syncthreads();
    }
    int run = s[t] - sum;
#pragma unroll
    for (int k = 0; k < PER; k++) {
        if (p0 + k == 0) sbase[b0] = run;
        goff[(p0 + k) * BNUM + b0] = run;
        run += v[k];
    }
    if (t == 0) {
        sbase[BNUM] = E_;
        rp[N_] = E_ + N_;
    }
}

// ---------------- pass C: scatter into block-private per-bucket ranges ----------------
__global__ void __launch_bounds__(256) k_scatter3(const int* __restrict__ ei,
                                                  const int* __restrict__ goff,
                                                  unsigned* __restrict__ staged,
                                                  int E_, int CH) {
    __shared__ int loff[BNUM];
    __shared__ int lpos[BNUM];
    int t = threadIdx.x, p = blockIdx.x;
    loff[t] = goff[p * BNUM + t];
    lpos[t] = 0;
    __syncthreads();
    int beg = p * CH, end = beg + CH;
    if (end > E_) end = E_;
    for (int e = beg + t; e < end; e += 256) {
        int s = ei[e], d = ei[E_ + e];
        int b = d >> 9;
        unsigned pk = ((unsigned)s << 9) | (unsigned)(d & 511);
        int pos = loff[b] + atomicAdd(&lpos[b], 1);
        staged[pos] = pk;
    }
}

// ---------------- per-bucket finalize: count, scan, write rp + esrc (+self loops) -------
__global__ void __launch_bounds__(512) k_bucket(const unsigned* __restrict__ staged,
                                                const int* __restrict__ sbase,
                                                int* __restrict__ rp, int* __restrict__ esrc,
                                                int N_) {
    int b = blockIdx.x;
    int n0 = b << 9;
    int nn = N_ - n0;
    if (nn > 512) nn = 512;
    if (nn <= 0) return;
    __shared__ int lc[512];
    __shared__ int sc[512];
    __shared__ int wpos[512];
    int t = threadIdx.x;
    lc[t] = 0;
    __syncthreads();
    int sb = sbase[b];
    int m = sbase[b + 1] - sb;
    int eb = sb + (b << 9);
    for (int i = t; i < m; i += 512) atomicAdd(&lc[staged[sb + i] & 511], 1);
    __syncthreads();
    sc[t] = lc[t];
    __syncthreads();
    for (int off = 1; off < 512; off <<= 1) {
        int a = (t >= off) ? sc[t - off] : 0;
        __syncthreads();
        sc[t] += a;
        __syncthreads();
    }
    if (t < nn) {
        int r = eb + (sc[t] - lc[t]) + t;
        rp[n0 + t] = r;
        wpos[t] = r;
        esrc[r + lc[t]] = n0 + t;          // self loop at final slot (no atomic)
    }
    __syncthreads();
    for (int i = t; i < m; i += 512) {
        unsigned p = staged[sb + i];
        int q = atomicAdd(&wpos[p & 511], 1);
        esrc[q] = (int)(p >> 9);
    }
}

// ---------------- layer 1 aggregation: 16-lane group per dst node, uint4 bf16 gather ----
// No max pass: logits are O(1) here so exp() cannot overflow; softmax is shift-invariant.
// 4 nodes per wave; lane cp covers channels 8cp..8cp+7 (head = cp>>2).
__global__ void __launch_bounds__(256) k_agg1(
        const unsigned* __restrict__ h1bf, const float* __restrict__ als1,
        const float* __restrict__ ald1, const int* __restrict__ rp,
        const int* __restrict__ esrc, const float* __restrict__ b1,
        float* __restrict__ out, int n) {
    __shared__ int ss[4][4][16];
    __shared__ float4 sw4[4][4][17];   // padded stride 17 -> group weight reads on disjoint banks
    int wslot = threadIdx.x >> 6;
    int lane = threadIdx.x & 63;
    int g = lane >> 4;       // group within wave
    int cp = lane & 15;      // lane within group: dwords 4cp..4cp+3 of the row
    int hd = cp >> 2;        // head of this lane's channels
    int wid = blockIdx.x * 16 + wslot * 4 + g;
    if (wid >= n) return;
    int beg = rp[wid], end = rp[wid + 1];
    const float4 ad = *reinterpret_cast<const float4*>(&ald1[wid * 4]);
    float a0 = 0.f, a1 = 0.f, a2 = 0.f, a3 = 0.f, a4 = 0.f, a5 = 0.f, a6 = 0.f, a7 = 0.f;
    float z = 0.f;
    const uint4* __restrict__ hrow = reinterpret_cast<const uint4*>(h1bf);
    for (int cb = beg; cb < end; cb += 16) {
        int cnt = end - cb;
        if (cnt > 16) cnt = 16;
        if (cp < cnt) {
            int s = esrc[cb + cp];
            const float4 a = *reinterpret_cast<const float4*>(&als1[s * 4]);
            ss[wslot][g][cp] = s;
            float4 wv;
            wv.x = __expf(lrelu(a.x + ad.x));
            wv.y = __expf(lrelu(a.y + ad.y));
            wv.z = __expf(lrelu(a.z + ad.z));
            wv.w = __expf(lrelu(a.w + ad.w));
            sw4[wslot][g][cp] = wv;
        }
        // wave-private LDS slots: in-wave lgkmcnt ordering suffices, no barrier
#pragma unroll 2
        for (int j = 0; j < cnt; j++) {
            int s = ss[wslot][g][j];
            float wgt = reinterpret_cast<const float*>(&sw4[wslot][g][j])[hd];
            z += wgt;
            uint4 p = hrow[(size_t)s * 16 + cp];
            a0 = fmaf(wgt, bf_lo(p.x), a0);
            a1 = fmaf(wgt, bf_hi(p.x), a1);
            a2 = fmaf(wgt, bf_lo(p.y), a2);
            a3 = fmaf(wgt, bf_hi(p.y), a3);
            a4 = fmaf(wgt, bf_lo(p.z), a4);
            a5 = fmaf(wgt, bf_hi(p.z), a5);
            a6 = fmaf(wgt, bf_lo(p.w), a6);
            a7 = fmaf(wgt, bf_hi(p.w), a7);
        }
    }
    float inv = 1.f / (z + 1e-16f);   // z is uniform across the 16-lane group
    const float4 bv0 = *reinterpret_cast<const float4*>(&b1[8 * cp]);
    const float4 bv1 = *reinterpret_cast<const float4*>(&b1[8 * cp + 4]);
    float4 o0 = make_float4(a0 * inv + bv0.x, a1 * inv + bv0.y, a2 * inv + bv0.z, a3 * inv + bv0.w);
    float4 o1 = make_float4(a4 * inv + bv1.x, a5 * inv + bv1.y, a6 * inv + bv1.z, a7 * inv + bv1.w);
    *reinterpret_cast<float4*>(&out[(size_t)wid * 128 + 8 * cp]) = o0;
    *reinterpret_cast<float4*>(&out[(size_t)wid * 128 + 8 * cp + 4]) = o1;
}

// ---------------- BN stats: stage 1 (deterministic tree) ----------------
__global__ void k_stats(const float* __restrict__ x, float* __restrict__ partials,
                        int n, int C) {
    int t = threadIdx.x;
    int c = t & (C - 1);
    int rr = t / C;
    int RPB = 256 / C;
    float s = 0.f, s2 = 0.f;
    for (int r = blockIdx.x * RPB + rr; r < n; r += gridDim.x * RPB) {
        float v = x[(size_t)r * C + c];
        s += v;
        s2 += v * v;
    }
    __shared__ float ls[256], ls2[256];
    ls[t] = s;
    ls2[t] = s2;
    __syncthreads();
    if (rr == 0) {
        for (int j = 1; j < RPB; j++) { s += ls[j * C + c]; s2 += ls2[j * C + c]; }
        partials[(size_t)blockIdx.x * 2 * C + c] = s;
        partials[(size_t)blockIdx.x * 2 * C + C + c] = s2;
    }
}
// ---------------- BN stats stage 2: parallel finalize (512 threads) ----------------
__global__ void k_stats2(const float* __restrict__ partials, const float* __restrict__ gamma,
                         const float* __restrict__ beta, float* __restrict__ AB,
                         int n, int C, int nb) {
    __shared__ float ls[512], ls2[512];
    int t = threadIdx.x;
    int R = 512 / C;
    int c = t & (C - 1);
    int r = t / C;
    float s = 0.f, s2 = 0.f;
    for (int b = r; b < nb; b += R) {
        s += partials[(size_t)b * 2 * C + c];
        s2 += partials[(size_t)b * 2 * C + C + c];
    }
    ls[t] = s;
    ls2[t] = s2;
    __syncthreads();
    for (int step = R >> 1; step > 0; step >>= 1) {
        if (r < step) {
            ls[t] += ls[t + step * C];
            ls2[t] += ls2[t + step * C];
        }
        __syncthreads();
    }
    if (r == 0) {
        float mu = ls[t] / n;
        float var = ls2[t] / n - mu * mu;
        float inv = rsqrtf(var + BN_EPS);
        float A = gamma[c] * inv;
        AB[c] = A;
        AB[C + c] = beta[c] - mu * A;
    }
}

// ---------------- node transform layer 2: BN+ELU then @ W2 (bf16 out), attn logits --------
__global__ void k_node2(const float* __restrict__ hin, const float* __restrict__ AB1,
                        const float* __restrict__ W2, const float* __restrict__ as2,
                        const float* __restrict__ ad2, unsigned* __restrict__ h2bf,
                        float* __restrict__ als2, float* __restrict__ ald2, int n) {
    __shared__ float sy[64 * 129];
    __shared__ float sw[128 * 32];
    int t = threadIdx.x;
    for (int i = t; i < 128 * 32; i += 256) sw[i] = W2[i];
    int base = blockIdx.x * 64;
    for (int i = t; i < 64 * 128; i += 256) {
        int r = i >> 7, c = i & 127;
        float v = 0.f;
        if (base + r < n) {
            float xx = hin[(size_t)(base + r) * 128 + c];
            v = elu(xx * AB1[c] + AB1[128 + c]);
        }
        sy[r * 129 + c] = v;
    }
    __syncthreads();
    int node = t >> 2, q = t & 3;
    float acc[8];
#pragma unroll
    for (int d = 0; d < 8; d++) acc[d] = 0.f;
    for (int k = 0; k < 128; k++) {
        float y = sy[node * 129 + k];
#pragma unroll
        for (int d = 0; d < 8; d++) acc[d] += y * sw[k * 32 + q * 8 + d];
    }
    float ps = 0.f, pd = 0.f;
#pragma unroll
    for (int d = 0; d < 8; d++) {
        ps += acc[d] * as2[q * 8 + d];
        pd += acc[d] * ad2[q * 8 + d];
    }
    ps += __shfl_xor(ps, 1); ps += __shfl_xor(ps, 2);
    pd += __shfl_xor(pd, 1); pd += __shfl_xor(pd, 2);
    int g = base + node;
    if (g < n) {
#pragma unroll
        for (int d = 0; d < 8; d += 2)
            h2bf[(size_t)g * 16 + q * 4 + (d >> 1)] = f2bf_pack(acc[d], acc[d + 1]);
        if (q == 0) { als2[g] = ps; ald2[g] = pd; }
    }
}

// ---------------- layer 2 aggregation: 8-lane group per dst node, uint2 bf16 gather -------
// 8 nodes per wave; lane e covers channels 4e..4e+3.
__global__ void __launch_bounds__(256) k_agg2(
        const unsigned* __restrict__ h2bf, const float* __restrict__ als2,
        const float* __restrict__ ald2, const int* __restrict__ rp,
        const int* __restrict__ esrc, const float* __restrict__ b2,
        float* __restrict__ out, int n) {
    __shared__ int ss2[4][8][9];    // pad 9 -> group broadcasts on disjoint banks
    __shared__ float swv[4][8][9];
    int wslot = threadIdx.x >> 6;
    int lane = threadIdx.x & 63;
    int g = lane >> 3;       // group within wave
    int e = lane & 7;        // lane within group: dwords 2e,2e+1 of the row
    int wid = blockIdx.x * 32 + wslot * 8 + g;
    if (wid >= n) return;
    int beg = rp[wid], end = rp[wid + 1];
    float ad = ald2[wid];
    float a0 = 0.f, a1 = 0.f, a2 = 0.f, a3 = 0.f;
    float z = 0.f;
    const uint2* __restrict__ hrow = reinterpret_cast<const uint2*>(h2bf);
    for (int cb = beg; cb < end; cb += 8) {
        int cnt = end - cb;
        if (cnt > 8) cnt = 8;
        if (e < cnt) {
            int s = esrc[cb + e];
            ss2[wslot][g][e] = s;
            swv[wslot][g][e] = __expf(lrelu(als2[s] + ad));
        }
#pragma unroll 2
        for (int j = 0; j < cnt; j++) {
            int s = ss2[wslot][g][j];
            float wgt = swv[wslot][g][j];
            z += wgt;
            uint2 p = hrow[(size_t)s * 8 + e];
            a0 = fmaf(wgt, bf_lo(p.x), a0);
            a1 = fmaf(wgt, bf_hi(p.x), a1);
            a2 = fmaf(wgt, bf_lo(p.y), a2);
            a3 = fmaf(wgt, bf_hi(p.y), a3);
        }
    }
    float inv = 1.f / (z + 1e-16f);   // z uniform across the 8-lane group
    const float4 bv = *reinterpret_cast<const float4*>(&b2[4 * e]);
    float4 o = make_float4(a0 * inv + bv.x, a1 * inv + bv.y, a2 * inv + bv.z, a3 * inv + bv.w);
    *reinterpret_cast<float4*>(&out[(size_t)wid * 32 + 4 * e]) = o;
}

// ---------------- graph boundaries via binary search on sorted batch ----------------
__global__ void k_bounds(const int* __restrict__ batch, int* __restrict__ bnd, int n, int g) {
    int i = blockIdx.x * blockDim.x + threadIdx.x;
    if (i > g) return;
    if (i == g) { bnd[g] = n; return; }
    int lo = 0, hi = n;
    while (lo < hi) {
        int mid = (lo + hi) >> 1;
        if (batch[mid] < i) lo = mid + 1; else hi = mid;
    }
    bnd[i] = lo;
}

// ---------------- BN2+ELU + mean pool + classifier: wave per graph ----------------
__global__ void k_pool(const float* __restrict__ x, const float* __restrict__ AB2,
                       const int* __restrict__ bnd, const float* __restrict__ Wc,
                       const float* __restrict__ bc, float* __restrict__ out, int G_) {
    int wid = (blockIdx.x * blockDim.x + threadIdx.x) >> 6;
    int lane = threadIdx.x & 63;
    if (wid >= G_) return;
    int beg = bnd[wid], end = bnd[wid + 1];
    int half = lane >> 5, f = lane & 31;
    float A = AB2[f], B = AB2[32 + f];
    float acc = 0.f;
    for (int r = beg + half; r < end; r += 2) {
        float v = x[(size_t)r * 32 + f] * A + B;
        acc += elu(v);
    }
    acc += __shfl_xor(acc, 32);
    float cntf = (float)((end - beg) > 1 ? (end - beg) : 1);
    float embv = acc / cntf;
    float p0 = embv * Wc[f * 2], p1 = embv * Wc[f * 2 + 1];
#pragma unroll
    for (int o = 1; o < 32; o <<= 1) {
        p0 += __shfl_xor(p0, o);
        p1 += __shfl_xor(p1, o);
    }
    if (lane == 0) {
        out[wid * 2] = p0 + bc[0];
        out[wid * 2 + 1] = p1 + bc[1];
    }
}

extern "C" void kernel_launch(void* const* d_in, const int* in_sizes, int n_in,
                              void* d_out, int out_size, void* d_ws, size_t ws_size,
                              hipStream_t stream) {
    const float* x = (const float*)d_in[0];
    const int* ei = (const int*)d_in[1];
    const int* batch = (const int*)d_in[2];
    const float* W1 = (const float*)d_in[3];
    const float* as1 = (const float*)d_in[4];
    const float* ad1 = (const float*)d_in[5];
    const float* b1 = (const float*)d_in[6];
    const float* g1 = (const float*)d_in[7];
    const float* be1 = (const float*)d_in[8];
    const float* W2 = (const float*)d_in[9];
    const float* as2 = (const float*)d_in[10];
    const float* ad2 = (const float*)d_in[11];
    const float* b2 = (const float*)d_in[12];
    const float* g2 = (const float*)d_in[13];
    const float* be2 = (const float*)d_in[14];
    const float* Wc = (const float*)d_in[15];
    const float* bc = (const float*)d_in[16];
    float* out = (float*)d_out;

    const int N = in_sizes[0] / 2;
    const int E = in_sizes[1] / 2;
    const int G = out_size / 2;
    const int Etot = E + N;
    const int B = (N + 511) >> 9;     // buckets of 512 dst nodes (<= 256)
    const int CH = (E + P - 1) / P;   // edges per radix block

    // workspace layout
    char* w = (char*)d_ws;
    size_t off = 0;
    auto alloc = [&](size_t bytes) { void* p = w + off; off = (off + bytes + 255) & ~(size_t)255; return p; };
    unsigned* h1bf = (unsigned*)alloc((size_t)N * 64 * 4);   // N x 128 bf16 packed
    float* h_ag1 = (float*)alloc((size_t)N * 128 * 4);
    float* als1 = (float*)alloc((size_t)N * 4 * 4);
    float* ald1 = (float*)alloc((size_t)N * 4 * 4);
    int* esrc = (int*)alloc((size_t)Etot * 4);
    unsigned* staged = (unsigned*)alloc((size_t)E * 4);
    int* rp = (int*)alloc((size_t)(N + 1) * 4);
    int* ghist = (int*)alloc((size_t)P * BNUM * 4);
    int* goff = (int*)alloc((size_t)P * BNUM * 4);
    int* sbase = (int*)alloc((BNUM + 1) * 4);
    float* partials = (float*)alloc((size_t)STATS_BLOCKS * 256 * 4);
    float* AB1 = (float*)alloc(256 * 4);
    float* AB2 = (float*)alloc(64 * 4);
    int* bnd = (int*)alloc((size_t)(G + 1) * 4);
    // reuse h1bf's space after layer-1 aggregation (N*64 uints available):
    unsigned* h2bf = h1bf;                                   // N*16 uints (N x 32 bf16)
    float* als2 = (float*)(h1bf + (size_t)N * 16);           // N floats
    float* ald2 = (float*)(h1bf + (size_t)N * 17);           // N floats
    float* out2 = (float*)(h1bf + (size_t)N * 18);           // N*32 floats (ends at N*50)

    // 1. node transform layer 1
    k_node1<<<(N * 4 + 255) / 256, 256, 0, stream>>>(x, W1, as1, ad1, h1bf, als1, ald1, N);
    // 2. radix pass A: per-block histograms
    k_hist<<<P, 256, 0, stream>>>(ei, ghist, E, CH);
    // 3. radix pass B: bucket-major exclusive scan -> goff, sbase, rp[N]
    k_gscan<<<1, 1024, 0, stream>>>(ghist, goff, sbase, rp, N, E);
    // 4. radix pass C: scatter to block-private ranges
    k_scatter3<<<P, 256, 0, stream>>>(ei, goff, staged, E, CH);
    // 5. per-bucket finalize: rp + esrc (+self loops)
    k_bucket<<<B, 512, 0, stream>>>(staged, sbase, rp, esrc, N);
    // 6. layer 1 aggregation (16-lane group per node)
    k_agg1<<<(N + 15) / 16, 256, 0, stream>>>(h1bf, als1, ald1, rp, esrc, b1, h_ag1, N);
    // 7. BN1 stats
    k_stats<<<STATS_BLOCKS, 256, 0, stream>>>(h_ag1, partials, N, 128);
    k_stats2<<<1, 512, 0, stream>>>(partials, g1, be1, AB1, N, 128, STATS_BLOCKS);
    // 8. node transform layer 2 (BN+ELU fused)
    k_node2<<<(N + 63) / 64, 256, 0, stream>>>(h_ag1, AB1, W2, as2, ad2, h2bf, als2, ald2, N);
    // 9. layer 2 aggregation (8-lane group per node)
    k_agg2<<<(N + 31) / 32, 256, 0, stream>>>(h2bf, als2, ald2, rp, esrc, b2, out2, N);
    // 10. BN2 stats
    k_stats<<<STATS_BLOCKS, 256, 0, stream>>>(out2, partials, N, 32);
    k_stats2<<<1, 512, 0, stream>>>(partials, g2, be2, AB2, N, 32, STATS_BLOCKS);
    // 11. graph boundaries
    k_bounds<<<(G + 256) / 256, 256, 0, stream>>>(batch, bnd, N, G);
    // 12. BN2+ELU + pool + classifier
    k_pool<<<(G * 64 + 255) / 256, 256, 0, stream>>>(out2, AB2, bnd, Wc, bc, out, G);
}

// Round 8
// 337.791 us; speedup vs baseline: 3.4086x; 1.1290x over previous
//
#include <hip/hip_runtime.h>
#include <hip/hip_bf16.h>
#include <math.h>

#define HEADS 4
#define HID 32
#define EMB 32
#define SLOPE 0.2f
#define BN_EPS 1e-5f
#define STATS_BLOCKS 256
#define BNUM 256   // bucket array size (actual B = ceil(N/512) <= 256)
#define P 256      // radix blocks

__device__ __forceinline__ float lrelu(float x) { return x > 0.f ? x : SLOPE * x; }
__device__ __forceinline__ float elu(float x) { return x > 0.f ? x : expm1f(x); }

// RNE float->bf16 and pack/unpack helpers
__device__ __forceinline__ unsigned f2bf_pack(float a, float b) {
    unsigned ua = __float_as_uint(a);
    unsigned ub = __float_as_uint(b);
    unsigned ra = (ua + 0x7fffu + ((ua >> 16) & 1u)) >> 16;
    unsigned rb = (ub + 0x7fffu + ((ub >> 16) & 1u)) >> 16;
    return ra | (rb << 16);
}
__device__ __forceinline__ float bf_lo(unsigned p) { return __uint_as_float(p << 16); }
__device__ __forceinline__ float bf_hi(unsigned p) { return __uint_as_float(p & 0xffff0000u); }

// ---------------- node transform layer 1: h1 = x @ W1 (packed bf16); al_src/al_dst ----------------
__global__ void k_node1(const float* __restrict__ x, const float* __restrict__ W1,
                        const float* __restrict__ as1, const float* __restrict__ ad1,
                        unsigned* __restrict__ h1bf, float* __restrict__ als, float* __restrict__ ald,
                        int n) {
    int idx = blockIdx.x * blockDim.x + threadIdx.x;
    int node = idx >> 2, hd = idx & 3;
    if (node >= n) return;
    float x0 = x[node * 2], x1 = x[node * 2 + 1];
    float ps = 0.f, pd = 0.f;
#pragma unroll
    for (int d = 0; d < 32; d += 2) {
        int c = hd * 32 + d;
        float v0 = x0 * W1[c] + x1 * W1[128 + c];
        float v1 = x0 * W1[c + 1] + x1 * W1[128 + c + 1];
        ps += v0 * as1[c] + v1 * as1[c + 1];
        pd += v0 * ad1[c] + v1 * ad1[c + 1];
        h1bf[(size_t)node * 64 + hd * 16 + (d >> 1)] = f2bf_pack(v0, v1);
    }
    als[node * 4 + hd] = ps;
    ald[node * 4 + hd] = pd;
}

// ---------------- pass A: per-block histogram, p-major ghist[p][b] ----------------
__global__ void __launch_bounds__(256) k_hist(const int* __restrict__ ei,
                                              int* __restrict__ ghist, int E_, int CH) {
    __shared__ int h[BNUM];
    int t = threadIdx.x, p = blockIdx.x;
    h[t] = 0;
    __syncthreads();
    int beg = p * CH, end = beg + CH;
    if (end > E_) end = E_;
    for (int e = beg + t; e < end; e += 256) atomicAdd(&h[ei[E_ + e] >> 9], 1);
    __syncthreads();
    ghist[p * BNUM + t] = h[t];  // coalesced
}

// ---------------- pass B: exclusive scan of ghist in bucket-major order ----------------
__global__ void __launch_bounds__(1024) k_gscan(const int* __restrict__ ghist,
                                                int* __restrict__ goff, int* __restrict__ sbase,
                                                int* __restrict__ rp, int N_, int E_) {
    __shared__ int s[1024];
    int t = threadIdx.x;
    const int PER = (BNUM * P) / 1024;  // 64
    int b0 = t >> 2;
    int p0 = (t & 3) * PER;
    int v[PER];
    int sum = 0;
#pragma unroll
    for (int k = 0; k < PER; k++) {
        v[k] = ghist[(p0 + k) * BNUM + b0];
        sum += v[k];
    }
    s[t] = sum;
    __syncthreads();
    for (int off = 1; off < 1024; off <<= 1) {
        int a = (t >= off) ? s[t - off] : 0;
        __syncthreads();
        s[t] += a;
        __syncthreads();
    }
    int run = s[t] - sum;
#pragma unroll
    for (int k = 0; k < PER; k++) {
        if (p0 + k == 0) sbase[b0] = run;
        goff[(p0 + k) * BNUM + b0] = run;
        run += v[k];
    }
    if (t == 0) {
        sbase[BNUM] = E_;
        rp[N_] = E_ + N_;
    }
}

// ---------------- pass C: scatter into block-private per-bucket ranges ----------------
__global__ void __launch_bounds__(256) k_scatter3(const int* __restrict__ ei,
                                                  const int* __restrict__ goff,
                                                  unsigned* __restrict__ staged,
                                                  int E_, int CH) {
    __shared__ int loff[BNUM];
    __shared__ int lpos[BNUM];
    int t = threadIdx.x, p = blockIdx.x;
    loff[t] = goff[p * BNUM + t];
    lpos[t] = 0;
    __syncthreads();
    int beg = p * CH, end = beg + CH;
    if (end > E_) end = E_;
    for (int e = beg + t; e < end; e += 256) {
        int s = ei[e], d = ei[E_ + e];
        int b = d >> 9;
        unsigned pk = ((unsigned)s << 9) | (unsigned)(d & 511);
        int pos = loff[b] + atomicAdd(&lpos[b], 1);
        staged[pos] = pk;
    }
}

// ---------------- per-bucket finalize: count, scan, write rp + esrc (+self loops) -------
__global__ void __launch_bounds__(512) k_bucket(const unsigned* __restrict__ staged,
                                                const int* __restrict__ sbase,
                                                int* __restrict__ rp, int* __restrict__ esrc,
                                                int N_) {
    int b = blockIdx.x;
    int n0 = b << 9;
    int nn = N_ - n0;
    if (nn > 512) nn = 512;
    if (nn <= 0) return;
    __shared__ int lc[512];
    __shared__ int sc[512];
    __shared__ int wpos[512];
    int t = threadIdx.x;
    lc[t] = 0;
    __syncthreads();
    int sb = sbase[b];
    int m = sbase[b + 1] - sb;
    int eb = sb + (b << 9);
    for (int i = t; i < m; i += 512) atomicAdd(&lc[staged[sb + i] & 511], 1);
    __syncthreads();
    sc[t] = lc[t];
    __syncthreads();
    for (int off = 1; off < 512; off <<= 1) {
        int a = (t >= off) ? sc[t - off] : 0;
        __syncthreads();
        sc[t] += a;
        __syncthreads();
    }
    if (t < nn) {
        int r = eb + (sc[t] - lc[t]) + t;
        rp[n0 + t] = r;
        wpos[t] = r;
        esrc[r + lc[t]] = n0 + t;          // self loop at final slot (no atomic)
    }
    __syncthreads();
    for (int i = t; i < m; i += 512) {
        unsigned p = staged[sb + i];
        int q = atomicAdd(&wpos[p & 511], 1);
        esrc[q] = (int)(p >> 9);
    }
}

// ---------------- layer 1 aggregation: 16-lane group per dst node, uint4 bf16 gather ----
// No max pass: logits are O(1) here so exp() cannot overflow; softmax is shift-invariant.
// 4 nodes per wave; lane cp covers channels 8cp..8cp+7 (head = cp>>2). 4-edge unroll for MLP.
__global__ void __launch_bounds__(256) k_agg1(
        const unsigned* __restrict__ h1bf, const float* __restrict__ als1,
        const float* __restrict__ ald1, const int* __restrict__ rp,
        const int* __restrict__ esrc, const float* __restrict__ b1,
        float* __restrict__ out, int n) {
    __shared__ int ss[4][4][16];
    __shared__ float4 sw4[4][4][17];   // padded stride 17 -> group weight reads on disjoint banks
    int wslot = threadIdx.x >> 6;
    int lane = threadIdx.x & 63;
    int g = lane >> 4;       // group within wave
    int cp = lane & 15;      // lane within group: dwords 4cp..4cp+3 of the row
    int hd = cp >> 2;        // head of this lane's channels
    int wid = blockIdx.x * 16 + wslot * 4 + g;
    if (wid >= n) return;
    int beg = rp[wid], end = rp[wid + 1];
    const float4 ad = *reinterpret_cast<const float4*>(&ald1[wid * 4]);
    float a0 = 0.f, a1 = 0.f, a2 = 0.f, a3 = 0.f, a4 = 0.f, a5 = 0.f, a6 = 0.f, a7 = 0.f;
    float z = 0.f;
    const uint4* __restrict__ hrow = reinterpret_cast<const uint4*>(h1bf);
    for (int cb = beg; cb < end; cb += 16) {
        int cnt = end - cb;
        if (cnt > 16) cnt = 16;
        if (cp < cnt) {
            int s = esrc[cb + cp];
            const float4 a = *reinterpret_cast<const float4*>(&als1[s * 4]);
            ss[wslot][g][cp] = s;
            float4 wv;
            wv.x = __expf(lrelu(a.x + ad.x));
            wv.y = __expf(lrelu(a.y + ad.y));
            wv.z = __expf(lrelu(a.z + ad.z));
            wv.w = __expf(lrelu(a.w + ad.w));
            sw4[wslot][g][cp] = wv;
        }
        // wave-private LDS slots: in-wave lgkmcnt ordering suffices, no barrier
        int j = 0;
        for (; j + 4 <= cnt; j += 4) {
            int s0 = ss[wslot][g][j];
            int s1 = ss[wslot][g][j + 1];
            int s2 = ss[wslot][g][j + 2];
            int s3 = ss[wslot][g][j + 3];
            float w0 = reinterpret_cast<const float*>(&sw4[wslot][g][j])[hd];
            float w1 = reinterpret_cast<const float*>(&sw4[wslot][g][j + 1])[hd];
            float w2 = reinterpret_cast<const float*>(&sw4[wslot][g][j + 2])[hd];
            float w3 = reinterpret_cast<const float*>(&sw4[wslot][g][j + 3])[hd];
            uint4 p0 = hrow[(size_t)s0 * 16 + cp];
            uint4 p1 = hrow[(size_t)s1 * 16 + cp];
            uint4 p2 = hrow[(size_t)s2 * 16 + cp];
            uint4 p3 = hrow[(size_t)s3 * 16 + cp];
            z += w0 + w1 + w2 + w3;
            a0 = fmaf(w0, bf_lo(p0.x), a0); a1 = fmaf(w0, bf_hi(p0.x), a1);
            a2 = fmaf(w0, bf_lo(p0.y), a2); a3 = fmaf(w0, bf_hi(p0.y), a3);
            a4 = fmaf(w0, bf_lo(p0.z), a4); a5 = fmaf(w0, bf_hi(p0.z), a5);
            a6 = fmaf(w0, bf_lo(p0.w), a6); a7 = fmaf(w0, bf_hi(p0.w), a7);
            a0 = fmaf(w1, bf_lo(p1.x), a0); a1 = fmaf(w1, bf_hi(p1.x), a1);
            a2 = fmaf(w1, bf_lo(p1.y), a2); a3 = fmaf(w1, bf_hi(p1.y), a3);
            a4 = fmaf(w1, bf_lo(p1.z), a4); a5 = fmaf(w1, bf_hi(p1.z), a5);
            a6 = fmaf(w1, bf_lo(p1.w), a6); a7 = fmaf(w1, bf_hi(p1.w), a7);
            a0 = fmaf(w2, bf_lo(p2.x), a0); a1 = fmaf(w2, bf_hi(p2.x), a1);
            a2 = fmaf(w2, bf_lo(p2.y), a2); a3 = fmaf(w2, bf_hi(p2.y), a3);
            a4 = fmaf(w2, bf_lo(p2.z), a4); a5 = fmaf(w2, bf_hi(p2.z), a5);
            a6 = fmaf(w2, bf_lo(p2.w), a6); a7 = fmaf(w2, bf_hi(p2.w), a7);
            a0 = fmaf(w3, bf_lo(p3.x), a0); a1 = fmaf(w3, bf_hi(p3.x), a1);
            a2 = fmaf(w3, bf_lo(p3.y), a2); a3 = fmaf(w3, bf_hi(p3.y), a3);
            a4 = fmaf(w3, bf_lo(p3.z), a4); a5 = fmaf(w3, bf_hi(p3.z), a5);
            a6 = fmaf(w3, bf_lo(p3.w), a6); a7 = fmaf(w3, bf_hi(p3.w), a7);
        }
        for (; j < cnt; j++) {
            int s = ss[wslot][g][j];
            float wgt = reinterpret_cast<const float*>(&sw4[wslot][g][j])[hd];
            z += wgt;
            uint4 p = hrow[(size_t)s * 16 + cp];
            a0 = fmaf(wgt, bf_lo(p.x), a0); a1 = fmaf(wgt, bf_hi(p.x), a1);
            a2 = fmaf(wgt, bf_lo(p.y), a2); a3 = fmaf(wgt, bf_hi(p.y), a3);
            a4 = fmaf(wgt, bf_lo(p.z), a4); a5 = fmaf(wgt, bf_hi(p.z), a5);
            a6 = fmaf(wgt, bf_lo(p.w), a6); a7 = fmaf(wgt, bf_hi(p.w), a7);
        }
    }
    float inv = 1.f / (z + 1e-16f);   // z is uniform across the 16-lane group
    const float4 bv0 = *reinterpret_cast<const float4*>(&b1[8 * cp]);
    const float4 bv1 = *reinterpret_cast<const float4*>(&b1[8 * cp + 4]);
    float4 o0 = make_float4(a0 * inv + bv0.x, a1 * inv + bv0.y, a2 * inv + bv0.z, a3 * inv + bv0.w);
    float4 o1 = make_float4(a4 * inv + bv1.x, a5 * inv + bv1.y, a6 * inv + bv1.z, a7 * inv + bv1.w);
    *reinterpret_cast<float4*>(&out[(size_t)wid * 128 + 8 * cp]) = o0;
    *reinterpret_cast<float4*>(&out[(size_t)wid * 128 + 8 * cp + 4]) = o1;
}

// ---------------- BN stats: stage 1 (deterministic tree, float4 loads) ----------------
__global__ void k_stats(const float* __restrict__ x, float* __restrict__ partials,
                        int n, int C) {
    int t = threadIdx.x;
    int G4 = C >> 2;            // float4 groups per row (32 for C=128, 8 for C=32)
    int c4 = t & (G4 - 1);
    int rr = t / G4;
    int RPB = 256 / G4;
    float sx = 0.f, sy = 0.f, sz = 0.f, sw_ = 0.f;
    float qx = 0.f, qy = 0.f, qz = 0.f, qw = 0.f;
    for (int r = blockIdx.x * RPB + rr; r < n; r += gridDim.x * RPB) {
        float4 v = *reinterpret_cast<const float4*>(&x[(size_t)r * C + 4 * c4]);
        sx += v.x; sy += v.y; sz += v.z; sw_ += v.w;
        qx += v.x * v.x; qy += v.y * v.y; qz += v.z * v.z; qw += v.w * v.w;
    }
    __shared__ float4 ls[256], ls2[256];
    ls[t] = make_float4(sx, sy, sz, sw_);
    ls2[t] = make_float4(qx, qy, qz, qw);
    __syncthreads();
    if (rr == 0) {
        for (int j = 1; j < RPB; j++) {
            float4 a = ls[j * G4 + c4], b = ls2[j * G4 + c4];
            sx += a.x; sy += a.y; sz += a.z; sw_ += a.w;
            qx += b.x; qy += b.y; qz += b.z; qw += b.w;
        }
        *reinterpret_cast<float4*>(&partials[(size_t)blockIdx.x * 2 * C + 4 * c4]) =
            make_float4(sx, sy, sz, sw_);
        *reinterpret_cast<float4*>(&partials[(size_t)blockIdx.x * 2 * C + C + 4 * c4]) =
            make_float4(qx, qy, qz, qw);
    }
}
// ---------------- BN stats stage 2: parallel finalize (512 threads) ----------------
__global__ void k_stats2(const float* __restrict__ partials, const float* __restrict__ gamma,
                         const float* __restrict__ beta, float* __restrict__ AB,
                         int n, int C, int nb) {
    __shared__ float ls[512], ls2[512];
    int t = threadIdx.x;
    int R = 512 / C;
    int c = t & (C - 1);
    int r = t / C;
    float s = 0.f, s2 = 0.f;
    for (int b = r; b < nb; b += R) {
        s += partials[(size_t)b * 2 * C + c];
        s2 += partials[(size_t)b * 2 * C + C + c];
    }
    ls[t] = s;
    ls2[t] = s2;
    __syncthreads();
    for (int step = R >> 1; step > 0; step >>= 1) {
        if (r < step) {
            ls[t] += ls[t + step * C];
            ls2[t] += ls2[t + step * C];
        }
        __syncthreads();
    }
    if (r == 0) {
        float mu = ls[t] / n;
        float var = ls2[t] / n - mu * mu;
        float inv = rsqrtf(var + BN_EPS);
        float A = gamma[c] * inv;
        AB[c] = A;
        AB[C + c] = beta[c] - mu * A;
    }
}

// ---------------- node transform layer 2: BN+ELU then @ W2 (bf16 out), attn logits --------
// 2 k-steps per iteration: one ds_read_b64 for y, halving sy LDS traffic.
__global__ void k_node2(const float* __restrict__ hin, const float* __restrict__ AB1,
                        const float* __restrict__ W2, const float* __restrict__ as2,
                        const float* __restrict__ ad2, unsigned* __restrict__ h2bf,
                        float* __restrict__ als2, float* __restrict__ ald2, int n) {
    __shared__ float sy[64 * 130];
    __shared__ float sw[128 * 32];
    int t = threadIdx.x;
    for (int i = t; i < 128 * 32; i += 256) sw[i] = W2[i];
    int base = blockIdx.x * 64;
    for (int i = t; i < 64 * 128; i += 256) {
        int r = i >> 7, c = i & 127;
        float v = 0.f;
        if (base + r < n) {
            float xx = hin[(size_t)(base + r) * 128 + c];
            v = elu(xx * AB1[c] + AB1[128 + c]);
        }
        sy[r * 130 + c] = v;
    }
    __syncthreads();
    int node = t >> 2, q = t & 3;
    float acc[8];
#pragma unroll
    for (int d = 0; d < 8; d++) acc[d] = 0.f;
    for (int k2 = 0; k2 < 64; k2++) {
        float2 y = *reinterpret_cast<const float2*>(&sy[node * 130 + 2 * k2]);
        const float4 w0a = *reinterpret_cast<const float4*>(&sw[(2 * k2) * 32 + q * 8]);
        const float4 w0b = *reinterpret_cast<const float4*>(&sw[(2 * k2) * 32 + q * 8 + 4]);
        const float4 w1a = *reinterpret_cast<const float4*>(&sw[(2 * k2 + 1) * 32 + q * 8]);
        const float4 w1b = *reinterpret_cast<const float4*>(&sw[(2 * k2 + 1) * 32 + q * 8 + 4]);
        acc[0] = fmaf(y.x, w0a.x, fmaf(y.y, w1a.x, acc[0]));
        acc[1] = fmaf(y.x, w0a.y, fmaf(y.y, w1a.y, acc[1]));
        acc[2] = fmaf(y.x, w0a.z, fmaf(y.y, w1a.z, acc[2]));
        acc[3] = fmaf(y.x, w0a.w, fmaf(y.y, w1a.w, acc[3]));
        acc[4] = fmaf(y.x, w0b.x, fmaf(y.y, w1b.x, acc[4]));
        acc[5] = fmaf(y.x, w0b.y, fmaf(y.y, w1b.y, acc[5]));
        acc[6] = fmaf(y.x, w0b.z, fmaf(y.y, w1b.z, acc[6]));
        acc[7] = fmaf(y.x, w0b.w, fmaf(y.y, w1b.w, acc[7]));
    }
    float ps = 0.f, pd = 0.f;
#pragma unroll
    for (int d = 0; d < 8; d++) {
        ps += acc[d] * as2[q * 8 + d];
        pd += acc[d] * ad2[q * 8 + d];
    }
    ps += __shfl_xor(ps, 1); ps += __shfl_xor(ps, 2);
    pd += __shfl_xor(pd, 1); pd += __shfl_xor(pd, 2);
    int g = base + node;
    if (g < n) {
#pragma unroll
        for (int d = 0; d < 8; d += 2)
            h2bf[(size_t)g * 16 + q * 4 + (d >> 1)] = f2bf_pack(acc[d], acc[d + 1]);
        if (q == 0) { als2[g] = ps; ald2[g] = pd; }
    }
}

// ---------------- layer 2 aggregation: 8-lane group per dst node, uint2 bf16 gather -------
// 8 nodes per wave; lane e covers channels 4e..4e+3. 4-edge unroll for MLP.
__global__ void __launch_bounds__(256) k_agg2(
        const unsigned* __restrict__ h2bf, const float* __restrict__ als2,
        const float* __restrict__ ald2, const int* __restrict__ rp,
        const int* __restrict__ esrc, const float* __restrict__ b2,
        float* __restrict__ out, int n) {
    __shared__ int ss2[4][8][9];    // pad 9 -> group broadcasts on disjoint banks
    __shared__ float swv[4][8][9];
    int wslot = threadIdx.x >> 6;
    int lane = threadIdx.x & 63;
    int g = lane >> 3;       // group within wave
    int e = lane & 7;        // lane within group: dwords 2e,2e+1 of the row
    int wid = blockIdx.x * 32 + wslot * 8 + g;
    if (wid >= n) return;
    int beg = rp[wid], end = rp[wid + 1];
    float ad = ald2[wid];
    float a0 = 0.f, a1 = 0.f, a2 = 0.f, a3 = 0.f;
    float z = 0.f;
    const uint2* __restrict__ hrow = reinterpret_cast<const uint2*>(h2bf);
    for (int cb = beg; cb < end; cb += 8) {
        int cnt = end - cb;
        if (cnt > 8) cnt = 8;
        if (e < cnt) {
            int s = esrc[cb + e];
            ss2[wslot][g][e] = s;
            swv[wslot][g][e] = __expf(lrelu(als2[s] + ad));
        }
        int j = 0;
        for (; j + 4 <= cnt; j += 4) {
            int s0 = ss2[wslot][g][j];
            int s1 = ss2[wslot][g][j + 1];
            int s2 = ss2[wslot][g][j + 2];
            int s3 = ss2[wslot][g][j + 3];
            float w0 = swv[wslot][g][j];
            float w1 = swv[wslot][g][j + 1];
            float w2 = swv[wslot][g][j + 2];
            float w3 = swv[wslot][g][j + 3];
            uint2 p0 = hrow[(size_t)s0 * 8 + e];
            uint2 p1 = hrow[(size_t)s1 * 8 + e];
            uint2 p2 = hrow[(size_t)s2 * 8 + e];
            uint2 p3 = hrow[(size_t)s3 * 8 + e];
            z += w0 + w1 + w2 + w3;
            a0 = fmaf(w0, bf_lo(p0.x), a0); a1 = fmaf(w0, bf_hi(p0.x), a1);
            a2 = fmaf(w0, bf_lo(p0.y), a2); a3 = fmaf(w0, bf_hi(p0.y), a3);
            a0 = fmaf(w1, bf_lo(p1.x), a0); a1 = fmaf(w1, bf_hi(p1.x), a1);
            a2 = fmaf(w1, bf_lo(p1.y), a2); a3 = fmaf(w1, bf_hi(p1.y), a3);
            a0 = fmaf(w2, bf_lo(p2.x), a0); a1 = fmaf(w2, bf_hi(p2.x), a1);
            a2 = fmaf(w2, bf_lo(p2.y), a2); a3 = fmaf(w2, bf_hi(p2.y), a3);
            a0 = fmaf(w3, bf_lo(p3.x), a0); a1 = fmaf(w3, bf_hi(p3.x), a1);
            a2 = fmaf(w3, bf_lo(p3.y), a2); a3 = fmaf(w3, bf_hi(p3.y), a3);
        }
        for (; j < cnt; j++) {
            int s = ss2[wslot][g][j];
            float wgt = swv[wslot][g][j];
            z += wgt;
            uint2 p = hrow[(size_t)s * 8 + e];
            a0 = fmaf(wgt, bf_lo(p.x), a0);
            a1 = fmaf(wgt, bf_hi(p.x), a1);
            a2 = fmaf(wgt, bf_lo(p.y), a2);
            a3 = fmaf(wgt, bf_hi(p.y), a3);
        }
    }
    float inv = 1.f / (z + 1e-16f);   // z uniform across the 8-lane group
    const float4 bv = *reinterpret_cast<const float4*>(&b2[4 * e]);
    float4 o = make_float4(a0 * inv + bv.x, a1 * inv + bv.y, a2 * inv + bv.z, a3 * inv + bv.w);
    *reinterpret_cast<float4*>(&out[(size_t)wid * 32 + 4 * e]) = o;
}

// ---------------- BN2+ELU + mean pool + classifier: wave per graph (inline bounds) -------
__global__ void k_pool(const float* __restrict__ x, const float* __restrict__ AB2,
                       const int* __restrict__ batch, const float* __restrict__ Wc,
                       const float* __restrict__ bc, float* __restrict__ out, int n, int G_) {
    int wid = (blockIdx.x * blockDim.x + threadIdx.x) >> 6;
    int lane = threadIdx.x & 63;
    if (wid >= G_) return;
    // binary search graph boundaries (redundant per lane; sorted batch)
    int lo = 0, hi = n;
    while (lo < hi) {
        int mid = (lo + hi) >> 1;
        if (batch[mid] < wid) lo = mid + 1; else hi = mid;
    }
    int beg = lo;
    hi = n;
    while (lo < hi) {
        int mid = (lo + hi) >> 1;
        if (batch[mid] < wid + 1) lo = mid + 1; else hi = mid;
    }
    int end = lo;
    int half = lane >> 5, f = lane & 31;
    float A = AB2[f], B = AB2[32 + f];
    float acc = 0.f;
    for (int r = beg + half; r < end; r += 2) {
        float v = x[(size_t)r * 32 + f] * A + B;
        acc += elu(v);
    }
    acc += __shfl_xor(acc, 32);
    float cntf = (float)((end - beg) > 1 ? (end - beg) : 1);
    float embv = acc / cntf;
    float p0 = embv * Wc[f * 2], p1 = embv * Wc[f * 2 + 1];
#pragma unroll
    for (int o = 1; o < 32; o <<= 1) {
        p0 += __shfl_xor(p0, o);
        p1 += __shfl_xor(p1, o);
    }
    if (lane == 0) {
        out[wid * 2] = p0 + bc[0];
        out[wid * 2 + 1] = p1 + bc[1];
    }
}

extern "C" void kernel_launch(void* const* d_in, const int* in_sizes, int n_in,
                              void* d_out, int out_size, void* d_ws, size_t ws_size,
                              hipStream_t stream) {
    const float* x = (const float*)d_in[0];
    const int* ei = (const int*)d_in[1];
    const int* batch = (const int*)d_in[2];
    const float* W1 = (const float*)d_in[3];
    const float* as1 = (const float*)d_in[4];
    const float* ad1 = (const float*)d_in[5];
    const float* b1 = (const float*)d_in[6];
    const float* g1 = (const float*)d_in[7];
    const float* be1 = (const float*)d_in[8];
    const float* W2 = (const float*)d_in[9];
    const float* as2 = (const float*)d_in[10];
    const float* ad2 = (const float*)d_in[11];
    const float* b2 = (const float*)d_in[12];
    const float* g2 = (const float*)d_in[13];
    const float* be2 = (const float*)d_in[14];
    const float* Wc = (const float*)d_in[15];
    const float* bc = (const float*)d_in[16];
    float* out = (float*)d_out;

    const int N = in_sizes[0] / 2;
    const int E = in_sizes[1] / 2;
    const int G = out_size / 2;
    const int Etot = E + N;
    const int B = (N + 511) >> 9;     // buckets of 512 dst nodes (<= 256)
    const int CH = (E + P - 1) / P;   // edges per radix block

    // workspace layout
    char* w = (char*)d_ws;
    size_t off = 0;
    auto alloc = [&](size_t bytes) { void* p = w + off; off = (off + bytes + 255) & ~(size_t)255; return p; };
    unsigned* h1bf = (unsigned*)alloc((size_t)N * 64 * 4);   // N x 128 bf16 packed
    float* h_ag1 = (float*)alloc((size_t)N * 128 * 4);
    float* als1 = (float*)alloc((size_t)N * 4 * 4);
    float* ald1 = (float*)alloc((size_t)N * 4 * 4);
    int* esrc = (int*)alloc((size_t)Etot * 4);
    unsigned* staged = (unsigned*)alloc((size_t)E * 4);
    int* rp = (int*)alloc((size_t)(N + 1) * 4);
    int* ghist = (int*)alloc((size_t)P * BNUM * 4);
    int* goff = (int*)alloc((size_t)P * BNUM * 4);
    int* sbase = (int*)alloc((BNUM + 1) * 4);
    float* partials = (float*)alloc((size_t)STATS_BLOCKS * 256 * 4);
    float* AB1 = (float*)alloc(256 * 4);
    float* AB2 = (float*)alloc(64 * 4);
    // reuse h1bf's space after layer-1 aggregation (N*64 uints available):
    unsigned* h2bf = h1bf;                                   // N*16 uints (N x 32 bf16)
    float* als2 = (float*)(h1bf + (size_t)N * 16);           // N floats
    float* ald2 = (float*)(h1bf + (size_t)N * 17);           // N floats
    float* out2 = (float*)(h1bf + (size_t)N * 18);           // N*32 floats (ends at N*50)

    // 1. node transform layer 1
    k_node1<<<(N * 4 + 255) / 256, 256, 0, stream>>>(x, W1, as1, ad1, h1bf, als1, ald1, N);
    // 2. radix pass A: per-block histograms
    k_hist<<<P, 256, 0, stream>>>(ei, ghist, E, CH);
    // 3. radix pass B: bucket-major exclusive scan -> goff, sbase, rp[N]
    k_gscan<<<1, 1024, 0, stream>>>(ghist, goff, sbase, rp, N, E);
    // 4. radix pass C: scatter to block-private ranges
    k_scatter3<<<P, 256, 0, stream>>>(ei, goff, staged, E, CH);
    // 5. per-bucket finalize: rp + esrc (+self loops)
    k_bucket<<<B, 512, 0, stream>>>(staged, sbase, rp, esrc, N);
    // 6. layer 1 aggregation (16-lane group per node, 4-edge unroll)
    k_agg1<<<(N + 15) / 16, 256, 0, stream>>>(h1bf, als1, ald1, rp, esrc, b1, h_ag1, N);
    // 7. BN1 stats
    k_stats<<<STATS_BLOCKS, 256, 0, stream>>>(h_ag1, partials, N, 128);
    k_stats2<<<1, 512, 0, stream>>>(partials, g1, be1, AB1, N, 128, STATS_BLOCKS);
    // 8. node transform layer 2 (BN+ELU fused)
    k_node2<<<(N + 63) / 64, 256, 0, stream>>>(h_ag1, AB1, W2, as2, ad2, h2bf, als2, ald2, N);
    // 9. layer 2 aggregation (8-lane group per node, 4-edge unroll)
    k_agg2<<<(N + 31) / 32, 256, 0, stream>>>(h2bf, als2, ald2, rp, esrc, b2, out2, N);
    // 10. BN2 stats
    k_stats<<<STATS_BLOCKS, 256, 0, stream>>>(out2, partials, N, 32);
    k_stats2<<<1, 512, 0, stream>>>(partials, g2, be2, AB2, N, 32, STATS_BLOCKS);
    // 11. BN2+ELU + pool + classifier (bounds inline)
    k_pool<<<(G * 64 + 255) / 256, 256, 0, stream>>>(out2, AB2, batch, Wc, bc, out, N, G);
}

// Round 9
// 264.335 us; speedup vs baseline: 4.3558x; 1.2779x over previous
//
#include <hip/hip_runtime.h>
#include <hip/hip_bf16.h>
#include <math.h>

#define HEADS 4
#define HID 32
#define EMB 32
#define SLOPE 0.2f
#define BN_EPS 1e-5f
#define STATS_BLOCKS 256
#define BNUM 256   // bucket array size (actual B = ceil(N/512) <= 256)
#define P 256      // radix blocks

__device__ __forceinline__ float lrelu(float x) { return x > 0.f ? x : SLOPE * x; }
__device__ __forceinline__ float elu(float x) { return x > 0.f ? x : expm1f(x); }

// RNE float->bf16 and pack/unpack helpers
__device__ __forceinline__ unsigned f2bf_pack(float a, float b) {
    unsigned ua = __float_as_uint(a);
    unsigned ub = __float_as_uint(b);
    unsigned ra = (ua + 0x7fffu + ((ua >> 16) & 1u)) >> 16;
    unsigned rb = (ub + 0x7fffu + ((ub >> 16) & 1u)) >> 16;
    return ra | (rb << 16);
}
__device__ __forceinline__ float bf_lo(unsigned p) { return __uint_as_float(p << 16); }
__device__ __forceinline__ float bf_hi(unsigned p) { return __uint_as_float(p & 0xffff0000u); }

// ---------------- tiny prep: Ms[2][4], Md[2][4] = per-head dot(W1 row, attn vec) ----------------
__global__ void k_prep(const float* __restrict__ W1, const float* __restrict__ as1,
                       const float* __restrict__ ad1, float* __restrict__ MsMd) {
    int t = threadIdx.x;
    if (t >= 16) return;
    int r = (t >> 2) & 1, h = t & 3;
    const float* a = (t >= 8) ? ad1 : as1;
    float s = 0.f;
#pragma unroll
    for (int d = 0; d < 32; d++) s += W1[r * 128 + h * 32 + d] * a[h * 32 + d];
    MsMd[t] = s;
}

// ---------------- pass A: per-block histogram, p-major ghist[p][b] ----------------
__global__ void __launch_bounds__(256) k_hist(const int* __restrict__ ei,
                                              int* __restrict__ ghist, int E_, int CH) {
    __shared__ int h[BNUM];
    int t = threadIdx.x, p = blockIdx.x;
    h[t] = 0;
    __syncthreads();
    int beg = p * CH, end = beg + CH;
    if (end > E_) end = E_;
    for (int e = beg + t; e < end; e += 256) atomicAdd(&h[ei[E_ + e] >> 9], 1);
    __syncthreads();
    ghist[p * BNUM + t] = h[t];  // coalesced
}

// ---------------- pass B: exclusive scan of ghist in bucket-major order ----------------
__global__ void __launch_bounds__(1024) k_gscan(const int* __restrict__ ghist,
                                                int* __restrict__ goff, int* __restrict__ sbase,
                                                int* __restrict__ rp, int N_, int E_) {
    __shared__ int s[1024];
    int t = threadIdx.x;
    const int PER = (BNUM * P) / 1024;  // 64
    int b0 = t >> 2;
    int p0 = (t & 3) * PER;
    int v[PER];
    int sum = 0;
#pragma unroll
    for (int k = 0; k < PER; k++) {
        v[k] = ghist[(p0 + k) * BNUM + b0];
        sum += v[k];
    }
    s[t] = sum;
    __syncthreads();
    for (int off = 1; off < 1024; off <<= 1) {
        int a = (t >= off) ? s[t - off] : 0;
        __syncthreads();
        s[t] += a;
        __syncthreads();
    }
    int run = s[t] - sum;
#pragma unroll
    for (int k = 0; k < PER; k++) {
        if (p0 + k == 0) sbase[b0] = run;
        goff[(p0 + k) * BNUM + b0] = run;
        run += v[k];
    }
    if (t == 0) {
        sbase[BNUM] = E_;
        rp[N_] = E_ + N_;
    }
}

// ---------------- pass C: scatter into block-private per-bucket ranges ----------------
__global__ void __launch_bounds__(256) k_scatter3(const int* __restrict__ ei,
                                                  const int* __restrict__ goff,
                                                  unsigned* __restrict__ staged,
                                                  int E_, int CH) {
    __shared__ int loff[BNUM];
    __shared__ int lpos[BNUM];
    int t = threadIdx.x, p = blockIdx.x;
    loff[t] = goff[p * BNUM + t];
    lpos[t] = 0;
    __syncthreads();
    int beg = p * CH, end = beg + CH;
    if (end > E_) end = E_;
    for (int e = beg + t; e < end; e += 256) {
        int s = ei[e], d = ei[E_ + e];
        int b = d >> 9;
        unsigned pk = ((unsigned)s << 9) | (unsigned)(d & 511);
        int pos = loff[b] + atomicAdd(&lpos[b], 1);
        staged[pos] = pk;
    }
}

// ---------------- per-bucket finalize: count, scan, write rp + esrc (+self loops) -------
__global__ void __launch_bounds__(512) k_bucket(const unsigned* __restrict__ staged,
                                                const int* __restrict__ sbase,
                                                int* __restrict__ rp, int* __restrict__ esrc,
                                                int N_) {
    int b = blockIdx.x;
    int n0 = b << 9;
    int nn = N_ - n0;
    if (nn > 512) nn = 512;
    if (nn <= 0) return;
    __shared__ int lc[512];
    __shared__ int sc[512];
    __shared__ int wpos[512];
    int t = threadIdx.x;
    lc[t] = 0;
    __syncthreads();
    int sb = sbase[b];
    int m = sbase[b + 1] - sb;
    int eb = sb + (b << 9);
    for (int i = t; i < m; i += 512) atomicAdd(&lc[staged[sb + i] & 511], 1);
    __syncthreads();
    sc[t] = lc[t];
    __syncthreads();
    for (int off = 1; off < 512; off <<= 1) {
        int a = (t >= off) ? sc[t - off] : 0;
        __syncthreads();
        sc[t] += a;
        __syncthreads();
    }
    if (t < nn) {
        int r = eb + (sc[t] - lc[t]) + t;
        rp[n0 + t] = r;
        wpos[t] = r;
        esrc[r + lc[t]] = n0 + t;          // self loop at final slot (no atomic)
    }
    __syncthreads();
    for (int i = t; i < m; i += 512) {
        unsigned p = staged[sb + i];
        int q = atomicAdd(&wpos[p & 511], 1);
        esrc[q] = (int)(p >> 9);
    }
}

// ---------------- layer 1 aggregation, FACTORIZED: 4 lanes per node (lane = head) ----------
// h1[s] = x0[s]*W1r0 + x1[s]*W1r1  (rank-2), so per head only z, sum(w*x0), sum(w*x1) are
// needed; the 128-channel output is reconstructed from W1 at the end. x (0.8 MB) is
// L2-resident, so the per-edge gather is cache-hit. No max pass (logits O(1), exp safe).
__global__ void __launch_bounds__(256) k_agg1f(
        const float* __restrict__ x, const int* __restrict__ rp,
        const int* __restrict__ esrc, const float* __restrict__ MsMd,
        const float* __restrict__ W1, const float* __restrict__ b1,
        float* __restrict__ out, int n) {
    __shared__ float sW[256];
    __shared__ float sb[128];
    __shared__ float sM[16];
    int t = threadIdx.x;
    sW[t] = W1[t];
    if (t < 128) sb[t] = b1[t];
    if (t < 16) sM[t] = MsMd[t];
    __syncthreads();
    int node = blockIdx.x * 64 + (t >> 2);
    int h = t & 3;
    if (node >= n) return;
    int beg = rp[node], end = rp[node + 1];
    const float2 xd = *reinterpret_cast<const float2*>(&x[(size_t)node * 2]);
    float ald = xd.x * sM[8 + h] + xd.y * sM[12 + h];
    float ms0 = sM[h], ms1 = sM[4 + h];
    float z = 0.f, sx = 0.f, sy = 0.f;
    for (int e = beg; e < end; e++) {
        int s = esrc[e];
        float2 xs = *reinterpret_cast<const float2*>(&x[(size_t)s * 2]);
        float al = xs.x * ms0 + xs.y * ms1;
        float w = __expf(lrelu(al + ald));
        z += w;
        sx = fmaf(w, xs.x, sx);
        sy = fmaf(w, xs.y, sy);
    }
    float inv = 1.f / (z + 1e-16f);
    sx *= inv;
    sy *= inv;
#pragma unroll
    for (int d = 0; d < 32; d += 4) {
        int c = h * 32 + d;
        const float4 w0 = *reinterpret_cast<const float4*>(&sW[c]);
        const float4 w1 = *reinterpret_cast<const float4*>(&sW[128 + c]);
        const float4 bb = *reinterpret_cast<const float4*>(&sb[c]);
        float4 o;
        o.x = fmaf(sx, w0.x, fmaf(sy, w1.x, bb.x));
        o.y = fmaf(sx, w0.y, fmaf(sy, w1.y, bb.y));
        o.z = fmaf(sx, w0.z, fmaf(sy, w1.z, bb.z));
        o.w = fmaf(sx, w0.w, fmaf(sy, w1.w, bb.w));
        *reinterpret_cast<float4*>(&out[(size_t)node * 128 + c]) = o;
    }
}

// ---------------- BN stats: stage 1 (deterministic tree, float4 loads) ----------------
__global__ void k_stats(const float* __restrict__ x, float* __restrict__ partials,
                        int n, int C) {
    int t = threadIdx.x;
    int G4 = C >> 2;            // float4 groups per row (32 for C=128, 8 for C=32)
    int c4 = t & (G4 - 1);
    int rr = t / G4;
    int RPB = 256 / G4;
    float sx = 0.f, sy = 0.f, sz = 0.f, sw_ = 0.f;
    float qx = 0.f, qy = 0.f, qz = 0.f, qw = 0.f;
    for (int r = blockIdx.x * RPB + rr; r < n; r += gridDim.x * RPB) {
        float4 v = *reinterpret_cast<const float4*>(&x[(size_t)r * C + 4 * c4]);
        sx += v.x; sy += v.y; sz += v.z; sw_ += v.w;
        qx += v.x * v.x; qy += v.y * v.y; qz += v.z * v.z; qw += v.w * v.w;
    }
    __shared__ float4 ls[256], ls2[256];
    ls[t] = make_float4(sx, sy, sz, sw_);
    ls2[t] = make_float4(qx, qy, qz, qw);
    __syncthreads();
    if (rr == 0) {
        for (int j = 1; j < RPB; j++) {
            float4 a = ls[j * G4 + c4], b = ls2[j * G4 + c4];
            sx += a.x; sy += a.y; sz += a.z; sw_ += a.w;
            qx += b.x; qy += b.y; qz += b.z; qw += b.w;
        }
        *reinterpret_cast<float4*>(&partials[(size_t)blockIdx.x * 2 * C + 4 * c4]) =
            make_float4(sx, sy, sz, sw_);
        *reinterpret_cast<float4*>(&partials[(size_t)blockIdx.x * 2 * C + C + 4 * c4]) =
            make_float4(qx, qy, qz, qw);
    }
}
// ---------------- BN stats stage 2: parallel finalize (512 threads) ----------------
__global__ void k_stats2(const float* __restrict__ partials, const float* __restrict__ gamma,
                         const float* __restrict__ beta, float* __restrict__ AB,
                         int n, int C, int nb) {
    __shared__ float ls[512], ls2[512];
    int t = threadIdx.x;
    int R = 512 / C;
    int c = t & (C - 1);
    int r = t / C;
    float s = 0.f, s2 = 0.f;
    for (int b = r; b < nb; b += R) {
        s += partials[(size_t)b * 2 * C + c];
        s2 += partials[(size_t)b * 2 * C + C + c];
    }
    ls[t] = s;
    ls2[t] = s2;
    __syncthreads();
    for (int step = R >> 1; step > 0; step >>= 1) {
        if (r < step) {
            ls[t] += ls[t + step * C];
            ls2[t] += ls2[t + step * C];
        }
        __syncthreads();
    }
    if (r == 0) {
        float mu = ls[t] / n;
        float var = ls2[t] / n - mu * mu;
        float inv = rsqrtf(var + BN_EPS);
        float A = gamma[c] * inv;
        AB[c] = A;
        AB[C + c] = beta[c] - mu * A;
    }
}

// ---------------- node transform layer 2: BN+ELU then @ W2 (bf16 out), attn logits --------
// 2 k-steps per iteration: one ds_read_b64 for y, halving sy LDS traffic.
__global__ void k_node2(const float* __restrict__ hin, const float* __restrict__ AB1,
                        const float* __restrict__ W2, const float* __restrict__ as2,
                        const float* __restrict__ ad2, unsigned* __restrict__ h2bf,
                        float* __restrict__ als2, float* __restrict__ ald2, int n) {
    __shared__ float sy[64 * 130];
    __shared__ float sw[128 * 32];
    int t = threadIdx.x;
    for (int i = t; i < 128 * 32; i += 256) sw[i] = W2[i];
    int base = blockIdx.x * 64;
    for (int i = t; i < 64 * 128; i += 256) {
        int r = i >> 7, c = i & 127;
        float v = 0.f;
        if (base + r < n) {
            float xx = hin[(size_t)(base + r) * 128 + c];
            v = elu(xx * AB1[c] + AB1[128 + c]);
        }
        sy[r * 130 + c] = v;
    }
    __syncthreads();
    int node = t >> 2, q = t & 3;
    float acc[8];
#pragma unroll
    for (int d = 0; d < 8; d++) acc[d] = 0.f;
    for (int k2 = 0; k2 < 64; k2++) {
        float2 y = *reinterpret_cast<const float2*>(&sy[node * 130 + 2 * k2]);
        const float4 w0a = *reinterpret_cast<const float4*>(&sw[(2 * k2) * 32 + q * 8]);
        const float4 w0b = *reinterpret_cast<const float4*>(&sw[(2 * k2) * 32 + q * 8 + 4]);
        const float4 w1a = *reinterpret_cast<const float4*>(&sw[(2 * k2 + 1) * 32 + q * 8]);
        const float4 w1b = *reinterpret_cast<const float4*>(&sw[(2 * k2 + 1) * 32 + q * 8 + 4]);
        acc[0] = fmaf(y.x, w0a.x, fmaf(y.y, w1a.x, acc[0]));
        acc[1] = fmaf(y.x, w0a.y, fmaf(y.y, w1a.y, acc[1]));
        acc[2] = fmaf(y.x, w0a.z, fmaf(y.y, w1a.z, acc[2]));
        acc[3] = fmaf(y.x, w0a.w, fmaf(y.y, w1a.w, acc[3]));
        acc[4] = fmaf(y.x, w0b.x, fmaf(y.y, w1b.x, acc[4]));
        acc[5] = fmaf(y.x, w0b.y, fmaf(y.y, w1b.y, acc[5]));
        acc[6] = fmaf(y.x, w0b.z, fmaf(y.y, w1b.z, acc[6]));
        acc[7] = fmaf(y.x, w0b.w, fmaf(y.y, w1b.w, acc[7]));
    }
    float ps = 0.f, pd = 0.f;
#pragma unroll
    for (int d = 0; d < 8; d++) {
        ps += acc[d] * as2[q * 8 + d];
        pd += acc[d] * ad2[q * 8 + d];
    }
    ps += __shfl_xor(ps, 1); ps += __shfl_xor(ps, 2);
    pd += __shfl_xor(pd, 1); pd += __shfl_xor(pd, 2);
    int g = base + node;
    if (g < n) {
#pragma unroll
        for (int d = 0; d < 8; d += 2)
            h2bf[(size_t)g * 16 + q * 4 + (d >> 1)] = f2bf_pack(acc[d], acc[d + 1]);
        if (q == 0) { als2[g] = ps; ald2[g] = pd; }
    }
}

// ---------------- layer 2 aggregation: 8-lane group per dst node, uint2 bf16 gather -------
// 8 nodes per wave; lane e covers channels 4e..4e+3. 4-edge unroll for MLP.
__global__ void __launch_bounds__(256) k_agg2(
        const unsigned* __restrict__ h2bf, const float* __restrict__ als2,
        const float* __restrict__ ald2, const int* __restrict__ rp,
        const int* __restrict__ esrc, const float* __restrict__ b2,
        float* __restrict__ out, int n) {
    __shared__ int ss2[4][8][9];    // pad 9 -> group broadcasts on disjoint banks
    __shared__ float swv[4][8][9];
    int wslot = threadIdx.x >> 6;
    int lane = threadIdx.x & 63;
    int g = lane >> 3;       // group within wave
    int e = lane & 7;        // lane within group: dwords 2e,2e+1 of the row
    int wid = blockIdx.x * 32 + wslot * 8 + g;
    if (wid >= n) return;
    int beg = rp[wid], end = rp[wid + 1];
    float ad = ald2[wid];
    float a0 = 0.f, a1 = 0.f, a2 = 0.f, a3 = 0.f;
    float z = 0.f;
    const uint2* __restrict__ hrow = reinterpret_cast<const uint2*>(h2bf);
    for (int cb = beg; cb < end; cb += 8) {
        int cnt = end - cb;
        if (cnt > 8) cnt = 8;
        if (e < cnt) {
            int s = esrc[cb + e];
            ss2[wslot][g][e] = s;
            swv[wslot][g][e] = __expf(lrelu(als2[s] + ad));
        }
        int j = 0;
        for (; j + 4 <= cnt; j += 4) {
            int s0 = ss2[wslot][g][j];
            int s1 = ss2[wslot][g][j + 1];
            int s2 = ss2[wslot][g][j + 2];
            int s3 = ss2[wslot][g][j + 3];
            float w0 = swv[wslot][g][j];
            float w1 = swv[wslot][g][j + 1];
            float w2 = swv[wslot][g][j + 2];
            float w3 = swv[wslot][g][j + 3];
            uint2 p0 = hrow[(size_t)s0 * 8 + e];
            uint2 p1 = hrow[(size_t)s1 * 8 + e];
            uint2 p2 = hrow[(size_t)s2 * 8 + e];
            uint2 p3 = hrow[(size_t)s3 * 8 + e];
            z += w0 + w1 + w2 + w3;
            a0 = fmaf(w0, bf_lo(p0.x), a0); a1 = fmaf(w0, bf_hi(p0.x), a1);
            a2 = fmaf(w0, bf_lo(p0.y), a2); a3 = fmaf(w0, bf_hi(p0.y), a3);
            a0 = fmaf(w1, bf_lo(p1.x), a0); a1 = fmaf(w1, bf_hi(p1.x), a1);
            a2 = fmaf(w1, bf_lo(p1.y), a2); a3 = fmaf(w1, bf_hi(p1.y), a3);
            a0 = fmaf(w2, bf_lo(p2.x), a0); a1 = fmaf(w2, bf_hi(p2.x), a1);
            a2 = fmaf(w2, bf_lo(p2.y), a2); a3 = fmaf(w2, bf_hi(p2.y), a3);
            a0 = fmaf(w3, bf_lo(p3.x), a0); a1 = fmaf(w3, bf_hi(p3.x), a1);
            a2 = fmaf(w3, bf_lo(p3.y), a2); a3 = fmaf(w3, bf_hi(p3.y), a3);
        }
        for (; j < cnt; j++) {
            int s = ss2[wslot][g][j];
            float wgt = swv[wslot][g][j];
            z += wgt;
            uint2 p = hrow[(size_t)s * 8 + e];
            a0 = fmaf(wgt, bf_lo(p.x), a0);
            a1 = fmaf(wgt, bf_hi(p.x), a1);
            a2 = fmaf(wgt, bf_lo(p.y), a2);
            a3 = fmaf(wgt, bf_hi(p.y), a3);
        }
    }
    float inv = 1.f / (z + 1e-16f);   // z uniform across the 8-lane group
    const float4 bv = *reinterpret_cast<const float4*>(&b2[4 * e]);
    float4 o = make_float4(a0 * inv + bv.x, a1 * inv + bv.y, a2 * inv + bv.z, a3 * inv + bv.w);
    *reinterpret_cast<float4*>(&out[(size_t)wid * 32 + 4 * e]) = o;
}

// ---------------- BN2+ELU + mean pool + classifier: wave per graph (inline bounds) -------
__global__ void k_pool(const float* __restrict__ x, const float* __restrict__ AB2,
                       const int* __restrict__ batch, const float* __restrict__ Wc,
                       const float* __restrict__ bc, float* __restrict__ out, int n, int G_) {
    int wid = (blockIdx.x * blockDim.x + threadIdx.x) >> 6;
    int lane = threadIdx.x & 63;
    if (wid >= G_) return;
    int lo = 0, hi = n;
    while (lo < hi) {
        int mid = (lo + hi) >> 1;
        if (batch[mid] < wid) lo = mid + 1; else hi = mid;
    }
    int beg = lo;
    hi = n;
    while (lo < hi) {
        int mid = (lo + hi) >> 1;
        if (batch[mid] < wid + 1) lo = mid + 1; else hi = mid;
    }
    int end = lo;
    int half = lane >> 5, f = lane & 31;
    float A = AB2[f], B = AB2[32 + f];
    float acc = 0.f;
    for (int r = beg + half; r < end; r += 2) {
        float v = x[(size_t)r * 32 + f] * A + B;
        acc += elu(v);
    }
    acc += __shfl_xor(acc, 32);
    float cntf = (float)((end - beg) > 1 ? (end - beg) : 1);
    float embv = acc / cntf;
    float p0 = embv * Wc[f * 2], p1 = embv * Wc[f * 2 + 1];
#pragma unroll
    for (int o = 1; o < 32; o <<= 1) {
        p0 += __shfl_xor(p0, o);
        p1 += __shfl_xor(p1, o);
    }
    if (lane == 0) {
        out[wid * 2] = p0 + bc[0];
        out[wid * 2 + 1] = p1 + bc[1];
    }
}

extern "C" void kernel_launch(void* const* d_in, const int* in_sizes, int n_in,
                              void* d_out, int out_size, void* d_ws, size_t ws_size,
                              hipStream_t stream) {
    const float* x = (const float*)d_in[0];
    const int* ei = (const int*)d_in[1];
    const int* batch = (const int*)d_in[2];
    const float* W1 = (const float*)d_in[3];
    const float* as1 = (const float*)d_in[4];
    const float* ad1 = (const float*)d_in[5];
    const float* b1 = (const float*)d_in[6];
    const float* g1 = (const float*)d_in[7];
    const float* be1 = (const float*)d_in[8];
    const float* W2 = (const float*)d_in[9];
    const float* as2 = (const float*)d_in[10];
    const float* ad2 = (const float*)d_in[11];
    const float* b2 = (const float*)d_in[12];
    const float* g2 = (const float*)d_in[13];
    const float* be2 = (const float*)d_in[14];
    const float* Wc = (const float*)d_in[15];
    const float* bc = (const float*)d_in[16];
    float* out = (float*)d_out;

    const int N = in_sizes[0] / 2;
    const int E = in_sizes[1] / 2;
    const int G = out_size / 2;
    const int Etot = E + N;
    const int B = (N + 511) >> 9;     // buckets of 512 dst nodes (<= 256)
    const int CH = (E + P - 1) / P;   // edges per radix block

    // workspace layout
    char* w = (char*)d_ws;
    size_t off = 0;
    auto alloc = [&](size_t bytes) { void* p = w + off; off = (off + bytes + 255) & ~(size_t)255; return p; };
    float* h_ag1 = (float*)alloc((size_t)N * 128 * 4);
    unsigned* l2buf = (unsigned*)alloc((size_t)N * 50 * 4);  // h2bf + als2 + ald2 + out2
    int* esrc = (int*)alloc((size_t)Etot * 4);
    unsigned* staged = (unsigned*)alloc((size_t)E * 4);
    int* rp = (int*)alloc((size_t)(N + 1) * 4);
    int* ghist = (int*)alloc((size_t)P * BNUM * 4);
    int* goff = (int*)alloc((size_t)P * BNUM * 4);
    int* sbase = (int*)alloc((BNUM + 1) * 4);
    float* partials = (float*)alloc((size_t)STATS_BLOCKS * 256 * 4);
    float* AB1 = (float*)alloc(256 * 4);
    float* AB2 = (float*)alloc(64 * 4);
    float* MsMd = (float*)alloc(64 * 4);
    unsigned* h2bf = l2buf;                                  // N*16 uints (N x 32 bf16)
    float* als2 = (float*)(l2buf + (size_t)N * 16);          // N floats
    float* ald2 = (float*)(l2buf + (size_t)N * 17);          // N floats
    float* out2 = (float*)(l2buf + (size_t)N * 18);          // N*32 floats

    // 1. tiny prep: factorized attention matrices
    k_prep<<<1, 64, 0, stream>>>(W1, as1, ad1, MsMd);
    // 2. radix pass A: per-block histograms
    k_hist<<<P, 256, 0, stream>>>(ei, ghist, E, CH);
    // 3. radix pass B: bucket-major exclusive scan -> goff, sbase, rp[N]
    k_gscan<<<1, 1024, 0, stream>>>(ghist, goff, sbase, rp, N, E);
    // 4. radix pass C: scatter to block-private ranges
    k_scatter3<<<P, 256, 0, stream>>>(ei, goff, staged, E, CH);
    // 5. per-bucket finalize: rp + esrc (+self loops)
    k_bucket<<<B, 512, 0, stream>>>(staged, sbase, rp, esrc, N);
    // 6. layer 1 aggregation, factorized (4 lanes per node)
    k_agg1f<<<(N + 63) / 64, 256, 0, stream>>>(x, rp, esrc, MsMd, W1, b1, h_ag1, N);
    // 7. BN1 stats
    k_stats<<<STATS_BLOCKS, 256, 0, stream>>>(h_ag1, partials, N, 128);
    k_stats2<<<1, 512, 0, stream>>>(partials, g1, be1, AB1, N, 128, STATS_BLOCKS);
    // 8. node transform layer 2 (BN+ELU fused)
    k_node2<<<(N + 63) / 64, 256, 0, stream>>>(h_ag1, AB1, W2, as2, ad2, h2bf, als2, ald2, N);
    // 9. layer 2 aggregation (8-lane group per node, 4-edge unroll)
    k_agg2<<<(N + 31) / 32, 256, 0, stream>>>(h2bf, als2, ald2, rp, esrc, b2, out2, N);
    // 10. BN2 stats
    k_stats<<<STATS_BLOCKS, 256, 0, stream>>>(out2, partials, N, 32);
    k_stats2<<<1, 512, 0, stream>>>(partials, g2, be2, AB2, N, 32, STATS_BLOCKS);
    // 11. BN2+ELU + pool + classifier (bounds inline)
    k_pool<<<(G * 64 + 255) / 256, 256, 0, stream>>>(out2, AB2, batch, Wc, bc, out, N, G);
}

// Round 10
// 221.247 us; speedup vs baseline: 5.2041x; 1.1947x over previous
//
#include <hip/hip_runtime.h>
#include <hip/hip_bf16.h>
#include <math.h>

#define HEADS 4
#define HID 32
#define EMB 32
#define SLOPE 0.2f
#define BN_EPS 1e-5f
#define STATS_BLOCKS 256
#define MB 128     // moment-stats blocks
#define BNUM 256   // bucket array size (actual B = ceil(N/512) <= 256)
#define P 256      // radix blocks

__device__ __forceinline__ float lrelu(float x) { return x > 0.f ? x : SLOPE * x; }
__device__ __forceinline__ float elu(float x) { return x > 0.f ? x : expm1f(x); }

// RNE float->bf16 and pack/unpack helpers
__device__ __forceinline__ unsigned f2bf_pack(float a, float b) {
    unsigned ua = __float_as_uint(a);
    unsigned ub = __float_as_uint(b);
    unsigned ra = (ua + 0x7fffu + ((ua >> 16) & 1u)) >> 16;
    unsigned rb = (ub + 0x7fffu + ((ub >> 16) & 1u)) >> 16;
    return ra | (rb << 16);
}
__device__ __forceinline__ float bf_lo(unsigned p) { return __uint_as_float(p << 16); }
__device__ __forceinline__ float bf_hi(unsigned p) { return __uint_as_float(p & 0xffff0000u); }

// ---------------- tiny prep: Ms[2][4], Md[2][4] = per-head dot(W1 row, attn vec) ----------------
__global__ void k_prep(const float* __restrict__ W1, const float* __restrict__ as1,
                       const float* __restrict__ ad1, float* __restrict__ MsMd) {
    int t = threadIdx.x;
    if (t >= 16) return;
    int r = (t >> 2) & 1, h = t & 3;
    const float* a = (t >= 8) ? ad1 : as1;
    float s = 0.f;
#pragma unroll
    for (int d = 0; d < 32; d++) s += W1[r * 128 + h * 32 + d] * a[h * 32 + d];
    MsMd[t] = s;
}

// ---------------- pass A: per-block histogram, p-major ghist[p][b] ----------------
__global__ void __launch_bounds__(256) k_hist(const int* __restrict__ ei,
                                              int* __restrict__ ghist, int E_, int CH) {
    __shared__ int h[BNUM];
    int t = threadIdx.x, p = blockIdx.x;
    h[t] = 0;
    __syncthreads();
    int beg = p * CH, end = beg + CH;
    if (end > E_) end = E_;
    for (int e = beg + t; e < end; e += 256) atomicAdd(&h[ei[E_ + e] >> 9], 1);
    __syncthreads();
    ghist[p * BNUM + t] = h[t];  // coalesced
}

// ---------------- pass B: exclusive scan of ghist in bucket-major order ----------------
__global__ void __launch_bounds__(1024) k_gscan(const int* __restrict__ ghist,
                                                int* __restrict__ goff, int* __restrict__ sbase,
                                                int* __restrict__ rp, int N_, int E_) {
    __shared__ int s[1024];
    int t = threadIdx.x;
    const int PER = (BNUM * P) / 1024;  // 64
    int b0 = t >> 2;
    int p0 = (t & 3) * PER;
    int v[PER];
    int sum = 0;
#pragma unroll
    for (int k = 0; k < PER; k++) {
        v[k] = ghist[(p0 + k) * BNUM + b0];
        sum += v[k];
    }
    s[t] = sum;
    __syncthreads();
    for (int off = 1; off < 1024; off <<= 1) {
        int a = (t >= off) ? s[t - off] : 0;
        __syncthreads();
        s[t] += a;
        __syncthreads();
    }
    int run = s[t] - sum;
#pragma unroll
    for (int k = 0; k < PER; k++) {
        if (p0 + k == 0) sbase[b0] = run;
        goff[(p0 + k) * BNUM + b0] = run;
        run += v[k];
    }
    if (t == 0) {
        sbase[BNUM] = E_;
        rp[N_] = E_ + N_;
    }
}

// ---------------- pass C: scatter into block-private per-bucket ranges ----------------
__global__ void __launch_bounds__(256) k_scatter3(const int* __restrict__ ei,
                                                  const int* __restrict__ goff,
                                                  unsigned* __restrict__ staged,
                                                  int E_, int CH) {
    __shared__ int loff[BNUM];
    __shared__ int lpos[BNUM];
    int t = threadIdx.x, p = blockIdx.x;
    loff[t] = goff[p * BNUM + t];
    lpos[t] = 0;
    __syncthreads();
    int beg = p * CH, end = beg + CH;
    if (end > E_) end = E_;
    for (int e = beg + t; e < end; e += 256) {
        int s = ei[e], d = ei[E_ + e];
        int b = d >> 9;
        unsigned pk = ((unsigned)s << 9) | (unsigned)(d & 511);
        int pos = loff[b] + atomicAdd(&lpos[b], 1);
        staged[pos] = pk;
    }
}

// ---------------- per-bucket finalize: count, scan, write rp + esrc (+self loops) -------
__global__ void __launch_bounds__(512) k_bucket(const unsigned* __restrict__ staged,
                                                const int* __restrict__ sbase,
                                                int* __restrict__ rp, int* __restrict__ esrc,
                                                int N_) {
    int b = blockIdx.x;
    int n0 = b << 9;
    int nn = N_ - n0;
    if (nn > 512) nn = 512;
    if (nn <= 0) return;
    __shared__ int lc[512];
    __shared__ int sc[512];
    __shared__ int wpos[512];
    int t = threadIdx.x;
    lc[t] = 0;
    __syncthreads();
    int sb = sbase[b];
    int m = sbase[b + 1] - sb;
    int eb = sb + (b << 9);
    for (int i = t; i < m; i += 512) atomicAdd(&lc[staged[sb + i] & 511], 1);
    __syncthreads();
    sc[t] = lc[t];
    __syncthreads();
    for (int off = 1; off < 512; off <<= 1) {
        int a = (t >= off) ? sc[t - off] : 0;
        __syncthreads();
        sc[t] += a;
        __syncthreads();
    }
    if (t < nn) {
        int r = eb + (sc[t] - lc[t]) + t;
        rp[n0 + t] = r;
        wpos[t] = r;
        esrc[r + lc[t]] = n0 + t;          // self loop at final slot (no atomic)
    }
    __syncthreads();
    for (int i = t; i < m; i += 512) {
        unsigned p = staged[sb + i];
        int q = atomicAdd(&wpos[p & 511], 1);
        esrc[q] = (int)(p >> 9);
    }
}

// ---------------- layer 1 aggregation, FACTORIZED: emit only (sx,sy) per head ----------
// h1[s] = x0[s]*W1r0 + x1[s]*W1r1 (rank-2): softmax-weighted mean of x per head fully
// determines the 128-d output. Writes nsum[node][8] = {sx[0..3], sy[0..3]}.
__global__ void __launch_bounds__(256) k_agg1f(
        const float* __restrict__ x, const int* __restrict__ rp,
        const int* __restrict__ esrc, const float* __restrict__ MsMd,
        float* __restrict__ nsum, int n) {
    __shared__ float sM[16];
    int t = threadIdx.x;
    if (t < 16) sM[t] = MsMd[t];
    __syncthreads();
    int node = blockIdx.x * 64 + (t >> 2);
    int h = t & 3;
    if (node >= n) return;
    int beg = rp[node], end = rp[node + 1];
    const float2 xd = *reinterpret_cast<const float2*>(&x[(size_t)node * 2]);
    float ald = xd.x * sM[8 + h] + xd.y * sM[12 + h];
    float ms0 = sM[h], ms1 = sM[4 + h];
    float z = 0.f, sx = 0.f, sy = 0.f;
#pragma unroll 2
    for (int e = beg; e < end; e++) {
        int s = esrc[e];
        float2 xs = *reinterpret_cast<const float2*>(&x[(size_t)s * 2]);
        float al = xs.x * ms0 + xs.y * ms1;
        float w = __expf(lrelu(al + ald));
        z += w;
        sx = fmaf(w, xs.x, sx);
        sy = fmaf(w, xs.y, sy);
    }
    float inv = 1.f / (z + 1e-16f);
    nsum[(size_t)node * 8 + h] = sx * inv;
    nsum[(size_t)node * 8 + 4 + h] = sy * inv;
}

// ---------------- BN1 moment stats: 5 moments per head over nsum ----------------
__global__ void __launch_bounds__(256) k_mstats(const float* __restrict__ nsum,
                                                float* __restrict__ mpart, int n) {
    int t = threadIdx.x;
    float m[20];
#pragma unroll
    for (int j = 0; j < 20; j++) m[j] = 0.f;
    for (int node = blockIdx.x * 256 + t; node < n; node += gridDim.x * 256) {
        float4 a = *reinterpret_cast<const float4*>(&nsum[(size_t)node * 8]);
        float4 b = *reinterpret_cast<const float4*>(&nsum[(size_t)node * 8 + 4]);
        m[0] += a.x; m[1] += b.x; m[2] += a.x * a.x; m[3] += b.x * b.x; m[4] += a.x * b.x;
        m[5] += a.y; m[6] += b.y; m[7] += a.y * a.y; m[8] += b.y * b.y; m[9] += a.y * b.y;
        m[10] += a.z; m[11] += b.z; m[12] += a.z * a.z; m[13] += b.z * b.z; m[14] += a.z * b.z;
        m[15] += a.w; m[16] += b.w; m[17] += a.w * a.w; m[18] += b.w * b.w; m[19] += a.w * b.w;
    }
#pragma unroll
    for (int off = 1; off < 64; off <<= 1)
#pragma unroll
        for (int j = 0; j < 20; j++) m[j] += __shfl_xor(m[j], off);
    __shared__ float ls[4][20];
    if ((t & 63) == 0)
#pragma unroll
        for (int j = 0; j < 20; j++) ls[t >> 6][j] = m[j];
    __syncthreads();
    if (t < 20) mpart[blockIdx.x * 20 + t] = ls[0][t] + ls[1][t] + ls[2][t] + ls[3][t];
}

// ---------------- BN1 finalize: per-channel P,Q,R  (y = elu(P*sx + Q*sy + R)) ----------
__global__ void k_bn1fin(const float* __restrict__ mpart, const float* __restrict__ W1,
                         const float* __restrict__ b1, const float* __restrict__ g1,
                         const float* __restrict__ be1, float4* __restrict__ PQR,
                         int n, int nb) {
    int c = threadIdx.x;
    if (c >= 128) return;
    int h = c >> 5;
    float mx = 0.f, my = 0.f, mxx = 0.f, myy = 0.f, mxy = 0.f;
    for (int b = 0; b < nb; b++) {
        const float* p = &mpart[b * 20 + h * 5];
        mx += p[0]; my += p[1]; mxx += p[2]; myy += p[3]; mxy += p[4];
    }
    float invn = 1.f / (float)n;
    mx *= invn; my *= invn; mxx *= invn; myy *= invn; mxy *= invn;
    float w0 = W1[c], w1 = W1[128 + c], bb = b1[c];
    float mu = w0 * mx + w1 * my + bb;
    float ex2 = w0 * w0 * mxx + w1 * w1 * myy + 2.f * w0 * w1 * mxy
              + 2.f * bb * (w0 * mx + w1 * my) + bb * bb;
    float var = ex2 - mu * mu;
    float A = g1[c] * rsqrtf(var + BN_EPS);
    float B = be1[c] - mu * A;
    PQR[c] = make_float4(A * w0, A * w1, A * bb + B, 0.f);
}

// ---------------- layer 2 node transform: one thread per node, y on the fly -------------
// y[k] = elu(P[k]*sx[h] + Q[k]*sy[h] + R[k]); acc[32] in registers; W2 broadcast from LDS.
__global__ void __launch_bounds__(256) k_node2f(
        const float* __restrict__ nsum, const float4* __restrict__ PQR,
        const float* __restrict__ W2, const float* __restrict__ as2,
        const float* __restrict__ ad2, unsigned* __restrict__ h2bf,
        float* __restrict__ als2, float* __restrict__ ald2, int n) {
    __shared__ float sw[128 * 32];     // 16 KB
    __shared__ float4 spqr[128];       // 2 KB
    int t = threadIdx.x;
    for (int i = t; i < 128 * 32; i += 256) sw[i] = W2[i];
    if (t < 128) spqr[t] = PQR[t];
    __syncthreads();
    int node = blockIdx.x * 256 + t;
    if (node >= n) return;
    float4 sx4 = *reinterpret_cast<const float4*>(&nsum[(size_t)node * 8]);
    float4 sy4 = *reinterpret_cast<const float4*>(&nsum[(size_t)node * 8 + 4]);
    float acc[32];
#pragma unroll
    for (int c = 0; c < 32; c++) acc[c] = 0.f;
    const float4* sw4 = reinterpret_cast<const float4*>(sw);
    float sxh, syh;
#pragma unroll
    for (int h = 0; h < 4; h++) {
        if (h == 0) { sxh = sx4.x; syh = sy4.x; }
        else if (h == 1) { sxh = sx4.y; syh = sy4.y; }
        else if (h == 2) { sxh = sx4.z; syh = sy4.z; }
        else { sxh = sx4.w; syh = sy4.w; }
        for (int kk = 0; kk < 32; kk++) {
            int k = h * 32 + kk;
            float4 pqr = spqr[k];
            float yk = elu(fmaf(pqr.x, sxh, fmaf(pqr.y, syh, pqr.z)));
#pragma unroll
            for (int c4 = 0; c4 < 8; c4++) {
                float4 wv = sw4[k * 8 + c4];
                acc[c4 * 4 + 0] = fmaf(yk, wv.x, acc[c4 * 4 + 0]);
                acc[c4 * 4 + 1] = fmaf(yk, wv.y, acc[c4 * 4 + 1]);
                acc[c4 * 4 + 2] = fmaf(yk, wv.z, acc[c4 * 4 + 2]);
                acc[c4 * 4 + 3] = fmaf(yk, wv.w, acc[c4 * 4 + 3]);
            }
        }
    }
    float ps = 0.f, pd = 0.f;
#pragma unroll
    for (int c = 0; c < 32; c++) {
        ps = fmaf(acc[c], as2[c], ps);
        pd = fmaf(acc[c], ad2[c], pd);
    }
#pragma unroll
    for (int c = 0; c < 16; c++)
        h2bf[(size_t)node * 16 + c] = f2bf_pack(acc[2 * c], acc[2 * c + 1]);
    als2[node] = ps;
    ald2[node] = pd;
}

// ---------------- BN stats: stage 1 (deterministic tree, float4 loads) ----------------
__global__ void k_stats(const float* __restrict__ x, float* __restrict__ partials,
                        int n, int C) {
    int t = threadIdx.x;
    int G4 = C >> 2;
    int c4 = t & (G4 - 1);
    int rr = t / G4;
    int RPB = 256 / G4;
    float sx = 0.f, sy = 0.f, sz = 0.f, sw_ = 0.f;
    float qx = 0.f, qy = 0.f, qz = 0.f, qw = 0.f;
    for (int r = blockIdx.x * RPB + rr; r < n; r += gridDim.x * RPB) {
        float4 v = *reinterpret_cast<const float4*>(&x[(size_t)r * C + 4 * c4]);
        sx += v.x; sy += v.y; sz += v.z; sw_ += v.w;
        qx += v.x * v.x; qy += v.y * v.y; qz += v.z * v.z; qw += v.w * v.w;
    }
    __shared__ float4 ls[256], ls2[256];
    ls[t] = make_float4(sx, sy, sz, sw_);
    ls2[t] = make_float4(qx, qy, qz, qw);
    __syncthreads();
    if (rr == 0) {
        for (int j = 1; j < RPB; j++) {
            float4 a = ls[j * G4 + c4], b = ls2[j * G4 + c4];
            sx += a.x; sy += a.y; sz += a.z; sw_ += a.w;
            qx += b.x; qy += b.y; qz += b.z; qw += b.w;
        }
        *reinterpret_cast<float4*>(&partials[(size_t)blockIdx.x * 2 * C + 4 * c4]) =
            make_float4(sx, sy, sz, sw_);
        *reinterpret_cast<float4*>(&partials[(size_t)blockIdx.x * 2 * C + C + 4 * c4]) =
            make_float4(qx, qy, qz, qw);
    }
}
// ---------------- BN stats stage 2: parallel finalize (512 threads) ----------------
__global__ void k_stats2(const float* __restrict__ partials, const float* __restrict__ gamma,
                         const float* __restrict__ beta, float* __restrict__ AB,
                         int n, int C, int nb) {
    __shared__ float ls[512], ls2[512];
    int t = threadIdx.x;
    int R = 512 / C;
    int c = t & (C - 1);
    int r = t / C;
    float s = 0.f, s2 = 0.f;
    for (int b = r; b < nb; b += R) {
        s += partials[(size_t)b * 2 * C + c];
        s2 += partials[(size_t)b * 2 * C + C + c];
    }
    ls[t] = s;
    ls2[t] = s2;
    __syncthreads();
    for (int step = R >> 1; step > 0; step >>= 1) {
        if (r < step) {
            ls[t] += ls[t + step * C];
            ls2[t] += ls2[t + step * C];
        }
        __syncthreads();
    }
    if (r == 0) {
        float mu = ls[t] / n;
        float var = ls2[t] / n - mu * mu;
        float inv = rsqrtf(var + BN_EPS);
        float A = gamma[c] * inv;
        AB[c] = A;
        AB[C + c] = beta[c] - mu * A;
    }
}

// ---------------- layer 2 aggregation: 8-lane group per dst node, uint2 bf16 gather -------
__global__ void __launch_bounds__(256) k_agg2(
        const unsigned* __restrict__ h2bf, const float* __restrict__ als2,
        const float* __restrict__ ald2, const int* __restrict__ rp,
        const int* __restrict__ esrc, const float* __restrict__ b2,
        float* __restrict__ out, int n) {
    __shared__ int ss2[4][8][9];    // pad 9 -> group broadcasts on disjoint banks
    __shared__ float swv[4][8][9];
    int wslot = threadIdx.x >> 6;
    int lane = threadIdx.x & 63;
    int g = lane >> 3;       // group within wave
    int e = lane & 7;        // lane within group: dwords 2e,2e+1 of the row
    int wid = blockIdx.x * 32 + wslot * 8 + g;
    if (wid >= n) return;
    int beg = rp[wid], end = rp[wid + 1];
    float ad = ald2[wid];
    float a0 = 0.f, a1 = 0.f, a2 = 0.f, a3 = 0.f;
    float z = 0.f;
    const uint2* __restrict__ hrow = reinterpret_cast<const uint2*>(h2bf);
    for (int cb = beg; cb < end; cb += 8) {
        int cnt = end - cb;
        if (cnt > 8) cnt = 8;
        if (e < cnt) {
            int s = esrc[cb + e];
            ss2[wslot][g][e] = s;
            swv[wslot][g][e] = __expf(lrelu(als2[s] + ad));
        }
        int j = 0;
        for (; j + 4 <= cnt; j += 4) {
            int s0 = ss2[wslot][g][j];
            int s1 = ss2[wslot][g][j + 1];
            int s2 = ss2[wslot][g][j + 2];
            int s3 = ss2[wslot][g][j + 3];
            float w0 = swv[wslot][g][j];
            float w1 = swv[wslot][g][j + 1];
            float w2 = swv[wslot][g][j + 2];
            float w3 = swv[wslot][g][j + 3];
            uint2 p0 = hrow[(size_t)s0 * 8 + e];
            uint2 p1 = hrow[(size_t)s1 * 8 + e];
            uint2 p2 = hrow[(size_t)s2 * 8 + e];
            uint2 p3 = hrow[(size_t)s3 * 8 + e];
            z += w0 + w1 + w2 + w3;
            a0 = fmaf(w0, bf_lo(p0.x), a0); a1 = fmaf(w0, bf_hi(p0.x), a1);
            a2 = fmaf(w0, bf_lo(p0.y), a2); a3 = fmaf(w0, bf_hi(p0.y), a3);
            a0 = fmaf(w1, bf_lo(p1.x), a0); a1 = fmaf(w1, bf_hi(p1.x), a1);
            a2 = fmaf(w1, bf_lo(p1.y), a2); a3 = fmaf(w1, bf_hi(p1.y), a3);
            a0 = fmaf(w2, bf_lo(p2.x), a0); a1 = fmaf(w2, bf_hi(p2.x), a1);
            a2 = fmaf(w2, bf_lo(p2.y), a2); a3 = fmaf(w2, bf_hi(p2.y), a3);
            a0 = fmaf(w3, bf_lo(p3.x), a0); a1 = fmaf(w3, bf_hi(p3.x), a1);
            a2 = fmaf(w3, bf_lo(p3.y), a2); a3 = fmaf(w3, bf_hi(p3.y), a3);
        }
        for (; j < cnt; j++) {
            int s = ss2[wslot][g][j];
            float wgt = swv[wslot][g][j];
            z += wgt;
            uint2 p = hrow[(size_t)s * 8 + e];
            a0 = fmaf(wgt, bf_lo(p.x), a0);
            a1 = fmaf(wgt, bf_hi(p.x), a1);
            a2 = fmaf(wgt, bf_lo(p.y), a2);
            a3 = fmaf(wgt, bf_hi(p.y), a3);
        }
    }
    float inv = 1.f / (z + 1e-16f);   // z uniform across the 8-lane group
    const float4 bv = *reinterpret_cast<const float4*>(&b2[4 * e]);
    float4 o = make_float4(a0 * inv + bv.x, a1 * inv + bv.y, a2 * inv + bv.z, a3 * inv + bv.w);
    *reinterpret_cast<float4*>(&out[(size_t)wid * 32 + 4 * e]) = o;
}

// ---------------- BN2+ELU + mean pool + classifier: wave per graph (inline bounds) -------
__global__ void k_pool(const float* __restrict__ x, const float* __restrict__ AB2,
                       const int* __restrict__ batch, const float* __restrict__ Wc,
                       const float* __restrict__ bc, float* __restrict__ out, int n, int G_) {
    int wid = (blockIdx.x * blockDim.x + threadIdx.x) >> 6;
    int lane = threadIdx.x & 63;
    if (wid >= G_) return;
    int lo = 0, hi = n;
    while (lo < hi) {
        int mid = (lo + hi) >> 1;
        if (batch[mid] < wid) lo = mid + 1; else hi = mid;
    }
    int beg = lo;
    hi = n;
    while (lo < hi) {
        int mid = (lo + hi) >> 1;
        if (batch[mid] < wid + 1) lo = mid + 1; else hi = mid;
    }
    int end = lo;
    int half = lane >> 5, f = lane & 31;
    float A = AB2[f], B = AB2[32 + f];
    float acc = 0.f;
    for (int r = beg + half; r < end; r += 2) {
        float v = x[(size_t)r * 32 + f] * A + B;
        acc += elu(v);
    }
    acc += __shfl_xor(acc, 32);
    float cntf = (float)((end - beg) > 1 ? (end - beg) : 1);
    float embv = acc / cntf;
    float p0 = embv * Wc[f * 2], p1 = embv * Wc[f * 2 + 1];
#pragma unroll
    for (int o = 1; o < 32; o <<= 1) {
        p0 += __shfl_xor(p0, o);
        p1 += __shfl_xor(p1, o);
    }
    if (lane == 0) {
        out[wid * 2] = p0 + bc[0];
        out[wid * 2 + 1] = p1 + bc[1];
    }
}

extern "C" void kernel_launch(void* const* d_in, const int* in_sizes, int n_in,
                              void* d_out, int out_size, void* d_ws, size_t ws_size,
                              hipStream_t stream) {
    const float* x = (const float*)d_in[0];
    const int* ei = (const int*)d_in[1];
    const int* batch = (const int*)d_in[2];
    const float* W1 = (const float*)d_in[3];
    const float* as1 = (const float*)d_in[4];
    const float* ad1 = (const float*)d_in[5];
    const float* b1 = (const float*)d_in[6];
    const float* g1 = (const float*)d_in[7];
    const float* be1 = (const float*)d_in[8];
    const float* W2 = (const float*)d_in[9];
    const float* as2 = (const float*)d_in[10];
    const float* ad2 = (const float*)d_in[11];
    const float* b2 = (const float*)d_in[12];
    const float* g2 = (const float*)d_in[13];
    const float* be2 = (const float*)d_in[14];
    const float* Wc = (const float*)d_in[15];
    const float* bc = (const float*)d_in[16];
    float* out = (float*)d_out;

    const int N = in_sizes[0] / 2;
    const int E = in_sizes[1] / 2;
    const int G = out_size / 2;
    const int Etot = E + N;
    const int B = (N + 511) >> 9;     // buckets of 512 dst nodes (<= 256)
    const int CH = (E + P - 1) / P;   // edges per radix block

    // workspace layout
    char* w = (char*)d_ws;
    size_t off = 0;
    auto alloc = [&](size_t bytes) { void* p = w + off; off = (off + bytes + 255) & ~(size_t)255; return p; };
    float* nsum = (float*)alloc((size_t)N * 8 * 4);          // per-node (sx[4], sy[4])
    unsigned* l2buf = (unsigned*)alloc((size_t)N * 50 * 4);  // h2bf + als2 + ald2 + out2
    int* esrc = (int*)alloc((size_t)Etot * 4);
    unsigned* staged = (unsigned*)alloc((size_t)E * 4);
    int* rp = (int*)alloc((size_t)(N + 1) * 4);
    int* ghist = (int*)alloc((size_t)P * BNUM * 4);
    int* goff = (int*)alloc((size_t)P * BNUM * 4);
    int* sbase = (int*)alloc((BNUM + 1) * 4);
    float* partials = (float*)alloc((size_t)STATS_BLOCKS * 256 * 4);
    float* mpart = (float*)alloc((size_t)MB * 20 * 4);
    float* AB2 = (float*)alloc(64 * 4);
    float* MsMd = (float*)alloc(64 * 4);
    float4* PQR = (float4*)alloc(128 * 16);
    unsigned* h2bf = l2buf;                                  // N*16 uints (N x 32 bf16)
    float* als2 = (float*)(l2buf + (size_t)N * 16);          // N floats
    float* ald2 = (float*)(l2buf + (size_t)N * 17);          // N floats
    float* out2 = (float*)(l2buf + (size_t)N * 18);          // N*32 floats

    // 1. tiny prep: factorized attention matrices
    k_prep<<<1, 64, 0, stream>>>(W1, as1, ad1, MsMd);
    // 2. radix pass A: per-block histograms
    k_hist<<<P, 256, 0, stream>>>(ei, ghist, E, CH);
    // 3. radix pass B: bucket-major exclusive scan -> goff, sbase, rp[N]
    k_gscan<<<1, 1024, 0, stream>>>(ghist, goff, sbase, rp, N, E);
    // 4. radix pass C: scatter to block-private ranges
    k_scatter3<<<P, 256, 0, stream>>>(ei, goff, staged, E, CH);
    // 5. per-bucket finalize: rp + esrc (+self loops)
    k_bucket<<<B, 512, 0, stream>>>(staged, sbase, rp, esrc, N);
    // 6. layer 1 aggregation, factorized: only (sx,sy) per head
    k_agg1f<<<(N + 63) / 64, 256, 0, stream>>>(x, rp, esrc, MsMd, nsum, N);
    // 7. BN1 via per-head moments -> per-channel P,Q,R
    k_mstats<<<MB, 256, 0, stream>>>(nsum, mpart, N);
    k_bn1fin<<<1, 128, 0, stream>>>(mpart, W1, b1, g1, be1, PQR, N, MB);
    // 8. layer 2 node transform: y on the fly, one thread per node
    k_node2f<<<(N + 255) / 256, 256, 0, stream>>>(nsum, PQR, W2, as2, ad2, h2bf, als2, ald2, N);
    // 9. layer 2 aggregation (8-lane group per node, 4-edge unroll)
    k_agg2<<<(N + 31) / 32, 256, 0, stream>>>(h2bf, als2, ald2, rp, esrc, b2, out2, N);
    // 10. BN2 stats
    k_stats<<<STATS_BLOCKS, 256, 0, stream>>>(out2, partials, N, 32);
    k_stats2<<<1, 512, 0, stream>>>(partials, g2, be2, AB2, N, 32, STATS_BLOCKS);
    // 11. BN2+ELU + pool + classifier (bounds inline)
    k_pool<<<(G * 64 + 255) / 256, 256, 0, stream>>>(out2, AB2, batch, Wc, bc, out, N, G);
}